// Round 1
// baseline (915.287 us; speedup 1.0000x reference)
//
#include <hip/hip_runtime.h>

#define NN 50000
#define NE 800000
#define NG 32
#define HID 128
#define BNEPS 1e-5f

__device__ __forceinline__ float lrelu(float x) { return x > 0.f ? x : 0.2f * x; }

__device__ __forceinline__ unsigned fenc(float f) {
  unsigned u = __float_as_uint(f);
  return (u & 0x80000000u) ? ~u : (u | 0x80000000u);
}

// ---------------- preprocessing ----------------

__global__ __launch_bounds__(256) void k_hist(const int* __restrict__ ei,
    const float* __restrict__ eattr, int* __restrict__ deg, float* __restrict__ tot) {
  int e = blockIdx.x * 256 + threadIdx.x;
  if (e >= NE) return;
  int d = ei[NE + e];
  atomicAdd(&deg[d], 1);
  atomicAdd(&tot[d * 3 + 0], eattr[e * 3 + 0]);
  atomicAdd(&tot[d * 3 + 1], eattr[e * 3 + 1]);
  atomicAdd(&tot[d * 3 + 2], eattr[e * 3 + 2]);
}

__global__ __launch_bounds__(1024) void k_scan(const int* __restrict__ deg,
                                               int* __restrict__ rowp) {
  __shared__ int wsum[16];
  __shared__ int carry_s;
  int t = threadIdx.x, lane = t & 63, w = t >> 6;
  if (t == 0) carry_s = 0;
  __syncthreads();
  for (int base = 0; base < NN; base += 1024) {
    int i = base + t;
    int v = (i < NN) ? (deg[i] + 1) : 0;  // +1 for self loop
    int s = v;
#pragma unroll
    for (int off = 1; off < 64; off <<= 1) {
      int y = __shfl_up(s, off, 64);
      if (lane >= off) s += y;
    }
    if (lane == 63) wsum[w] = s;
    __syncthreads();
    if (t < 16) {
      int xv = wsum[t];
#pragma unroll
      for (int off = 1; off < 16; off <<= 1) {
        int y = __shfl_up(xv, off, 64);
        if (t >= off) xv += y;
      }
      wsum[t] = xv;
    }
    __syncthreads();
    int wexcl = (w == 0) ? 0 : wsum[w - 1];
    int carry = carry_s;
    int incl = carry + wexcl + s;
    if (i < NN) rowp[i] = incl - v;  // exclusive
    __syncthreads();
    if (t == 1023) carry_s = incl;
    __syncthreads();
  }
  if (t == 0) rowp[NN] = carry_s;
}

__global__ __launch_bounds__(256) void k_scatter(const int* __restrict__ ei,
    const float* __restrict__ eattr, const int* __restrict__ rowp,
    int* __restrict__ fill, const int* __restrict__ deg, const float* __restrict__ tot,
    int* __restrict__ esrc, float* __restrict__ ecsr) {
  int e = blockIdx.x * 256 + threadIdx.x;
  if (e < NE) {
    int d = ei[NE + e];
    int p = rowp[d] + atomicAdd(&fill[d], 1);
    esrc[p] = ei[e];
    ecsr[p * 3 + 0] = eattr[e * 3 + 0];
    ecsr[p * 3 + 1] = eattr[e * 3 + 1];
    ecsr[p * 3 + 2] = eattr[e * 3 + 2];
  } else if (e < NE + NN) {
    int n = e - NE;
    int p = rowp[n + 1] - 1;  // self loop in last slot
    esrc[p] = n;
    float inv = 1.f / fmaxf((float)deg[n], 1.f);
    ecsr[p * 3 + 0] = tot[n * 3 + 0] * inv;
    ecsr[p * 3 + 1] = tot[n * 3 + 1] * inv;
    ecsr[p * 3 + 2] = tot[n * 3 + 2] * inv;
  }
}

// ---------------- layer 0 input transform: A = x@W0l, B = x@W0r ----------------

__global__ __launch_bounds__(256) void k_xform0(const float* __restrict__ x,
    const float* __restrict__ W0l, const float* __restrict__ W0r,
    float* __restrict__ A, float* __restrict__ B) {
  int t = blockIdx.x * 256 + threadIdx.x;
  int n = t >> 5;
  int c = (t & 31) * 4;
  if (n >= NN) return;
  float x0 = x[n * 3 + 0], x1 = x[n * 3 + 1], x2 = x[n * 3 + 2];
  float4 a0 = *(const float4*)&W0l[c];
  float4 a1 = *(const float4*)&W0l[HID + c];
  float4 a2 = *(const float4*)&W0l[2 * HID + c];
  float4 oa;
  oa.x = x0 * a0.x + x1 * a1.x + x2 * a2.x;
  oa.y = x0 * a0.y + x1 * a1.y + x2 * a2.y;
  oa.z = x0 * a0.z + x1 * a1.z + x2 * a2.z;
  oa.w = x0 * a0.w + x1 * a1.w + x2 * a2.w;
  *(float4*)&A[(size_t)n * HID + c] = oa;
  float4 b0 = *(const float4*)&W0r[c];
  float4 b1 = *(const float4*)&W0r[HID + c];
  float4 b2 = *(const float4*)&W0r[2 * HID + c];
  float4 ob;
  ob.x = x0 * b0.x + x1 * b1.x + x2 * b2.x;
  ob.y = x0 * b0.y + x1 * b1.y + x2 * b2.y;
  ob.z = x0 * b0.z + x1 * b1.z + x2 * b2.z;
  ob.w = x0 * b0.w + x1 * b1.w + x2 * b2.w;
  *(float4*)&B[(size_t)n * HID + c] = ob;
}

// ---------------- GEMM: A = BN(relu(H)) @ W  (128x128) ----------------

__global__ __launch_bounds__(256) void k_gemm(const float* __restrict__ H,
    const float* __restrict__ W, const float* __restrict__ bns,
    const float* __restrict__ bnh, float* __restrict__ A) {
  extern __shared__ float lds[];
  float* hs = lds;              // 32 x 128
  float* Ws = lds + 32 * HID;   // 128 x 128
  int t = threadIdx.x;
  for (int i = t * 4; i < HID * HID; i += 1024)
    *(float4*)&Ws[i] = *(const float4*)&W[i];
  int rl = t >> 5;
  int c4 = (t & 31) * 4;
  float4 sc = *(const float4*)&bns[c4];
  float4 sh = *(const float4*)&bnh[c4];
  for (int r0 = blockIdx.x * 32; r0 < NN; r0 += gridDim.x * 32) {
    __syncthreads();
#pragma unroll
    for (int j = 0; j < 4; ++j) {
      int row = rl + 8 * j;
      int r = r0 + row;
      float4 hv = make_float4(0.f, 0.f, 0.f, 0.f);
      if (r < NN) hv = *(const float4*)&H[(size_t)r * HID + c4];
      float4 o;
      o.x = fmaxf(hv.x, 0.f) * sc.x + sh.x;
      o.y = fmaxf(hv.y, 0.f) * sc.y + sh.y;
      o.z = fmaxf(hv.z, 0.f) * sc.z + sh.z;
      o.w = fmaxf(hv.w, 0.f) * sc.w + sh.w;
      *(float4*)&hs[row * HID + c4] = o;
    }
    __syncthreads();
    float4 a0 = make_float4(0.f, 0.f, 0.f, 0.f);
    float4 a1 = a0, a2 = a0, a3 = a0;
#pragma unroll 4
    for (int k = 0; k < HID; ++k) {
      float4 wv = *(float4*)&Ws[k * HID + c4];
      float h0 = hs[(rl + 0) * HID + k];
      float h1 = hs[(rl + 8) * HID + k];
      float h2 = hs[(rl + 16) * HID + k];
      float h3 = hs[(rl + 24) * HID + k];
      a0.x += h0 * wv.x; a0.y += h0 * wv.y; a0.z += h0 * wv.z; a0.w += h0 * wv.w;
      a1.x += h1 * wv.x; a1.y += h1 * wv.y; a1.z += h1 * wv.z; a1.w += h1 * wv.w;
      a2.x += h2 * wv.x; a2.y += h2 * wv.y; a2.z += h2 * wv.z; a2.w += h2 * wv.w;
      a3.x += h3 * wv.x; a3.y += h3 * wv.y; a3.z += h3 * wv.z; a3.w += h3 * wv.w;
    }
    int r = r0 + rl;
    if (r < NN)      *(float4*)&A[(size_t)(r)*HID + c4] = a0;
    if (r + 8 < NN)  *(float4*)&A[(size_t)(r + 8) * HID + c4] = a1;
    if (r + 16 < NN) *(float4*)&A[(size_t)(r + 16) * HID + c4] = a2;
    if (r + 24 < NN) *(float4*)&A[(size_t)(r + 24) * HID + c4] = a3;
  }
}

// ---------------- GATv2 edge phase: one wave per dst node, online softmax ----------------

__global__ __launch_bounds__(256) void k_edge(const float* __restrict__ XL,
    const float* XR, const int* __restrict__ esrc, const float* __restrict__ ecsr,
    const int* __restrict__ rowp, const float* __restrict__ We,
    const float* __restrict__ att, const float* __restrict__ bias, float* H) {
  __shared__ float WeS[3 * HID];
  int t = threadIdx.x;
  for (int i = t; i < 3 * HID; i += 256) WeS[i] = We[i];
  __syncthreads();
  int lane = t & 63;
  int n = blockIdx.x * 4 + (t >> 6);
  int c = lane * 2;
  float2 xr = *(const float2*)&XR[(size_t)n * HID + c];
  float2 av = *(const float2*)&att[c];
  float w00 = WeS[c], w01 = WeS[c + 1];
  float w10 = WeS[HID + c], w11 = WeS[HID + c + 1];
  float w20 = WeS[2 * HID + c], w21 = WeS[2 * HID + c + 1];
  int beg = __builtin_amdgcn_readfirstlane(rowp[n]);
  int end = __builtin_amdgcn_readfirstlane(rowp[n + 1]);
  float m = -1e38f, s = 0.f, ax = 0.f, ay = 0.f;
  for (int i = beg; i < end; ++i) {
    int sn = esrc[i];
    float e0 = ecsr[i * 3 + 0], e1 = ecsr[i * 3 + 1], e2 = ecsr[i * 3 + 2];
    float2 xs = *(const float2*)&XL[(size_t)sn * HID + c];
    float v0 = lrelu(xs.x + xr.x + e0 * w00 + e1 * w10 + e2 * w20);
    float v1 = lrelu(xs.y + xr.y + e0 * w01 + e1 * w11 + e2 * w21);
    float part = v0 * av.x + v1 * av.y;
#pragma unroll
    for (int off = 32; off > 0; off >>= 1) part += __shfl_xor(part, off, 64);
    float nm = fmaxf(m, part);
    float scl = __expf(m - nm);
    float p = __expf(part - nm);
    s = s * scl + p;
    ax = ax * scl + p * xs.x;
    ay = ay * scl + p * xs.y;
    m = nm;
  }
  float inv = 1.f / s;
  float2 bv = *(const float2*)&bias[c];
  float2 o;
  o.x = ax * inv + bv.x;
  o.y = ay * inv + bv.y;
  *(float2*)&H[(size_t)n * HID + c] = o;
}

// ---------------- BN stats / params ----------------

__global__ __launch_bounds__(128) void k_bnstats(const float* __restrict__ H,
                                                 float* __restrict__ cs) {
  int c = threadIdx.x;
  float s1 = 0.f, s2 = 0.f;
  for (int n = blockIdx.x; n < NN; n += gridDim.x) {
    float v = fmaxf(H[(size_t)n * HID + c], 0.f);
    s1 += v;
    s2 += v * v;
  }
  atomicAdd(&cs[c], s1);
  atomicAdd(&cs[HID + c], s2);
}

__global__ __launch_bounds__(128) void k_bnparams(const float* __restrict__ cs,
    const float* __restrict__ g, const float* __restrict__ b,
    float* __restrict__ bns, float* __restrict__ bnh) {
  int c = threadIdx.x;
  float mu = cs[c] * (1.f / NN);
  float var = fmaxf(cs[HID + c] * (1.f / NN) - mu * mu, 0.f);
  float scv = g[c] / sqrtf(var + BNEPS);
  bns[c] = scv;
  bnh[c] = b[c] - mu * scv;
}

// ---------------- pooling (segment_max over sorted batch) ----------------

__global__ __launch_bounds__(128) void k_pool(const float* __restrict__ H,
    const int* __restrict__ batch, const float* __restrict__ bns,
    const float* __restrict__ bnh, unsigned* __restrict__ pooled) {
  int c = threadIdx.x;
  const int chunk = (NN + gridDim.x - 1) / gridDim.x;
  int n0 = blockIdx.x * chunk;
  int n1 = min(n0 + chunk, NN);
  if (n0 >= n1) return;
  float sc = bns[c], sh = bnh[c];
  int curg = batch[n0];
  float vmax = -3.402823e38f;
  for (int n = n0; n < n1; ++n) {
    int g = batch[n];
    if (g != curg) {
      atomicMax(&pooled[curg * HID + c], fenc(vmax));
      curg = g;
      vmax = -3.402823e38f;
    }
    float v = fmaxf(H[(size_t)n * HID + c], 0.f) * sc + sh;
    vmax = fmaxf(vmax, v);
  }
  atomicMax(&pooled[curg * HID + c], fenc(vmax));
}

// ---------------- FC head ----------------

__global__ __launch_bounds__(256) void k_fc(const unsigned* __restrict__ pooled,
    const float* __restrict__ W1, const float* __restrict__ b1,
    const float* __restrict__ W2, const float* __restrict__ b2,
    float* __restrict__ out) {
  __shared__ float P[NG * HID];
  __shared__ float Z[NG * HID];
  int t = threadIdx.x;
  for (int i = t; i < NG * HID; i += 256) {
    unsigned k = pooled[i];
    P[i] = (k & 0x80000000u) ? __uint_as_float(k ^ 0x80000000u) : __uint_as_float(~k);
  }
  __syncthreads();
  for (int i = t; i < NG * HID; i += 256) {
    int g = i >> 7, cc = i & 127;
    float acc = b1[cc];
    for (int k = 0; k < HID; ++k) acc += P[g * HID + k] * W1[k * HID + cc];
    Z[i] = fmaxf(acc, 0.f);
  }
  __syncthreads();
  for (int i = t; i < NG * 40; i += 256) {
    int g = i / 40, o = i % 40;
    float acc = b2[o];
    for (int k = 0; k < HID; ++k) acc += Z[g * HID + k] * W2[k * 40 + o];
    out[i] = acc;
  }
}

// ---------------- launch ----------------

extern "C" void kernel_launch(void* const* d_in, const int* in_sizes, int n_in,
                              void* d_out, int out_size, void* d_ws, size_t ws_size,
                              hipStream_t stream) {
  (void)in_sizes; (void)n_in; (void)out_size; (void)ws_size;
  const float* x     = (const float*)d_in[0];
  const float* eattr = (const float*)d_in[1];
  const int*   ei    = (const int*)d_in[2];
  const int*   batch = (const int*)d_in[3];
  const float* W0l   = (const float*)d_in[4];
  const float* W0r   = (const float*)d_in[5];
  const float* We0   = (const float*)d_in[6];
  const float* a0    = (const float*)d_in[7];
  const float* b0    = (const float*)d_in[8];
  const float* bn0g  = (const float*)d_in[9];
  const float* bn0b  = (const float*)d_in[10];
  const float* Wl    = (const float*)d_in[11];
  const float* Wel   = (const float*)d_in[12];
  const float* al    = (const float*)d_in[13];
  const float* bl    = (const float*)d_in[14];
  const float* bng   = (const float*)d_in[15];
  const float* bnb   = (const float*)d_in[16];
  const float* fc1W  = (const float*)d_in[17];
  const float* fc1b  = (const float*)d_in[18];
  const float* fc2W  = (const float*)d_in[19];
  const float* fc2b  = (const float*)d_in[20];
  float* out = (float*)d_out;

  char* ws = (char*)d_ws;
  float* A    = (float*)(ws + 0);                 // 50000*128*4 = 25,600,000
  float* Bm   = (float*)(ws + 25600000);          // 25,600,000
  float* ecsr = (float*)(ws + 51200000);          // 850000*3*4 = 10,200,000
  int*   esrc = (int*)(ws + 61400000);            // 850000*4   =  3,400,000
  int*   rowp = (int*)(ws + 64800000);            // 50001*4
  char*  zb   = ws + 65000064;                    // zeroed region start
  int*   deg  = (int*)(zb + 0);                   // 200,000
  int*   fill = (int*)(zb + 200000);              // 200,000
  float* tot  = (float*)(zb + 400000);            // 600,000
  float* cs   = (float*)(zb + 1000000);           // 3*256*4 = 3,072
  unsigned* pooled = (unsigned*)(zb + 1003072);   // 32*128*4 = 16,384
  const size_t ZLEN = 1019456;
  float* bns = (float*)(ws + 66019520);
  float* bnh = (float*)(ws + 66020032);

  hipMemsetAsync(zb, 0, ZLEN, stream);

  // build CSR (dst-sorted) with self loops + mean edge_attr fill
  k_hist<<<(NE + 255) / 256, 256, 0, stream>>>(ei, eattr, deg, tot);
  k_scan<<<1, 1024, 0, stream>>>(deg, rowp);
  k_scatter<<<(NE + NN + 255) / 256, 256, 0, stream>>>(ei, eattr, rowp, fill, deg, tot,
                                                       esrc, ecsr);

  const size_t GEMM_LDS = (size_t)(32 * HID + HID * HID) * 4;  // 81920 B

  // layer 0
  k_xform0<<<(NN * 32) / 256, 256, 0, stream>>>(x, W0l, W0r, A, Bm);
  k_edge<<<NN / 4, 256, 0, stream>>>(A, Bm, esrc, ecsr, rowp, We0, a0, b0, Bm);
  k_bnstats<<<256, 128, 0, stream>>>(Bm, cs);
  k_bnparams<<<1, 128, 0, stream>>>(cs, bn0g, bn0b, bns, bnh);

  // layer 1
  k_gemm<<<512, 256, GEMM_LDS, stream>>>(Bm, Wl, bns, bnh, A);
  k_edge<<<NN / 4, 256, 0, stream>>>(A, A, esrc, ecsr, rowp, Wel, al, bl, Bm);
  k_bnstats<<<256, 128, 0, stream>>>(Bm, cs + 256);
  k_bnparams<<<1, 128, 0, stream>>>(cs + 256, bng, bnb, bns, bnh);

  // layer 2
  k_gemm<<<512, 256, GEMM_LDS, stream>>>(Bm, Wl + 128 * 128, bns, bnh, A);
  k_edge<<<NN / 4, 256, 0, stream>>>(A, A, esrc, ecsr, rowp, Wel + 384, al + 128, bl + 128, Bm);
  k_bnstats<<<256, 128, 0, stream>>>(Bm, cs + 512);
  k_bnparams<<<1, 128, 0, stream>>>(cs + 512, bng + 128, bnb + 128, bns, bnh);

  // pool + FC head
  k_pool<<<256, 128, 0, stream>>>(Bm, batch, bns, bnh, pooled);
  k_fc<<<1, 256, 0, stream>>>(pooled, fc1W, fc1b, fc2W, fc2b, out);
}

// Round 2
// 803.227 us; speedup vs baseline: 1.1395x; 1.1395x over previous
//
#include <hip/hip_runtime.h>

#define NN 50000
#define NE 800000
#define NG 32
#define HID 128
#define BNEPS 1e-5f

__device__ __forceinline__ float lrelu(float x) { return x > 0.f ? x : 0.2f * x; }

__device__ __forceinline__ unsigned fenc(float f) {
  unsigned u = __float_as_uint(f);
  return (u & 0x80000000u) ? ~u : (u | 0x80000000u);
}

// ---------------- preprocessing ----------------

// degree histogram only (no float atomics — self-loop mean comes from CSR later)
__global__ __launch_bounds__(256) void k_hist(const int* __restrict__ ei,
                                              int* __restrict__ deg) {
  int e = blockIdx.x * 256 + threadIdx.x;
  if (e >= NE) return;
  atomicAdd(&deg[ei[NE + e]], 1);
}

__global__ __launch_bounds__(1024) void k_scan(const int* __restrict__ deg,
                                               int* __restrict__ rowp) {
  __shared__ int wsum[16];
  __shared__ int carry_s;
  int t = threadIdx.x, lane = t & 63, w = t >> 6;
  if (t == 0) carry_s = 0;
  __syncthreads();
  for (int base = 0; base < NN; base += 1024) {
    int i = base + t;
    int v = (i < NN) ? (deg[i] + 1) : 0;  // +1 for self loop
    int s = v;
#pragma unroll
    for (int off = 1; off < 64; off <<= 1) {
      int y = __shfl_up(s, off, 64);
      if (lane >= off) s += y;
    }
    if (lane == 63) wsum[w] = s;
    __syncthreads();
    if (t < 16) {
      int xv = wsum[t];
#pragma unroll
      for (int off = 1; off < 16; off <<= 1) {
        int y = __shfl_up(xv, off, 64);
        if (t >= off) xv += y;
      }
      wsum[t] = xv;
    }
    __syncthreads();
    int wexcl = (w == 0) ? 0 : wsum[w - 1];
    int carry = carry_s;
    int incl = carry + wexcl + s;
    if (i < NN) rowp[i] = incl - v;  // exclusive
    __syncthreads();
    if (t == 1023) carry_s = incl;
    __syncthreads();
  }
  if (t == 0) rowp[NN] = carry_s;
}

// scatter edges into dst-CSR order as packed {src_bits, e0, e1, e2}
__global__ __launch_bounds__(256) void k_scatter(const int* __restrict__ ei,
    const float* __restrict__ eattr, const int* __restrict__ rowp,
    int* __restrict__ fill, float4* __restrict__ edat) {
  int e = blockIdx.x * 256 + threadIdx.x;
  if (e >= NE) return;
  int d = ei[NE + e];
  int p = rowp[d] + atomicAdd(&fill[d], 1);
  float4 v;
  v.x = __int_as_float(ei[e]);
  v.y = eattr[e * 3 + 0];
  v.z = eattr[e * 3 + 1];
  v.w = eattr[e * 3 + 2];
  edat[p] = v;
}

// self-loop entry: mean of incoming edge attrs (contiguous CSR segment)
__global__ __launch_bounds__(256) void k_selfmean(const int* __restrict__ rowp,
                                                  float4* __restrict__ edat) {
  int n = blockIdx.x * 256 + threadIdx.x;
  if (n >= NN) return;
  int beg = rowp[n], end = rowp[n + 1];
  int cnt = end - 1 - beg;
  float s0 = 0.f, s1 = 0.f, s2 = 0.f;
  for (int i = beg; i < end - 1; ++i) {
    float4 v = edat[i];
    s0 += v.y; s1 += v.z; s2 += v.w;
  }
  float inv = cnt > 0 ? 1.f / (float)cnt : 0.f;
  float4 o;
  o.x = __int_as_float(n);
  o.y = s0 * inv; o.z = s1 * inv; o.w = s2 * inv;
  edat[end - 1] = o;
}

// ---------------- layer 0 input transform: A = x@W0l, B = x@W0r ----------------

__global__ __launch_bounds__(256) void k_xform0(const float* __restrict__ x,
    const float* __restrict__ W0l, const float* __restrict__ W0r,
    float* __restrict__ A, float* __restrict__ B) {
  int t = blockIdx.x * 256 + threadIdx.x;
  int n = t >> 5;
  int c = (t & 31) * 4;
  if (n >= NN) return;
  float x0 = x[n * 3 + 0], x1 = x[n * 3 + 1], x2 = x[n * 3 + 2];
  float4 a0 = *(const float4*)&W0l[c];
  float4 a1 = *(const float4*)&W0l[HID + c];
  float4 a2 = *(const float4*)&W0l[2 * HID + c];
  float4 oa;
  oa.x = x0 * a0.x + x1 * a1.x + x2 * a2.x;
  oa.y = x0 * a0.y + x1 * a1.y + x2 * a2.y;
  oa.z = x0 * a0.z + x1 * a1.z + x2 * a2.z;
  oa.w = x0 * a0.w + x1 * a1.w + x2 * a2.w;
  *(float4*)&A[(size_t)n * HID + c] = oa;
  float4 b0 = *(const float4*)&W0r[c];
  float4 b1 = *(const float4*)&W0r[HID + c];
  float4 b2 = *(const float4*)&W0r[2 * HID + c];
  float4 ob;
  ob.x = x0 * b0.x + x1 * b1.x + x2 * b2.x;
  ob.y = x0 * b0.y + x1 * b1.y + x2 * b2.y;
  ob.z = x0 * b0.z + x1 * b1.z + x2 * b2.z;
  ob.w = x0 * b0.w + x1 * b1.w + x2 * b2.w;
  *(float4*)&B[(size_t)n * HID + c] = ob;
}

// ---------------- GEMM: A = BN(relu(H)) @ W  (128x128) ----------------

__global__ __launch_bounds__(256) void k_gemm(const float* __restrict__ H,
    const float* __restrict__ W, const float* __restrict__ bns,
    const float* __restrict__ bnh, float* __restrict__ A) {
  extern __shared__ float lds[];
  float* hs = lds;              // 32 x 128
  float* Ws = lds + 32 * HID;   // 128 x 128
  int t = threadIdx.x;
  for (int i = t * 4; i < HID * HID; i += 1024)
    *(float4*)&Ws[i] = *(const float4*)&W[i];
  int rl = t >> 5;
  int c4 = (t & 31) * 4;
  float4 sc = *(const float4*)&bns[c4];
  float4 sh = *(const float4*)&bnh[c4];
  for (int r0 = blockIdx.x * 32; r0 < NN; r0 += gridDim.x * 32) {
    __syncthreads();
#pragma unroll
    for (int j = 0; j < 4; ++j) {
      int row = rl + 8 * j;
      int r = r0 + row;
      float4 hv = make_float4(0.f, 0.f, 0.f, 0.f);
      if (r < NN) hv = *(const float4*)&H[(size_t)r * HID + c4];
      float4 o;
      o.x = fmaxf(hv.x, 0.f) * sc.x + sh.x;
      o.y = fmaxf(hv.y, 0.f) * sc.y + sh.y;
      o.z = fmaxf(hv.z, 0.f) * sc.z + sh.z;
      o.w = fmaxf(hv.w, 0.f) * sc.w + sh.w;
      *(float4*)&hs[row * HID + c4] = o;
    }
    __syncthreads();
    float4 a0 = make_float4(0.f, 0.f, 0.f, 0.f);
    float4 a1 = a0, a2 = a0, a3 = a0;
#pragma unroll 4
    for (int k = 0; k < HID; ++k) {
      float4 wv = *(float4*)&Ws[k * HID + c4];
      float h0 = hs[(rl + 0) * HID + k];
      float h1 = hs[(rl + 8) * HID + k];
      float h2 = hs[(rl + 16) * HID + k];
      float h3 = hs[(rl + 24) * HID + k];
      a0.x += h0 * wv.x; a0.y += h0 * wv.y; a0.z += h0 * wv.z; a0.w += h0 * wv.w;
      a1.x += h1 * wv.x; a1.y += h1 * wv.y; a1.z += h1 * wv.z; a1.w += h1 * wv.w;
      a2.x += h2 * wv.x; a2.y += h2 * wv.y; a2.z += h2 * wv.z; a2.w += h2 * wv.w;
      a3.x += h3 * wv.x; a3.y += h3 * wv.y; a3.z += h3 * wv.z; a3.w += h3 * wv.w;
    }
    int r = r0 + rl;
    if (r < NN)      *(float4*)&A[(size_t)(r)*HID + c4] = a0;
    if (r + 8 < NN)  *(float4*)&A[(size_t)(r + 8) * HID + c4] = a1;
    if (r + 16 < NN) *(float4*)&A[(size_t)(r + 16) * HID + c4] = a2;
    if (r + 24 < NN) *(float4*)&A[(size_t)(r + 24) * HID + c4] = a3;
  }
}

// ---------------- GATv2 edge phase: one wave per dst node, online softmax ----------------

__global__ __launch_bounds__(256) void k_edge(const float* __restrict__ XL,
    const float* XR, const float4* __restrict__ edat,
    const int* __restrict__ rowp, const float* __restrict__ We,
    const float* __restrict__ att, const float* __restrict__ bias, float* H) {
  __shared__ float WeS[3 * HID];
  int t = threadIdx.x;
  for (int i = t; i < 3 * HID; i += 256) WeS[i] = We[i];
  __syncthreads();
  int lane = t & 63;
  int n = blockIdx.x * 4 + (t >> 6);
  int c = lane * 2;
  float2 xr = *(const float2*)&XR[(size_t)n * HID + c];
  float2 av = *(const float2*)&att[c];
  float w00 = WeS[c], w01 = WeS[c + 1];
  float w10 = WeS[HID + c], w11 = WeS[HID + c + 1];
  float w20 = WeS[2 * HID + c], w21 = WeS[2 * HID + c + 1];
  int beg = __builtin_amdgcn_readfirstlane(rowp[n]);
  int end = __builtin_amdgcn_readfirstlane(rowp[n + 1]);
  float m = -1e38f, s = 0.f, ax = 0.f, ay = 0.f;
  for (int i = beg; i < end; ++i) {
    float4 ed = edat[i];
    int sn = __float_as_int(ed.x);
    float2 xs = *(const float2*)&XL[(size_t)sn * HID + c];
    float v0 = lrelu(xs.x + xr.x + ed.y * w00 + ed.z * w10 + ed.w * w20);
    float v1 = lrelu(xs.y + xr.y + ed.y * w01 + ed.z * w11 + ed.w * w21);
    float part = v0 * av.x + v1 * av.y;
#pragma unroll
    for (int off = 32; off > 0; off >>= 1) part += __shfl_xor(part, off, 64);
    float nm = fmaxf(m, part);
    float scl = __expf(m - nm);
    float p = __expf(part - nm);
    s = s * scl + p;
    ax = ax * scl + p * xs.x;
    ay = ay * scl + p * xs.y;
    m = nm;
  }
  float inv = 1.f / s;
  float2 bv = *(const float2*)&bias[c];
  float2 o;
  o.x = ax * inv + bv.x;
  o.y = ay * inv + bv.y;
  *(float2*)&H[(size_t)n * HID + c] = o;
}

// ---------------- BN stats / params ----------------

__global__ __launch_bounds__(128) void k_bnstats(const float* __restrict__ H,
                                                 float* __restrict__ cs) {
  int c = threadIdx.x;
  float s1 = 0.f, s2 = 0.f;
  for (int n = blockIdx.x; n < NN; n += gridDim.x) {
    float v = fmaxf(H[(size_t)n * HID + c], 0.f);
    s1 += v;
    s2 += v * v;
  }
  atomicAdd(&cs[c], s1);
  atomicAdd(&cs[HID + c], s2);
}

__global__ __launch_bounds__(128) void k_bnparams(const float* __restrict__ cs,
    const float* __restrict__ g, const float* __restrict__ b,
    float* __restrict__ bns, float* __restrict__ bnh) {
  int c = threadIdx.x;
  float mu = cs[c] * (1.f / NN);
  float var = fmaxf(cs[HID + c] * (1.f / NN) - mu * mu, 0.f);
  float scv = g[c] / sqrtf(var + BNEPS);
  bns[c] = scv;
  bnh[c] = b[c] - mu * scv;
}

// ---------------- pooling (segment_max over sorted batch) ----------------

__global__ __launch_bounds__(128) void k_pool(const float* __restrict__ H,
    const int* __restrict__ batch, const float* __restrict__ bns,
    const float* __restrict__ bnh, unsigned* __restrict__ pooled) {
  int c = threadIdx.x;
  const int chunk = (NN + gridDim.x - 1) / gridDim.x;
  int n0 = blockIdx.x * chunk;
  int n1 = min(n0 + chunk, NN);
  if (n0 >= n1) return;
  float sc = bns[c], sh = bnh[c];
  int curg = batch[n0];
  float vmax = -3.402823e38f;
  for (int n = n0; n < n1; ++n) {
    int g = batch[n];
    if (g != curg) {
      atomicMax(&pooled[curg * HID + c], fenc(vmax));
      curg = g;
      vmax = -3.402823e38f;
    }
    float v = fmaxf(H[(size_t)n * HID + c], 0.f) * sc + sh;
    vmax = fmaxf(vmax, v);
  }
  atomicMax(&pooled[curg * HID + c], fenc(vmax));
}

// ---------------- FC head ----------------

__global__ __launch_bounds__(256) void k_fc(const unsigned* __restrict__ pooled,
    const float* __restrict__ W1, const float* __restrict__ b1,
    const float* __restrict__ W2, const float* __restrict__ b2,
    float* __restrict__ out) {
  __shared__ float P[NG * HID];
  __shared__ float Z[NG * HID];
  int t = threadIdx.x;
  for (int i = t; i < NG * HID; i += 256) {
    unsigned k = pooled[i];
    P[i] = (k & 0x80000000u) ? __uint_as_float(k ^ 0x80000000u) : __uint_as_float(~k);
  }
  __syncthreads();
  for (int i = t; i < NG * HID; i += 256) {
    int g = i >> 7, cc = i & 127;
    float acc = b1[cc];
    for (int k = 0; k < HID; ++k) acc += P[g * HID + k] * W1[k * HID + cc];
    Z[i] = fmaxf(acc, 0.f);
  }
  __syncthreads();
  for (int i = t; i < NG * 40; i += 256) {
    int g = i / 40, o = i % 40;
    float acc = b2[o];
    for (int k = 0; k < HID; ++k) acc += Z[g * HID + k] * W2[k * 40 + o];
    out[i] = acc;
  }
}

// ---------------- launch ----------------

extern "C" void kernel_launch(void* const* d_in, const int* in_sizes, int n_in,
                              void* d_out, int out_size, void* d_ws, size_t ws_size,
                              hipStream_t stream) {
  (void)in_sizes; (void)n_in; (void)out_size; (void)ws_size;
  const float* x     = (const float*)d_in[0];
  const float* eattr = (const float*)d_in[1];
  const int*   ei    = (const int*)d_in[2];
  const int*   batch = (const int*)d_in[3];
  const float* W0l   = (const float*)d_in[4];
  const float* W0r   = (const float*)d_in[5];
  const float* We0   = (const float*)d_in[6];
  const float* a0    = (const float*)d_in[7];
  const float* b0    = (const float*)d_in[8];
  const float* bn0g  = (const float*)d_in[9];
  const float* bn0b  = (const float*)d_in[10];
  const float* Wl    = (const float*)d_in[11];
  const float* Wel   = (const float*)d_in[12];
  const float* al    = (const float*)d_in[13];
  const float* bl    = (const float*)d_in[14];
  const float* bng   = (const float*)d_in[15];
  const float* bnb   = (const float*)d_in[16];
  const float* fc1W  = (const float*)d_in[17];
  const float* fc1b  = (const float*)d_in[18];
  const float* fc2W  = (const float*)d_in[19];
  const float* fc2b  = (const float*)d_in[20];
  float* out = (float*)d_out;

  char* ws = (char*)d_ws;
  float*  A    = (float*)(ws + 0);                 // 25,600,000
  float*  Bm   = (float*)(ws + 25600000);          // 25,600,000
  float4* edat = (float4*)(ws + 51200000);         // 850000*16 = 13,600,000
  int*    rowp = (int*)(ws + 64800000);            // 50001*4
  char*   zb   = ws + 65000064;                    // zeroed region start
  int*    deg  = (int*)(zb + 0);                   // 200,000
  int*    fill = (int*)(zb + 200000);              // 200,000
  float*  cs   = (float*)(zb + 400000);            // 3*256*4 = 3,072
  unsigned* pooled = (unsigned*)(zb + 403072);     // 32*128*4 = 16,384
  const size_t ZLEN = 419456;
  float* bns = (float*)(ws + 65419520);
  float* bnh = (float*)(ws + 65420032);

  hipMemsetAsync(zb, 0, ZLEN, stream);

  // build CSR (dst-sorted) with self loops + mean edge_attr fill
  k_hist<<<(NE + 255) / 256, 256, 0, stream>>>(ei, deg);
  k_scan<<<1, 1024, 0, stream>>>(deg, rowp);
  k_scatter<<<(NE + 255) / 256, 256, 0, stream>>>(ei, eattr, rowp, fill, edat);
  k_selfmean<<<(NN + 255) / 256, 256, 0, stream>>>(rowp, edat);

  const size_t GEMM_LDS = (size_t)(32 * HID + HID * HID) * 4;  // 81920 B

  // layer 0
  k_xform0<<<(NN * 32) / 256, 256, 0, stream>>>(x, W0l, W0r, A, Bm);
  k_edge<<<NN / 4, 256, 0, stream>>>(A, Bm, edat, rowp, We0, a0, b0, Bm);
  k_bnstats<<<256, 128, 0, stream>>>(Bm, cs);
  k_bnparams<<<1, 128, 0, stream>>>(cs, bn0g, bn0b, bns, bnh);

  // layer 1
  k_gemm<<<512, 256, GEMM_LDS, stream>>>(Bm, Wl, bns, bnh, A);
  k_edge<<<NN / 4, 256, 0, stream>>>(A, A, edat, rowp, Wel, al, bl, Bm);
  k_bnstats<<<256, 128, 0, stream>>>(Bm, cs + 256);
  k_bnparams<<<1, 128, 0, stream>>>(cs + 256, bng, bnb, bns, bnh);

  // layer 2
  k_gemm<<<512, 256, GEMM_LDS, stream>>>(Bm, Wl + 128 * 128, bns, bnh, A);
  k_edge<<<NN / 4, 256, 0, stream>>>(A, A, edat, rowp, Wel + 384, al + 128, bl + 128, Bm);
  k_bnstats<<<256, 128, 0, stream>>>(Bm, cs + 512);
  k_bnparams<<<1, 128, 0, stream>>>(cs + 512, bng + 128, bnb + 128, bns, bnh);

  // pool + FC head
  k_pool<<<256, 128, 0, stream>>>(Bm, batch, bns, bnh, pooled);
  k_fc<<<1, 256, 0, stream>>>(pooled, fc1W, fc1b, fc2W, fc2b, out);
}

// Round 3
// 713.676 us; speedup vs baseline: 1.2825x; 1.1255x over previous
//
#include <hip/hip_runtime.h>

#define NN 50000
#define NE 800000
#define NG 32
#define HID 128
#define BNEPS 1e-5f

__device__ __forceinline__ float lrelu(float x) { return x > 0.f ? x : 0.2f * x; }

__device__ __forceinline__ unsigned fenc(float f) {
  unsigned u = __float_as_uint(f);
  return (u & 0x80000000u) ? ~u : (u | 0x80000000u);
}

// ---------------- preprocessing ----------------

__global__ __launch_bounds__(256) void k_hist(const int* __restrict__ ei,
                                              int* __restrict__ deg) {
  int e = blockIdx.x * 256 + threadIdx.x;
  if (e >= NE) return;
  atomicAdd(&deg[ei[NE + e]], 1);
}

__global__ __launch_bounds__(1024) void k_scan(const int* __restrict__ deg,
                                               int* __restrict__ rowp) {
  __shared__ int wsum[16];
  __shared__ int carry_s;
  int t = threadIdx.x, lane = t & 63, w = t >> 6;
  if (t == 0) carry_s = 0;
  __syncthreads();
  for (int base = 0; base < NN; base += 1024) {
    int i = base + t;
    int v = (i < NN) ? (deg[i] + 1) : 0;  // +1 for self loop
    int s = v;
#pragma unroll
    for (int off = 1; off < 64; off <<= 1) {
      int y = __shfl_up(s, off, 64);
      if (lane >= off) s += y;
    }
    if (lane == 63) wsum[w] = s;
    __syncthreads();
    if (t < 16) {
      int xv = wsum[t];
#pragma unroll
      for (int off = 1; off < 16; off <<= 1) {
        int y = __shfl_up(xv, off, 64);
        if (t >= off) xv += y;
      }
      wsum[t] = xv;
    }
    __syncthreads();
    int wexcl = (w == 0) ? 0 : wsum[w - 1];
    int carry = carry_s;
    int incl = carry + wexcl + s;
    if (i < NN) rowp[i] = incl - v;  // exclusive
    __syncthreads();
    if (t == 1023) carry_s = incl;
    __syncthreads();
  }
  if (t == 0) rowp[NN] = carry_s;
}

// scatter edges into dst-CSR order as packed {src_bits, e0, e1, e2}
__global__ __launch_bounds__(256) void k_scatter(const int* __restrict__ ei,
    const float* __restrict__ eattr, const int* __restrict__ rowp,
    int* __restrict__ fill, float4* __restrict__ edat) {
  int e = blockIdx.x * 256 + threadIdx.x;
  if (e >= NE) return;
  int d = ei[NE + e];
  int p = rowp[d] + atomicAdd(&fill[d], 1);
  float4 v;
  v.x = __int_as_float(ei[e]);
  v.y = eattr[e * 3 + 0];
  v.z = eattr[e * 3 + 1];
  v.w = eattr[e * 3 + 2];
  edat[p] = v;
}

// self-loop entry: mean of incoming edge attrs. one WAVE per node.
__global__ __launch_bounds__(256) void k_selfmean(const int* __restrict__ rowp,
                                                  float4* __restrict__ edat) {
  int n = blockIdx.x * 4 + (threadIdx.x >> 6);
  int lane = threadIdx.x & 63;
  if (n >= NN) return;
  int beg = rowp[n], endm1 = rowp[n + 1] - 1;
  float s0 = 0.f, s1 = 0.f, s2 = 0.f;
  for (int i = beg + lane; i < endm1; i += 64) {
    float4 v = edat[i];
    s0 += v.y; s1 += v.z; s2 += v.w;
  }
#pragma unroll
  for (int off = 32; off > 0; off >>= 1) {
    s0 += __shfl_xor(s0, off, 64);
    s1 += __shfl_xor(s1, off, 64);
    s2 += __shfl_xor(s2, off, 64);
  }
  if (lane == 0) {
    int cnt = endm1 - beg;
    float inv = cnt > 0 ? 1.f / (float)cnt : 0.f;
    float4 o;
    o.x = __int_as_float(n);
    o.y = s0 * inv; o.z = s1 * inv; o.w = s2 * inv;
    edat[endm1] = o;
  }
}

// ---------------- layer 0 input transform: A = x@W0l, B = x@W0r ----------------

__global__ __launch_bounds__(256) void k_xform0(const float* __restrict__ x,
    const float* __restrict__ W0l, const float* __restrict__ W0r,
    float* __restrict__ A, float* __restrict__ B) {
  int t = blockIdx.x * 256 + threadIdx.x;
  int n = t >> 5;
  int c = (t & 31) * 4;
  if (n >= NN) return;
  float x0 = x[n * 3 + 0], x1 = x[n * 3 + 1], x2 = x[n * 3 + 2];
  float4 a0 = *(const float4*)&W0l[c];
  float4 a1 = *(const float4*)&W0l[HID + c];
  float4 a2 = *(const float4*)&W0l[2 * HID + c];
  float4 oa;
  oa.x = x0 * a0.x + x1 * a1.x + x2 * a2.x;
  oa.y = x0 * a0.y + x1 * a1.y + x2 * a2.y;
  oa.z = x0 * a0.z + x1 * a1.z + x2 * a2.z;
  oa.w = x0 * a0.w + x1 * a1.w + x2 * a2.w;
  *(float4*)&A[(size_t)n * HID + c] = oa;
  float4 b0 = *(const float4*)&W0r[c];
  float4 b1 = *(const float4*)&W0r[HID + c];
  float4 b2 = *(const float4*)&W0r[2 * HID + c];
  float4 ob;
  ob.x = x0 * b0.x + x1 * b1.x + x2 * b2.x;
  ob.y = x0 * b0.y + x1 * b1.y + x2 * b2.y;
  ob.z = x0 * b0.z + x1 * b1.z + x2 * b2.z;
  ob.w = x0 * b0.w + x1 * b1.w + x2 * b2.w;
  *(float4*)&B[(size_t)n * HID + c] = ob;
}

// ---------------- GEMM: A = BN(relu(H)) @ W, BN params computed from raw sums ----------------

__global__ __launch_bounds__(256) void k_gemm(const float* __restrict__ H,
    const float* __restrict__ W, const float* __restrict__ cs,
    const float* __restrict__ g, const float* __restrict__ b,
    float* __restrict__ A) {
  extern __shared__ float lds[];
  float* hs = lds;              // 32 x 128
  float* Ws = lds + 32 * HID;   // 128 x 128
  int t = threadIdx.x;
  for (int i = t * 4; i < HID * HID; i += 1024)
    *(float4*)&Ws[i] = *(const float4*)&W[i];
  int rl = t >> 5;
  int c4 = (t & 31) * 4;
  float4 s1v = *(const float4*)&cs[c4];
  float4 s2v = *(const float4*)&cs[HID + c4];
  float4 gv  = *(const float4*)&g[c4];
  float4 bv  = *(const float4*)&b[c4];
  float4 sc, sh;
  {
    float mu, var;
    mu = s1v.x * (1.f / NN); var = fmaxf(s2v.x * (1.f / NN) - mu * mu, 0.f);
    sc.x = gv.x * rsqrtf(var + BNEPS); sh.x = bv.x - mu * sc.x;
    mu = s1v.y * (1.f / NN); var = fmaxf(s2v.y * (1.f / NN) - mu * mu, 0.f);
    sc.y = gv.y * rsqrtf(var + BNEPS); sh.y = bv.y - mu * sc.y;
    mu = s1v.z * (1.f / NN); var = fmaxf(s2v.z * (1.f / NN) - mu * mu, 0.f);
    sc.z = gv.z * rsqrtf(var + BNEPS); sh.z = bv.z - mu * sc.z;
    mu = s1v.w * (1.f / NN); var = fmaxf(s2v.w * (1.f / NN) - mu * mu, 0.f);
    sc.w = gv.w * rsqrtf(var + BNEPS); sh.w = bv.w - mu * sc.w;
  }
  for (int r0 = blockIdx.x * 32; r0 < NN; r0 += gridDim.x * 32) {
    __syncthreads();
#pragma unroll
    for (int j = 0; j < 4; ++j) {
      int row = rl + 8 * j;
      int r = r0 + row;
      float4 hv = make_float4(0.f, 0.f, 0.f, 0.f);
      if (r < NN) hv = *(const float4*)&H[(size_t)r * HID + c4];
      float4 o;
      o.x = fmaxf(hv.x, 0.f) * sc.x + sh.x;
      o.y = fmaxf(hv.y, 0.f) * sc.y + sh.y;
      o.z = fmaxf(hv.z, 0.f) * sc.z + sh.z;
      o.w = fmaxf(hv.w, 0.f) * sc.w + sh.w;
      *(float4*)&hs[row * HID + c4] = o;
    }
    __syncthreads();
    float4 a0 = make_float4(0.f, 0.f, 0.f, 0.f);
    float4 a1 = a0, a2 = a0, a3 = a0;
#pragma unroll 4
    for (int k = 0; k < HID; ++k) {
      float4 wv = *(float4*)&Ws[k * HID + c4];
      float h0 = hs[(rl + 0) * HID + k];
      float h1 = hs[(rl + 8) * HID + k];
      float h2 = hs[(rl + 16) * HID + k];
      float h3 = hs[(rl + 24) * HID + k];
      a0.x += h0 * wv.x; a0.y += h0 * wv.y; a0.z += h0 * wv.z; a0.w += h0 * wv.w;
      a1.x += h1 * wv.x; a1.y += h1 * wv.y; a1.z += h1 * wv.z; a1.w += h1 * wv.w;
      a2.x += h2 * wv.x; a2.y += h2 * wv.y; a2.z += h2 * wv.z; a2.w += h2 * wv.w;
      a3.x += h3 * wv.x; a3.y += h3 * wv.y; a3.z += h3 * wv.z; a3.w += h3 * wv.w;
    }
    int r = r0 + rl;
    if (r < NN)      *(float4*)&A[(size_t)(r)*HID + c4] = a0;
    if (r + 8 < NN)  *(float4*)&A[(size_t)(r + 8) * HID + c4] = a1;
    if (r + 16 < NN) *(float4*)&A[(size_t)(r + 16) * HID + c4] = a2;
    if (r + 24 < NN) *(float4*)&A[(size_t)(r + 24) * HID + c4] = a3;
  }
}

// ---------------- GATv2 edge phase: one wave per dst, online softmax, SW pipeline ----------------

__global__ __launch_bounds__(256) void k_edge(const float* __restrict__ XL,
    const float* XR, const float4* __restrict__ edat,
    const int* __restrict__ rowp, const float* __restrict__ We,
    const float* __restrict__ att, const float* __restrict__ bias, float* H) {
  __shared__ float WeS[3 * HID];
  int t = threadIdx.x;
  for (int i = t; i < 3 * HID; i += 256) WeS[i] = We[i];
  __syncthreads();
  int lane = t & 63;
  int n = blockIdx.x * 4 + (t >> 6);
  int c = lane * 2;
  float2 xr = *(const float2*)&XR[(size_t)n * HID + c];
  float2 av = *(const float2*)&att[c];
  float w00 = WeS[c], w01 = WeS[c + 1];
  float w10 = WeS[HID + c], w11 = WeS[HID + c + 1];
  float w20 = WeS[2 * HID + c], w21 = WeS[2 * HID + c + 1];
  int beg = __builtin_amdgcn_readfirstlane(rowp[n]);
  int end = __builtin_amdgcn_readfirstlane(rowp[n + 1]);
  int last = end - 1;
  // software pipeline: edat 2 ahead, XL gather 1 ahead (clamped, branch-free)
  float4 edA = edat[beg];
  float4 edB = edat[min(beg + 1, last)];
  float2 xsA = *(const float2*)&XL[(size_t)__float_as_int(edA.x) * HID + c];
  float m = -1e38f, s = 0.f, ax = 0.f, ay = 0.f;
  for (int i = beg; i < end; ++i) {
    float4 edC = edat[min(i + 2, last)];
    float2 xsB = *(const float2*)&XL[(size_t)__float_as_int(edB.x) * HID + c];
    float v0 = lrelu(xsA.x + xr.x + edA.y * w00 + edA.z * w10 + edA.w * w20);
    float v1 = lrelu(xsA.y + xr.y + edA.y * w01 + edA.z * w11 + edA.w * w21);
    float part = (v0 * av.x + v1 * av.y) * 1.44269504f;  // exp2 domain
#pragma unroll
    for (int off = 32; off > 0; off >>= 1) part += __shfl_xor(part, off, 64);
    float nm = fmaxf(m, part);
    float scl = exp2f(m - nm);
    float p = exp2f(part - nm);
    s = s * scl + p;
    ax = ax * scl + p * xsA.x;
    ay = ay * scl + p * xsA.y;
    m = nm;
    edA = edB; edB = edC; xsA = xsB;
  }
  float inv = 1.f / s;
  float2 bv = *(const float2*)&bias[c];
  float2 o;
  o.x = ax * inv + bv.x;
  o.y = ay * inv + bv.y;
  *(float2*)&H[(size_t)n * HID + c] = o;
}

// ---------------- BN stats (raw sums) ----------------

__global__ __launch_bounds__(128) void k_bnstats(const float* __restrict__ H,
                                                 float* __restrict__ cs) {
  int c = threadIdx.x;
  int chunk = (NN + gridDim.x - 1) / gridDim.x;
  int n0 = blockIdx.x * chunk, n1 = min(n0 + chunk, NN);
  if (n0 >= n1) return;
  float s1 = 0.f, s2 = 0.f;
  for (int n = n0; n < n1; ++n) {
    float v = fmaxf(H[(size_t)n * HID + c], 0.f);
    s1 += v; s2 += v * v;
  }
  atomicAdd(&cs[c], s1);
  atomicAdd(&cs[HID + c], s2);
}

// ---------------- pooling (segment_max over sorted batch), BN fused ----------------

__global__ __launch_bounds__(128) void k_pool(const float* __restrict__ H,
    const int* __restrict__ batch, const float* __restrict__ cs,
    const float* __restrict__ g, const float* __restrict__ b,
    unsigned* __restrict__ pooled) {
  int c = threadIdx.x;
  const int chunk = (NN + gridDim.x - 1) / gridDim.x;
  int n0 = blockIdx.x * chunk;
  int n1 = min(n0 + chunk, NN);
  if (n0 >= n1) return;
  float mu = cs[c] * (1.f / NN);
  float var = fmaxf(cs[HID + c] * (1.f / NN) - mu * mu, 0.f);
  float sc = g[c] * rsqrtf(var + BNEPS);
  float sh = b[c] - mu * sc;
  int curg = batch[n0];
  float vmax = -3.402823e38f;
  for (int n = n0; n < n1; ++n) {
    int gg = batch[n];
    if (gg != curg) {
      atomicMax(&pooled[curg * HID + c], fenc(vmax));
      curg = gg;
      vmax = -3.402823e38f;
    }
    float v = fmaxf(H[(size_t)n * HID + c], 0.f) * sc + sh;
    vmax = fmaxf(vmax, v);
  }
  atomicMax(&pooled[curg * HID + c], fenc(vmax));
}

// ---------------- FC head: one block per graph ----------------

__global__ __launch_bounds__(128) void k_fc(const unsigned* __restrict__ pooled,
    const float* __restrict__ W1, const float* __restrict__ b1,
    const float* __restrict__ W2, const float* __restrict__ b2,
    float* __restrict__ out) {
  __shared__ float P[HID];
  __shared__ float Z[HID];
  int g = blockIdx.x, c = threadIdx.x;
  unsigned k = pooled[g * HID + c];
  P[c] = (k & 0x80000000u) ? __uint_as_float(k ^ 0x80000000u) : __uint_as_float(~k);
  __syncthreads();
  float acc = b1[c];
  for (int kk = 0; kk < HID; ++kk) acc += P[kk] * W1[kk * HID + c];
  Z[c] = fmaxf(acc, 0.f);
  __syncthreads();
  if (c < 40) {
    float a2 = b2[c];
    for (int kk = 0; kk < HID; ++kk) a2 += Z[kk] * W2[kk * 40 + c];
    out[g * 40 + c] = a2;
  }
}

// ---------------- launch ----------------

extern "C" void kernel_launch(void* const* d_in, const int* in_sizes, int n_in,
                              void* d_out, int out_size, void* d_ws, size_t ws_size,
                              hipStream_t stream) {
  (void)in_sizes; (void)n_in; (void)out_size; (void)ws_size;
  const float* x     = (const float*)d_in[0];
  const float* eattr = (const float*)d_in[1];
  const int*   ei    = (const int*)d_in[2];
  const int*   batch = (const int*)d_in[3];
  const float* W0l   = (const float*)d_in[4];
  const float* W0r   = (const float*)d_in[5];
  const float* We0   = (const float*)d_in[6];
  const float* a0    = (const float*)d_in[7];
  const float* b0    = (const float*)d_in[8];
  const float* bn0g  = (const float*)d_in[9];
  const float* bn0b  = (const float*)d_in[10];
  const float* Wl    = (const float*)d_in[11];
  const float* Wel   = (const float*)d_in[12];
  const float* al    = (const float*)d_in[13];
  const float* bl    = (const float*)d_in[14];
  const float* bng   = (const float*)d_in[15];
  const float* bnb   = (const float*)d_in[16];
  const float* fc1W  = (const float*)d_in[17];
  const float* fc1b  = (const float*)d_in[18];
  const float* fc2W  = (const float*)d_in[19];
  const float* fc2b  = (const float*)d_in[20];
  float* out = (float*)d_out;

  char* ws = (char*)d_ws;
  float*  A    = (float*)(ws + 0);                 // 25,600,000
  float*  Bm   = (float*)(ws + 25600000);          // 25,600,000
  float4* edat = (float4*)(ws + 51200000);         // 850000*16 = 13,600,000
  int*    rowp = (int*)(ws + 64800000);            // 50001*4
  char*   zb   = ws + 65000064;                    // zeroed region start
  int*    deg  = (int*)(zb + 0);                   // 200,000
  int*    fill = (int*)(zb + 200000);              // 200,000
  float*  cs   = (float*)(zb + 400000);            // 3*256*4 = 3,072
  unsigned* pooled = (unsigned*)(zb + 403072);     // 32*128*4 = 16,384
  const size_t ZLEN = 419456;

  hipMemsetAsync(zb, 0, ZLEN, stream);

  // build CSR (dst-sorted) with self loops + mean edge_attr fill
  k_hist<<<(NE + 255) / 256, 256, 0, stream>>>(ei, deg);
  k_scan<<<1, 1024, 0, stream>>>(deg, rowp);
  k_scatter<<<(NE + 255) / 256, 256, 0, stream>>>(ei, eattr, rowp, fill, edat);
  k_selfmean<<<(NN + 3) / 4, 256, 0, stream>>>(rowp, edat);

  const size_t GEMM_LDS = (size_t)(32 * HID + HID * HID) * 4;  // 81920 B

  // layer 0
  k_xform0<<<(NN * 32) / 256, 256, 0, stream>>>(x, W0l, W0r, A, Bm);
  k_edge<<<NN / 4, 256, 0, stream>>>(A, Bm, edat, rowp, We0, a0, b0, Bm);
  k_bnstats<<<2048, 128, 0, stream>>>(Bm, cs);

  // layer 1
  k_gemm<<<782, 256, GEMM_LDS, stream>>>(Bm, Wl, cs, bn0g, bn0b, A);
  k_edge<<<NN / 4, 256, 0, stream>>>(A, A, edat, rowp, Wel, al, bl, Bm);
  k_bnstats<<<2048, 128, 0, stream>>>(Bm, cs + 256);

  // layer 2
  k_gemm<<<782, 256, GEMM_LDS, stream>>>(Bm, Wl + 128 * 128, cs + 256, bng, bnb, A);
  k_edge<<<NN / 4, 256, 0, stream>>>(A, A, edat, rowp, Wel + 384, al + 128, bl + 128, Bm);
  k_bnstats<<<2048, 128, 0, stream>>>(Bm, cs + 512);

  // pool + FC head
  k_pool<<<2048, 128, 0, stream>>>(Bm, batch, cs + 512, bng + 128, bnb + 128, pooled);
  k_fc<<<NG, 128, 0, stream>>>(pooled, fc1W, fc1b, fc2W, fc2b, out);
}

// Round 4
// 606.644 us; speedup vs baseline: 1.5088x; 1.1764x over previous
//
#include <hip/hip_runtime.h>

#define NN 50000
#define NE 800000
#define NG 32
#define HID 128
#define BNEPS 1e-5f

__device__ __forceinline__ unsigned fenc(float f) {
  unsigned u = __float_as_uint(f);
  return (u & 0x80000000u) ? ~u : (u | 0x80000000u);
}

// fused DPP add: x += dpp_move(x); masked-out rows add 0
#define DPPADD(x, ctrl, rmask)                                                   \
  (x) += __int_as_float(__builtin_amdgcn_update_dpp(0, __float_as_int(x),        \
                                                    (ctrl), (rmask), 0xf, true))

// wave64 sum -> uniform scalar (valid in SGPR via readlane 63)
__device__ __forceinline__ float wave_sum_u(float x) {
  DPPADD(x, 0x111, 0xf);  // row_shr:1
  DPPADD(x, 0x112, 0xf);  // row_shr:2
  DPPADD(x, 0x114, 0xf);  // row_shr:4
  DPPADD(x, 0x118, 0xf);  // row_shr:8
  DPPADD(x, 0x142, 0xa);  // row_bcast:15 -> rows 1,3
  DPPADD(x, 0x143, 0xc);  // row_bcast:31 -> rows 2,3
  return __int_as_float(__builtin_amdgcn_readlane(__float_as_int(x), 63));
}

// ---------------- preprocessing ----------------

__global__ __launch_bounds__(256) void k_hist(const int* __restrict__ ei,
                                              int* __restrict__ deg) {
  int e = blockIdx.x * 256 + threadIdx.x;
  if (e >= NE) return;
  atomicAdd(&deg[ei[NE + e]], 1);
}

// hierarchical scan: A (per-block) -> B (block sums) -> C (add offsets)
__global__ __launch_bounds__(1024) void k_scanA(const int* __restrict__ deg,
                                                int* __restrict__ rowp,
                                                int* __restrict__ bsum) {
  __shared__ int wsum[16];
  int t = threadIdx.x, lane = t & 63, w = t >> 6;
  int i = blockIdx.x * 1024 + t;
  int v = (i < NN) ? (deg[i] + 1) : 0;  // +1 self loop
  int s = v;
#pragma unroll
  for (int off = 1; off < 64; off <<= 1) {
    int y = __shfl_up(s, off, 64);
    if (lane >= off) s += y;
  }
  if (lane == 63) wsum[w] = s;
  __syncthreads();
  if (t < 16) {
    int xv = wsum[t];
#pragma unroll
    for (int off = 1; off < 16; off <<= 1) {
      int y = __shfl_up(xv, off, 64);
      if (t >= off) xv += y;
    }
    wsum[t] = xv;
  }
  __syncthreads();
  int wexcl = (w == 0) ? 0 : wsum[w - 1];
  int incl = wexcl + s;
  if (i < NN) rowp[i] = incl - v;  // block-local exclusive
  if (t == 1023) bsum[blockIdx.x] = incl;
}

__global__ __launch_bounds__(64) void k_scanB(int* __restrict__ bsum,
                                              int* __restrict__ rowp) {
  int t = threadIdx.x;  // one wave; 49 block sums
  int v = (t < 49) ? bsum[t] : 0;
  int s = v;
#pragma unroll
  for (int off = 1; off < 64; off <<= 1) {
    int y = __shfl_up(s, off, 64);
    if (t >= off) s += y;
  }
  bsum[t] = s - v;                 // exclusive
  if (t == 48) rowp[NN] = s;       // total
}

__global__ __launch_bounds__(1024) void k_scanC(int* __restrict__ rowp,
                                                const int* __restrict__ bsum) {
  int i = blockIdx.x * 1024 + threadIdx.x;
  if (i < NN) rowp[i] += bsum[blockIdx.x];
}

// scatter edges into dst-CSR order as packed {src_bits, e0, e1, e2}
__global__ __launch_bounds__(256) void k_scatter(const int* __restrict__ ei,
    const float* __restrict__ eattr, const int* __restrict__ rowp,
    int* __restrict__ fill, float4* __restrict__ edat) {
  int e = blockIdx.x * 256 + threadIdx.x;
  if (e >= NE) return;
  int d = ei[NE + e];
  int p = rowp[d] + atomicAdd(&fill[d], 1);
  float4 v;
  v.x = __int_as_float(ei[e]);
  v.y = eattr[e * 3 + 0];
  v.z = eattr[e * 3 + 1];
  v.w = eattr[e * 3 + 2];
  edat[p] = v;
}

// self-loop entry: mean of incoming edge attrs. one WAVE per node.
__global__ __launch_bounds__(256) void k_selfmean(const int* __restrict__ rowp,
                                                  float4* __restrict__ edat) {
  int n = blockIdx.x * 4 + (threadIdx.x >> 6);
  int lane = threadIdx.x & 63;
  if (n >= NN) return;
  int beg = rowp[n], endm1 = rowp[n + 1] - 1;
  float s0 = 0.f, s1 = 0.f, s2 = 0.f;
  for (int i = beg + lane; i < endm1; i += 64) {
    float4 v = edat[i];
    s0 += v.y; s1 += v.z; s2 += v.w;
  }
#pragma unroll
  for (int off = 32; off > 0; off >>= 1) {
    s0 += __shfl_xor(s0, off, 64);
    s1 += __shfl_xor(s1, off, 64);
    s2 += __shfl_xor(s2, off, 64);
  }
  if (lane == 0) {
    int cnt = endm1 - beg;
    float inv = cnt > 0 ? 1.f / (float)cnt : 0.f;
    float4 o;
    o.x = __int_as_float(n);
    o.y = s0 * inv; o.z = s1 * inv; o.w = s2 * inv;
    edat[endm1] = o;
  }
}

// ---------------- layer 0 input transform: A = x@W0l, B = x@W0r ----------------

__global__ __launch_bounds__(256) void k_xform0(const float* __restrict__ x,
    const float* __restrict__ W0l, const float* __restrict__ W0r,
    float* __restrict__ A, float* __restrict__ B) {
  int t = blockIdx.x * 256 + threadIdx.x;
  int n = t >> 5;
  int c = (t & 31) * 4;
  if (n >= NN) return;
  float x0 = x[n * 3 + 0], x1 = x[n * 3 + 1], x2 = x[n * 3 + 2];
  float4 a0 = *(const float4*)&W0l[c];
  float4 a1 = *(const float4*)&W0l[HID + c];
  float4 a2 = *(const float4*)&W0l[2 * HID + c];
  float4 oa;
  oa.x = x0 * a0.x + x1 * a1.x + x2 * a2.x;
  oa.y = x0 * a0.y + x1 * a1.y + x2 * a2.y;
  oa.z = x0 * a0.z + x1 * a1.z + x2 * a2.z;
  oa.w = x0 * a0.w + x1 * a1.w + x2 * a2.w;
  *(float4*)&A[(size_t)n * HID + c] = oa;
  float4 b0 = *(const float4*)&W0r[c];
  float4 b1 = *(const float4*)&W0r[HID + c];
  float4 b2 = *(const float4*)&W0r[2 * HID + c];
  float4 ob;
  ob.x = x0 * b0.x + x1 * b1.x + x2 * b2.x;
  ob.y = x0 * b0.y + x1 * b1.y + x2 * b2.y;
  ob.z = x0 * b0.z + x1 * b1.z + x2 * b2.z;
  ob.w = x0 * b0.w + x1 * b1.w + x2 * b2.w;
  *(float4*)&B[(size_t)n * HID + c] = ob;
}

// ---------------- GEMM: A = BN(relu(H)) @ W, BN params from raw sums ----------------

__global__ __launch_bounds__(256) void k_gemm(const float* __restrict__ H,
    const float* __restrict__ W, const float* __restrict__ cs,
    const float* __restrict__ g, const float* __restrict__ b,
    float* __restrict__ A) {
  extern __shared__ float lds[];
  float* hs = lds;              // 32 x 128
  float* Ws = lds + 32 * HID;   // 128 x 128
  int t = threadIdx.x;
  for (int i = t * 4; i < HID * HID; i += 1024)
    *(float4*)&Ws[i] = *(const float4*)&W[i];
  int rl = t >> 5;
  int c4 = (t & 31) * 4;
  float4 s1v = *(const float4*)&cs[c4];
  float4 s2v = *(const float4*)&cs[HID + c4];
  float4 gv  = *(const float4*)&g[c4];
  float4 bv  = *(const float4*)&b[c4];
  float4 sc, sh;
  {
    float mu, var;
    mu = s1v.x * (1.f / NN); var = fmaxf(s2v.x * (1.f / NN) - mu * mu, 0.f);
    sc.x = gv.x * rsqrtf(var + BNEPS); sh.x = bv.x - mu * sc.x;
    mu = s1v.y * (1.f / NN); var = fmaxf(s2v.y * (1.f / NN) - mu * mu, 0.f);
    sc.y = gv.y * rsqrtf(var + BNEPS); sh.y = bv.y - mu * sc.y;
    mu = s1v.z * (1.f / NN); var = fmaxf(s2v.z * (1.f / NN) - mu * mu, 0.f);
    sc.z = gv.z * rsqrtf(var + BNEPS); sh.z = bv.z - mu * sc.z;
    mu = s1v.w * (1.f / NN); var = fmaxf(s2v.w * (1.f / NN) - mu * mu, 0.f);
    sc.w = gv.w * rsqrtf(var + BNEPS); sh.w = bv.w - mu * sc.w;
  }
  for (int r0 = blockIdx.x * 32; r0 < NN; r0 += gridDim.x * 32) {
    __syncthreads();
#pragma unroll
    for (int j = 0; j < 4; ++j) {
      int row = rl + 8 * j;
      int r = r0 + row;
      float4 hv = make_float4(0.f, 0.f, 0.f, 0.f);
      if (r < NN) hv = *(const float4*)&H[(size_t)r * HID + c4];
      float4 o;
      o.x = fmaxf(hv.x, 0.f) * sc.x + sh.x;
      o.y = fmaxf(hv.y, 0.f) * sc.y + sh.y;
      o.z = fmaxf(hv.z, 0.f) * sc.z + sh.z;
      o.w = fmaxf(hv.w, 0.f) * sc.w + sh.w;
      *(float4*)&hs[row * HID + c4] = o;
    }
    __syncthreads();
    float4 a0 = make_float4(0.f, 0.f, 0.f, 0.f);
    float4 a1 = a0, a2 = a0, a3 = a0;
#pragma unroll 4
    for (int k = 0; k < HID; ++k) {
      float4 wv = *(float4*)&Ws[k * HID + c4];
      float h0 = hs[(rl + 0) * HID + k];
      float h1 = hs[(rl + 8) * HID + k];
      float h2 = hs[(rl + 16) * HID + k];
      float h3 = hs[(rl + 24) * HID + k];
      a0.x += h0 * wv.x; a0.y += h0 * wv.y; a0.z += h0 * wv.z; a0.w += h0 * wv.w;
      a1.x += h1 * wv.x; a1.y += h1 * wv.y; a1.z += h1 * wv.z; a1.w += h1 * wv.w;
      a2.x += h2 * wv.x; a2.y += h2 * wv.y; a2.z += h2 * wv.z; a2.w += h2 * wv.w;
      a3.x += h3 * wv.x; a3.y += h3 * wv.y; a3.z += h3 * wv.z; a3.w += h3 * wv.w;
    }
    int r = r0 + rl;
    if (r < NN)      *(float4*)&A[(size_t)(r)*HID + c4] = a0;
    if (r + 8 < NN)  *(float4*)&A[(size_t)(r + 8) * HID + c4] = a1;
    if (r + 16 < NN) *(float4*)&A[(size_t)(r + 16) * HID + c4] = a2;
    if (r + 24 < NN) *(float4*)&A[(size_t)(r + 24) * HID + c4] = a3;
  }
}

// ---------------- GATv2 edge phase v3: DPP reduce, uniform-branch softmax ----------------

__global__ __launch_bounds__(256) void k_edge(const float* __restrict__ XL,
    const float* XR, const float4* __restrict__ edat,
    const int* __restrict__ rowp, const float* __restrict__ We,
    const float* __restrict__ att, const float* __restrict__ bias, float* H) {
  __shared__ float WeS[3 * HID];
  int t = threadIdx.x;
  for (int i = t; i < 3 * HID; i += 256) WeS[i] = We[i];
  __syncthreads();
  int lane = t & 63;
  int n = blockIdx.x * 4 + (t >> 6);
  int c = lane * 2;
  float2 xr = *(const float2*)&XR[(size_t)n * HID + c];
  float2 av = *(const float2*)&att[c];
  av.x *= 1.44269504f;  // fold log2(e) into att
  av.y *= 1.44269504f;
  float w00 = WeS[c], w01 = WeS[c + 1];
  float w10 = WeS[HID + c], w11 = WeS[HID + c + 1];
  float w20 = WeS[2 * HID + c], w21 = WeS[2 * HID + c + 1];
  int beg = __builtin_amdgcn_readfirstlane(rowp[n]);
  int end = __builtin_amdgcn_readfirstlane(rowp[n + 1]);
  int last = end - 1;
  // pipeline: edat 3 ahead, XL gather 2 ahead (clamped, branch-free)
  float4 ed0 = edat[beg];
  float4 ed1 = edat[min(beg + 1, last)];
  float4 ed2 = edat[min(beg + 2, last)];
  float2 xs0 = *(const float2*)&XL[(size_t)__float_as_int(ed0.x) * HID + c];
  float2 xs1 = *(const float2*)&XL[(size_t)__float_as_int(ed1.x) * HID + c];
  float m = -1e30f, s = 0.f, ax = 0.f, ay = 0.f;
  for (int i = beg; i < end; ++i) {
    float4 edN = edat[min(i + 3, last)];
    float2 xs2 = *(const float2*)&XL[(size_t)__float_as_int(ed2.x) * HID + c];
    float u0 = xs0.x + xr.x + ed0.y * w00 + ed0.z * w10 + ed0.w * w20;
    float u1 = xs0.y + xr.y + ed0.y * w01 + ed0.z * w11 + ed0.w * w21;
    float v0 = fmaxf(u0, 0.2f * u0);          // leaky relu
    float v1 = fmaxf(u1, 0.2f * u1);
    float part = wave_sum_u(v0 * av.x + v1 * av.y);  // uniform logit (log2 domain)
    if (part <= m) {        // wave-uniform branch: no new max (common case)
      float p = exp2f(part - m);
      s += p;
      ax += p * xs0.x;
      ay += p * xs0.y;
    } else {                // rescale path
      float scl = exp2f(m - part);
      s = s * scl + 1.f;
      ax = ax * scl + xs0.x;
      ay = ay * scl + xs0.y;
      m = part;
    }
    ed0 = ed1; ed1 = ed2; ed2 = edN; xs0 = xs1; xs1 = xs2;
  }
  float inv = 1.f / s;
  float2 bv = *(const float2*)&bias[c];
  float2 o;
  o.x = ax * inv + bv.x;
  o.y = ay * inv + bv.y;
  *(float2*)&H[(size_t)n * HID + c] = o;
}

// ---------------- BN stats (raw sums) ----------------

__global__ __launch_bounds__(128) void k_bnstats(const float* __restrict__ H,
                                                 float* __restrict__ cs) {
  int c = threadIdx.x;
  int chunk = (NN + gridDim.x - 1) / gridDim.x;
  int n0 = blockIdx.x * chunk, n1 = min(n0 + chunk, NN);
  if (n0 >= n1) return;
  float s1 = 0.f, s2 = 0.f;
  for (int n = n0; n < n1; ++n) {
    float v = fmaxf(H[(size_t)n * HID + c], 0.f);
    s1 += v; s2 += v * v;
  }
  atomicAdd(&cs[c], s1);
  atomicAdd(&cs[HID + c], s2);
}

// ---------------- pooling (segment_max over sorted batch), BN fused ----------------

__global__ __launch_bounds__(128) void k_pool(const float* __restrict__ H,
    const int* __restrict__ batch, const float* __restrict__ cs,
    const float* __restrict__ g, const float* __restrict__ b,
    unsigned* __restrict__ pooled) {
  int c = threadIdx.x;
  const int chunk = (NN + gridDim.x - 1) / gridDim.x;
  int n0 = blockIdx.x * chunk;
  int n1 = min(n0 + chunk, NN);
  if (n0 >= n1) return;
  float mu = cs[c] * (1.f / NN);
  float var = fmaxf(cs[HID + c] * (1.f / NN) - mu * mu, 0.f);
  float sc = g[c] * rsqrtf(var + BNEPS);
  float sh = b[c] - mu * sc;
  int curg = batch[n0];
  float vmax = -3.402823e38f;
  for (int n = n0; n < n1; ++n) {
    int gg = batch[n];
    if (gg != curg) {
      atomicMax(&pooled[curg * HID + c], fenc(vmax));
      curg = gg;
      vmax = -3.402823e38f;
    }
    float v = fmaxf(H[(size_t)n * HID + c], 0.f) * sc + sh;
    vmax = fmaxf(vmax, v);
  }
  atomicMax(&pooled[curg * HID + c], fenc(vmax));
}

// ---------------- FC head: one block per graph ----------------

__global__ __launch_bounds__(128) void k_fc(const unsigned* __restrict__ pooled,
    const float* __restrict__ W1, const float* __restrict__ b1,
    const float* __restrict__ W2, const float* __restrict__ b2,
    float* __restrict__ out) {
  __shared__ float P[HID];
  __shared__ float Z[HID];
  int g = blockIdx.x, c = threadIdx.x;
  unsigned k = pooled[g * HID + c];
  P[c] = (k & 0x80000000u) ? __uint_as_float(k ^ 0x80000000u) : __uint_as_float(~k);
  __syncthreads();
  float acc = b1[c];
  for (int kk = 0; kk < HID; ++kk) acc += P[kk] * W1[kk * HID + c];
  Z[c] = fmaxf(acc, 0.f);
  __syncthreads();
  if (c < 40) {
    float a2 = b2[c];
    for (int kk = 0; kk < HID; ++kk) a2 += Z[kk] * W2[kk * 40 + c];
    out[g * 40 + c] = a2;
  }
}

// ---------------- launch ----------------

extern "C" void kernel_launch(void* const* d_in, const int* in_sizes, int n_in,
                              void* d_out, int out_size, void* d_ws, size_t ws_size,
                              hipStream_t stream) {
  (void)in_sizes; (void)n_in; (void)out_size; (void)ws_size;
  const float* x     = (const float*)d_in[0];
  const float* eattr = (const float*)d_in[1];
  const int*   ei    = (const int*)d_in[2];
  const int*   batch = (const int*)d_in[3];
  const float* W0l   = (const float*)d_in[4];
  const float* W0r   = (const float*)d_in[5];
  const float* We0   = (const float*)d_in[6];
  const float* a0    = (const float*)d_in[7];
  const float* b0    = (const float*)d_in[8];
  const float* bn0g  = (const float*)d_in[9];
  const float* bn0b  = (const float*)d_in[10];
  const float* Wl    = (const float*)d_in[11];
  const float* Wel   = (const float*)d_in[12];
  const float* al    = (const float*)d_in[13];
  const float* bl    = (const float*)d_in[14];
  const float* bng   = (const float*)d_in[15];
  const float* bnb   = (const float*)d_in[16];
  const float* fc1W  = (const float*)d_in[17];
  const float* fc1b  = (const float*)d_in[18];
  const float* fc2W  = (const float*)d_in[19];
  const float* fc2b  = (const float*)d_in[20];
  float* out = (float*)d_out;

  char* ws = (char*)d_ws;
  float*  A    = (float*)(ws + 0);                 // 25,600,000
  float*  Bm   = (float*)(ws + 25600000);          // 25,600,000
  float4* edat = (float4*)(ws + 51200000);         // 850000*16 = 13,600,000
  int*    rowp = (int*)(ws + 64800000);            // 50001*4
  char*   zb   = ws + 65000064;                    // zeroed region start
  int*    deg  = (int*)(zb + 0);                   // 200,000
  int*    fill = (int*)(zb + 200000);              // 200,000
  float*  cs   = (float*)(zb + 400000);            // 3*256*4 = 3,072
  unsigned* pooled = (unsigned*)(zb + 403072);     // 32*128*4 = 16,384
  int*    bsum = (int*)(zb + 419456);              // 64*4 = 256
  const size_t ZLEN = 419712;

  hipMemsetAsync(zb, 0, ZLEN, stream);

  // build CSR (dst-sorted) with self loops + mean edge_attr fill
  k_hist<<<(NE + 255) / 256, 256, 0, stream>>>(ei, deg);
  k_scanA<<<49, 1024, 0, stream>>>(deg, rowp, bsum);
  k_scanB<<<1, 64, 0, stream>>>(bsum, rowp);
  k_scanC<<<49, 1024, 0, stream>>>(rowp, bsum);
  k_scatter<<<(NE + 255) / 256, 256, 0, stream>>>(ei, eattr, rowp, fill, edat);
  k_selfmean<<<(NN + 3) / 4, 256, 0, stream>>>(rowp, edat);

  const size_t GEMM_LDS = (size_t)(32 * HID + HID * HID) * 4;  // 81920 B

  // layer 0
  k_xform0<<<(NN * 32) / 256, 256, 0, stream>>>(x, W0l, W0r, A, Bm);
  k_edge<<<NN / 4, 256, 0, stream>>>(A, Bm, edat, rowp, We0, a0, b0, Bm);
  k_bnstats<<<2048, 128, 0, stream>>>(Bm, cs);

  // layer 1
  k_gemm<<<782, 256, GEMM_LDS, stream>>>(Bm, Wl, cs, bn0g, bn0b, A);
  k_edge<<<NN / 4, 256, 0, stream>>>(A, A, edat, rowp, Wel, al, bl, Bm);
  k_bnstats<<<2048, 128, 0, stream>>>(Bm, cs + 256);

  // layer 2
  k_gemm<<<782, 256, GEMM_LDS, stream>>>(Bm, Wl + 128 * 128, cs + 256, bng, bnb, A);
  k_edge<<<NN / 4, 256, 0, stream>>>(A, A, edat, rowp, Wel + 384, al + 128, bl + 128, Bm);
  k_bnstats<<<2048, 128, 0, stream>>>(Bm, cs + 512);

  // pool + FC head
  k_pool<<<2048, 128, 0, stream>>>(Bm, batch, cs + 512, bng + 128, bnb + 128, pooled);
  k_fc<<<NG, 128, 0, stream>>>(pooled, fc1W, fc1b, fc2W, fc2b, out);
}

// Round 5
// 583.257 us; speedup vs baseline: 1.5693x; 1.0401x over previous
//
#include <hip/hip_runtime.h>

#define NN 50000
#define NE 800000
#define NG 32
#define HID 128
#define BNEPS 1e-5f
#define NETOT (NE + NN)  // 850000, CSR total incl self loops

__device__ __forceinline__ unsigned fenc(float f) {
  unsigned u = __float_as_uint(f);
  return (u & 0x80000000u) ? ~u : (u | 0x80000000u);
}

// fused DPP add: x += dpp_move(x); masked-out rows add 0
#define DPPADD(x, ctrl, rmask)                                                   \
  (x) += __int_as_float(__builtin_amdgcn_update_dpp(0, __float_as_int(x),        \
                                                    (ctrl), (rmask), 0xf, true))

// wave64 sum -> uniform scalar (valid via readlane 63)
__device__ __forceinline__ float wave_sum_u(float x) {
  DPPADD(x, 0x111, 0xf);  // row_shr:1
  DPPADD(x, 0x112, 0xf);  // row_shr:2
  DPPADD(x, 0x114, 0xf);  // row_shr:4
  DPPADD(x, 0x118, 0xf);  // row_shr:8
  DPPADD(x, 0x142, 0xa);  // row_bcast:15 -> rows 1,3
  DPPADD(x, 0x143, 0xc);  // row_bcast:31 -> rows 2,3
  return __int_as_float(__builtin_amdgcn_readlane(__float_as_int(x), 63));
}

// ---------------- preprocessing ----------------

__global__ __launch_bounds__(256) void k_hist(const int* __restrict__ ei,
                                              int* __restrict__ deg) {
  int e = blockIdx.x * 256 + threadIdx.x;
  if (e >= NE) return;
  atomicAdd(&deg[ei[NE + e]], 1);
}

// hierarchical scan: A (per-block) -> B (block sums) -> C (add offsets)
__global__ __launch_bounds__(1024) void k_scanA(const int* __restrict__ deg,
                                                int* __restrict__ rowp,
                                                int* __restrict__ bsum) {
  __shared__ int wsum[16];
  int t = threadIdx.x, lane = t & 63, w = t >> 6;
  int i = blockIdx.x * 1024 + t;
  int v = (i < NN) ? (deg[i] + 1) : 0;  // +1 self loop
  int s = v;
#pragma unroll
  for (int off = 1; off < 64; off <<= 1) {
    int y = __shfl_up(s, off, 64);
    if (lane >= off) s += y;
  }
  if (lane == 63) wsum[w] = s;
  __syncthreads();
  if (t < 16) {
    int xv = wsum[t];
#pragma unroll
    for (int off = 1; off < 16; off <<= 1) {
      int y = __shfl_up(xv, off, 64);
      if (t >= off) xv += y;
    }
    wsum[t] = xv;
  }
  __syncthreads();
  int wexcl = (w == 0) ? 0 : wsum[w - 1];
  int incl = wexcl + s;
  if (i < NN) rowp[i] = incl - v;  // block-local exclusive
  if (t == 1023) bsum[blockIdx.x] = incl;
}

__global__ __launch_bounds__(64) void k_scanB(int* __restrict__ bsum,
                                              int* __restrict__ rowp,
                                              float4* __restrict__ edat) {
  int t = threadIdx.x;  // one wave; 49 block sums
  int v = (t < 49) ? bsum[t] : 0;
  int s = v;
#pragma unroll
  for (int off = 1; off < 64; off <<= 1) {
    int y = __shfl_up(s, off, 64);
    if (t >= off) s += y;
  }
  bsum[t] = s - v;                 // exclusive
  if (t == 48) rowp[NN] = s;       // total (== NETOT)
  if (t < 4) {                     // pad entries for clamp-free prefetch
    float4 z;
    z.x = __int_as_float(0); z.y = 0.f; z.z = 0.f; z.w = 0.f;
    edat[NETOT + t] = z;
  }
}

__global__ __launch_bounds__(1024) void k_scanC(int* __restrict__ rowp,
                                                const int* __restrict__ bsum) {
  int i = blockIdx.x * 1024 + threadIdx.x;
  if (i < NN) rowp[i] += bsum[blockIdx.x];
}

// scatter edges into dst-CSR order as packed {src_bits, e0, e1, e2}
__global__ __launch_bounds__(256) void k_scatter(const int* __restrict__ ei,
    const float* __restrict__ eattr, const int* __restrict__ rowp,
    int* __restrict__ fill, float4* __restrict__ edat) {
  int e = blockIdx.x * 256 + threadIdx.x;
  if (e >= NE) return;
  int d = ei[NE + e];
  int p = rowp[d] + atomicAdd(&fill[d], 1);
  float4 v;
  v.x = __int_as_float(ei[e]);
  v.y = eattr[e * 3 + 0];
  v.z = eattr[e * 3 + 1];
  v.w = eattr[e * 3 + 2];
  edat[p] = v;
}

// self-loop entry: mean of incoming edge attrs. one WAVE per node.
__global__ __launch_bounds__(256) void k_selfmean(const int* __restrict__ rowp,
                                                  float4* __restrict__ edat) {
  int n = blockIdx.x * 4 + (threadIdx.x >> 6);
  int lane = threadIdx.x & 63;
  if (n >= NN) return;
  int beg = rowp[n], endm1 = rowp[n + 1] - 1;
  float s0 = 0.f, s1 = 0.f, s2 = 0.f;
  for (int i = beg + lane; i < endm1; i += 64) {
    float4 v = edat[i];
    s0 += v.y; s1 += v.z; s2 += v.w;
  }
#pragma unroll
  for (int off = 32; off > 0; off >>= 1) {
    s0 += __shfl_xor(s0, off, 64);
    s1 += __shfl_xor(s1, off, 64);
    s2 += __shfl_xor(s2, off, 64);
  }
  if (lane == 0) {
    int cnt = endm1 - beg;
    float inv = cnt > 0 ? 1.f / (float)cnt : 0.f;
    float4 o;
    o.x = __int_as_float(n);
    o.y = s0 * inv; o.z = s1 * inv; o.w = s2 * inv;
    edat[endm1] = o;
  }
}

// ---------------- layer 0 input transform: A = x@W0l, B = x@W0r ----------------

__global__ __launch_bounds__(256) void k_xform0(const float* __restrict__ x,
    const float* __restrict__ W0l, const float* __restrict__ W0r,
    float* __restrict__ A, float* __restrict__ B) {
  int t = blockIdx.x * 256 + threadIdx.x;
  int n = t >> 5;
  int c = (t & 31) * 4;
  if (n >= NN) return;
  float x0 = x[n * 3 + 0], x1 = x[n * 3 + 1], x2 = x[n * 3 + 2];
  float4 a0 = *(const float4*)&W0l[c];
  float4 a1 = *(const float4*)&W0l[HID + c];
  float4 a2 = *(const float4*)&W0l[2 * HID + c];
  float4 oa;
  oa.x = x0 * a0.x + x1 * a1.x + x2 * a2.x;
  oa.y = x0 * a0.y + x1 * a1.y + x2 * a2.y;
  oa.z = x0 * a0.z + x1 * a1.z + x2 * a2.z;
  oa.w = x0 * a0.w + x1 * a1.w + x2 * a2.w;
  *(float4*)&A[(size_t)n * HID + c] = oa;
  float4 b0 = *(const float4*)&W0r[c];
  float4 b1 = *(const float4*)&W0r[HID + c];
  float4 b2 = *(const float4*)&W0r[2 * HID + c];
  float4 ob;
  ob.x = x0 * b0.x + x1 * b1.x + x2 * b2.x;
  ob.y = x0 * b0.y + x1 * b1.y + x2 * b2.y;
  ob.z = x0 * b0.z + x1 * b1.z + x2 * b2.z;
  ob.w = x0 * b0.w + x1 * b1.w + x2 * b2.w;
  *(float4*)&B[(size_t)n * HID + c] = ob;
}

// ---------------- GEMM: A = BN(relu(H)) @ W, BN params from raw sums ----------------

__global__ __launch_bounds__(256) void k_gemm(const float* __restrict__ H,
    const float* __restrict__ W, const float* __restrict__ cs,
    const float* __restrict__ g, const float* __restrict__ b,
    float* __restrict__ A) {
  extern __shared__ float lds[];
  float* hs = lds;              // 32 x 128
  float* Ws = lds + 32 * HID;   // 128 x 128
  int t = threadIdx.x;
  for (int i = t * 4; i < HID * HID; i += 1024)
    *(float4*)&Ws[i] = *(const float4*)&W[i];
  int rl = t >> 5;
  int c4 = (t & 31) * 4;
  float4 s1v = *(const float4*)&cs[c4];
  float4 s2v = *(const float4*)&cs[HID + c4];
  float4 gv  = *(const float4*)&g[c4];
  float4 bv  = *(const float4*)&b[c4];
  float4 sc, sh;
  {
    float mu, var;
    mu = s1v.x * (1.f / NN); var = fmaxf(s2v.x * (1.f / NN) - mu * mu, 0.f);
    sc.x = gv.x * rsqrtf(var + BNEPS); sh.x = bv.x - mu * sc.x;
    mu = s1v.y * (1.f / NN); var = fmaxf(s2v.y * (1.f / NN) - mu * mu, 0.f);
    sc.y = gv.y * rsqrtf(var + BNEPS); sh.y = bv.y - mu * sc.y;
    mu = s1v.z * (1.f / NN); var = fmaxf(s2v.z * (1.f / NN) - mu * mu, 0.f);
    sc.z = gv.z * rsqrtf(var + BNEPS); sh.z = bv.z - mu * sc.z;
    mu = s1v.w * (1.f / NN); var = fmaxf(s2v.w * (1.f / NN) - mu * mu, 0.f);
    sc.w = gv.w * rsqrtf(var + BNEPS); sh.w = bv.w - mu * sc.w;
  }
  for (int r0 = blockIdx.x * 32; r0 < NN; r0 += gridDim.x * 32) {
    __syncthreads();
#pragma unroll
    for (int j = 0; j < 4; ++j) {
      int row = rl + 8 * j;
      int r = r0 + row;
      float4 hv = make_float4(0.f, 0.f, 0.f, 0.f);
      if (r < NN) hv = *(const float4*)&H[(size_t)r * HID + c4];
      float4 o;
      o.x = fmaxf(hv.x, 0.f) * sc.x + sh.x;
      o.y = fmaxf(hv.y, 0.f) * sc.y + sh.y;
      o.z = fmaxf(hv.z, 0.f) * sc.z + sh.z;
      o.w = fmaxf(hv.w, 0.f) * sc.w + sh.w;
      *(float4*)&hs[row * HID + c4] = o;
    }
    __syncthreads();
    float4 a0 = make_float4(0.f, 0.f, 0.f, 0.f);
    float4 a1 = a0, a2 = a0, a3 = a0;
#pragma unroll 4
    for (int k = 0; k < HID; ++k) {
      float4 wv = *(float4*)&Ws[k * HID + c4];
      float h0 = hs[(rl + 0) * HID + k];
      float h1 = hs[(rl + 8) * HID + k];
      float h2 = hs[(rl + 16) * HID + k];
      float h3 = hs[(rl + 24) * HID + k];
      a0.x += h0 * wv.x; a0.y += h0 * wv.y; a0.z += h0 * wv.z; a0.w += h0 * wv.w;
      a1.x += h1 * wv.x; a1.y += h1 * wv.y; a1.z += h1 * wv.z; a1.w += h1 * wv.w;
      a2.x += h2 * wv.x; a2.y += h2 * wv.y; a2.z += h2 * wv.z; a2.w += h2 * wv.w;
      a3.x += h3 * wv.x; a3.y += h3 * wv.y; a3.z += h3 * wv.z; a3.w += h3 * wv.w;
    }
    int r = r0 + rl;
    if (r < NN)      *(float4*)&A[(size_t)(r)*HID + c4] = a0;
    if (r + 8 < NN)  *(float4*)&A[(size_t)(r + 8) * HID + c4] = a1;
    if (r + 16 < NN) *(float4*)&A[(size_t)(r + 16) * HID + c4] = a2;
    if (r + 24 < NN) *(float4*)&A[(size_t)(r + 24) * HID + c4] = a3;
  }
}

// ---- GATv2 edge phase v4: 4x-unrolled circular pipeline, clamp-free, DPP reduce ----

__global__ __launch_bounds__(256) void k_edge(const float* __restrict__ XL,
    const float* __restrict__ XR, const float4* __restrict__ edat,
    const int* __restrict__ rowp, const float* __restrict__ We,
    const float* __restrict__ att, const float* __restrict__ bias,
    float* __restrict__ H) {
  __shared__ float WeS[3 * HID];
  int t = threadIdx.x;
  for (int i = t; i < 3 * HID; i += 256) WeS[i] = We[i];
  __syncthreads();
  int lane = t & 63;
  int n = blockIdx.x * 4 + (t >> 6);
  int c = lane * 2;
  float2 xr = *(const float2*)&XR[(size_t)n * HID + c];
  float2 av = *(const float2*)&att[c];
  av.x *= 1.44269504f;  // fold log2(e) into att
  av.y *= 1.44269504f;
  float w00 = WeS[c], w01 = WeS[c + 1];
  float w10 = WeS[HID + c], w11 = WeS[HID + c + 1];
  float w20 = WeS[2 * HID + c], w21 = WeS[2 * HID + c + 1];
  int beg = __builtin_amdgcn_readfirstlane(rowp[n]);
  int end = __builtin_amdgcn_readfirstlane(rowp[n + 1]);
  const float* XLc = XL + c;

  // prologue: fill circular buffers (pads make all loads in-bounds)
  float4 e0 = edat[beg], e1 = edat[beg + 1], e2 = edat[beg + 2], e3 = edat[beg + 3];
  float2 x0 = *(const float2*)&XLc[(size_t)__float_as_int(e0.x) << 7];
  float2 x1 = *(const float2*)&XLc[(size_t)__float_as_int(e1.x) << 7];
  float2 x2, x3;
  float m = -1e30f, s = 0.f, ax = 0.f, ay = 0.f;

#define EDGE_BODY(ED, XS)                                                         \
  {                                                                               \
    float u0 = __builtin_fmaf(ED.w, w20, __builtin_fmaf(ED.z, w10,                \
               __builtin_fmaf(ED.y, w00, XS.x + xr.x)));                          \
    float u1 = __builtin_fmaf(ED.w, w21, __builtin_fmaf(ED.z, w11,                \
               __builtin_fmaf(ED.y, w01, XS.y + xr.y)));                          \
    float v0 = fmaxf(u0, 0.2f * u0);                                              \
    float v1 = fmaxf(u1, 0.2f * u1);                                              \
    float part = wave_sum_u(__builtin_fmaf(v1, av.y, v0 * av.x));                 \
    if (part <= m) {                                                              \
      float p = exp2f(part - m);                                                  \
      s += p;                                                                     \
      ax = __builtin_fmaf(p, XS.x, ax);                                           \
      ay = __builtin_fmaf(p, XS.y, ay);                                           \
    } else {                                                                      \
      float scl = exp2f(m - part);                                                \
      s = __builtin_fmaf(s, scl, 1.f);                                            \
      ax = __builtin_fmaf(ax, scl, XS.x);                                         \
      ay = __builtin_fmaf(ay, scl, XS.y);                                         \
      m = part;                                                                   \
    }                                                                             \
  }

  int i = beg;
  for (; i + 4 <= end; i += 4) {
    x2 = *(const float2*)&XLc[(size_t)__float_as_int(e2.x) << 7];
    EDGE_BODY(e0, x0);
    e0 = edat[i + 4];
    x3 = *(const float2*)&XLc[(size_t)__float_as_int(e3.x) << 7];
    EDGE_BODY(e1, x1);
    e1 = edat[i + 5];
    x0 = *(const float2*)&XLc[(size_t)__float_as_int(e0.x) << 7];
    EDGE_BODY(e2, x2);
    e2 = edat[i + 6];
    x1 = *(const float2*)&XLc[(size_t)__float_as_int(e1.x) << 7];
    EDGE_BODY(e3, x3);
    e3 = edat[i + 7];
  }
  int r = end - i;
  if (r > 0) EDGE_BODY(e0, x0);
  if (r > 1) EDGE_BODY(e1, x1);
  if (r > 2) {
    x2 = *(const float2*)&XLc[(size_t)__float_as_int(e2.x) << 7];
    EDGE_BODY(e2, x2);
  }
#undef EDGE_BODY

  float inv = 1.f / s;
  float2 bv = *(const float2*)&bias[c];
  float2 o;
  o.x = __builtin_fmaf(ax, inv, bv.x);
  o.y = __builtin_fmaf(ay, inv, bv.y);
  *(float2*)&H[(size_t)n * HID + c] = o;
}

// ---------------- BN stats (raw sums) ----------------

__global__ __launch_bounds__(128) void k_bnstats(const float* __restrict__ H,
                                                 float* __restrict__ cs) {
  int c = threadIdx.x;
  int chunk = (NN + gridDim.x - 1) / gridDim.x;
  int n0 = blockIdx.x * chunk, n1 = min(n0 + chunk, NN);
  if (n0 >= n1) return;
  float s1 = 0.f, s2 = 0.f;
  for (int n = n0; n < n1; ++n) {
    float v = fmaxf(H[(size_t)n * HID + c], 0.f);
    s1 += v; s2 += v * v;
  }
  atomicAdd(&cs[c], s1);
  atomicAdd(&cs[HID + c], s2);
}

// ---------------- pooling (segment_max over sorted batch), BN fused ----------------

__global__ __launch_bounds__(128) void k_pool(const float* __restrict__ H,
    const int* __restrict__ batch, const float* __restrict__ cs,
    const float* __restrict__ g, const float* __restrict__ b,
    unsigned* __restrict__ pooled) {
  int c = threadIdx.x;
  const int chunk = (NN + gridDim.x - 1) / gridDim.x;
  int n0 = blockIdx.x * chunk;
  int n1 = min(n0 + chunk, NN);
  if (n0 >= n1) return;
  float mu = cs[c] * (1.f / NN);
  float var = fmaxf(cs[HID + c] * (1.f / NN) - mu * mu, 0.f);
  float sc = g[c] * rsqrtf(var + BNEPS);
  float sh = b[c] - mu * sc;
  int curg = batch[n0];
  float vmax = -3.402823e38f;
  for (int n = n0; n < n1; ++n) {
    int gg = batch[n];
    if (gg != curg) {
      atomicMax(&pooled[curg * HID + c], fenc(vmax));
      curg = gg;
      vmax = -3.402823e38f;
    }
    float v = fmaxf(H[(size_t)n * HID + c], 0.f) * sc + sh;
    vmax = fmaxf(vmax, v);
  }
  atomicMax(&pooled[curg * HID + c], fenc(vmax));
}

// ---------------- FC head: one block per graph ----------------

__global__ __launch_bounds__(128) void k_fc(const unsigned* __restrict__ pooled,
    const float* __restrict__ W1, const float* __restrict__ b1,
    const float* __restrict__ W2, const float* __restrict__ b2,
    float* __restrict__ out) {
  __shared__ float P[HID];
  __shared__ float Z[HID];
  int g = blockIdx.x, c = threadIdx.x;
  unsigned k = pooled[g * HID + c];
  P[c] = (k & 0x80000000u) ? __uint_as_float(k ^ 0x80000000u) : __uint_as_float(~k);
  __syncthreads();
  float acc = b1[c];
  for (int kk = 0; kk < HID; ++kk) acc += P[kk] * W1[kk * HID + c];
  Z[c] = fmaxf(acc, 0.f);
  __syncthreads();
  if (c < 40) {
    float a2 = b2[c];
    for (int kk = 0; kk < HID; ++kk) a2 += Z[kk] * W2[kk * 40 + c];
    out[g * 40 + c] = a2;
  }
}

// ---------------- launch ----------------

extern "C" void kernel_launch(void* const* d_in, const int* in_sizes, int n_in,
                              void* d_out, int out_size, void* d_ws, size_t ws_size,
                              hipStream_t stream) {
  (void)in_sizes; (void)n_in; (void)out_size; (void)ws_size;
  const float* x     = (const float*)d_in[0];
  const float* eattr = (const float*)d_in[1];
  const int*   ei    = (const int*)d_in[2];
  const int*   batch = (const int*)d_in[3];
  const float* W0l   = (const float*)d_in[4];
  const float* W0r   = (const float*)d_in[5];
  const float* We0   = (const float*)d_in[6];
  const float* a0    = (const float*)d_in[7];
  const float* b0    = (const float*)d_in[8];
  const float* bn0g  = (const float*)d_in[9];
  const float* bn0b  = (const float*)d_in[10];
  const float* Wl    = (const float*)d_in[11];
  const float* Wel   = (const float*)d_in[12];
  const float* al    = (const float*)d_in[13];
  const float* bl    = (const float*)d_in[14];
  const float* bng   = (const float*)d_in[15];
  const float* bnb   = (const float*)d_in[16];
  const float* fc1W  = (const float*)d_in[17];
  const float* fc1b  = (const float*)d_in[18];
  const float* fc2W  = (const float*)d_in[19];
  const float* fc2b  = (const float*)d_in[20];
  float* out = (float*)d_out;

  char* ws = (char*)d_ws;
  float*  A    = (float*)(ws + 0);                 // 25,600,000
  float*  Bm   = (float*)(ws + 25600000);          // 25,600,000
  float4* edat = (float4*)(ws + 51200000);         // (850000+4)*16
  int*    rowp = (int*)(ws + 64800128);            // 50001*4
  char*   zb   = ws + 65000192;                    // zeroed region start
  int*    deg  = (int*)(zb + 0);                   // 200,000
  int*    fill = (int*)(zb + 200000);              // 200,000
  float*  cs   = (float*)(zb + 400000);            // 3*256*4 = 3,072
  unsigned* pooled = (unsigned*)(zb + 403072);     // 32*128*4 = 16,384
  int*    bsum = (int*)(zb + 419456);              // 64*4 = 256
  const size_t ZLEN = 419712;

  hipMemsetAsync(zb, 0, ZLEN, stream);

  // build CSR (dst-sorted) with self loops + mean edge_attr fill
  k_hist<<<(NE + 255) / 256, 256, 0, stream>>>(ei, deg);
  k_scanA<<<49, 1024, 0, stream>>>(deg, rowp, bsum);
  k_scanB<<<1, 64, 0, stream>>>(bsum, rowp, edat);
  k_scanC<<<49, 1024, 0, stream>>>(rowp, bsum);
  k_scatter<<<(NE + 255) / 256, 256, 0, stream>>>(ei, eattr, rowp, fill, edat);
  k_selfmean<<<(NN + 3) / 4, 256, 0, stream>>>(rowp, edat);

  const size_t GEMM_LDS = (size_t)(32 * HID + HID * HID) * 4;  // 81920 B

  // layer 0
  k_xform0<<<(NN * 32) / 256, 256, 0, stream>>>(x, W0l, W0r, A, Bm);
  k_edge<<<NN / 4, 256, 0, stream>>>(A, Bm, edat, rowp, We0, a0, b0, Bm);
  k_bnstats<<<2048, 128, 0, stream>>>(Bm, cs);

  // layer 1
  k_gemm<<<782, 256, GEMM_LDS, stream>>>(Bm, Wl, cs, bn0g, bn0b, A);
  k_edge<<<NN / 4, 256, 0, stream>>>(A, A, edat, rowp, Wel, al, bl, Bm);
  k_bnstats<<<2048, 128, 0, stream>>>(Bm, cs + 256);

  // layer 2
  k_gemm<<<782, 256, GEMM_LDS, stream>>>(Bm, Wl + 128 * 128, cs + 256, bng, bnb, A);
  k_edge<<<NN / 4, 256, 0, stream>>>(A, A, edat, rowp, Wel + 384, al + 128, bl + 128, Bm);
  k_bnstats<<<2048, 128, 0, stream>>>(Bm, cs + 512);

  // pool + FC head
  k_pool<<<2048, 128, 0, stream>>>(Bm, batch, cs + 512, bng + 128, bnb + 128, pooled);
  k_fc<<<NG, 128, 0, stream>>>(pooled, fc1W, fc1b, fc2W, fc2b, out);
}

// Round 7
// 559.675 us; speedup vs baseline: 1.6354x; 1.0421x over previous
//
#include <hip/hip_runtime.h>

#define NN 50000
#define NE 800000
#define NG 32
#define HID 128
#define BNEPS 1e-5f
#define NETOT (NE + NN)  // 850000, CSR total incl self loops

__device__ __forceinline__ unsigned fenc(float f) {
  unsigned u = __float_as_uint(f);
  return (u & 0x80000000u) ? ~u : (u | 0x80000000u);
}

// round-to-nearest-even f32 -> bf16 (as low 16 bits)
__device__ __forceinline__ unsigned bfr(float f) {
  unsigned u = __float_as_uint(f);
  return (u + 0x7fffu + ((u >> 16) & 1u)) >> 16;
}
__device__ __forceinline__ unsigned pack2(float a, float b) {
  return bfr(a) | (bfr(b) << 16);
}

// fused DPP add: x += dpp_move(x); masked-out rows add 0
#define DPPADD(x, ctrl, rmask)                                                   \
  (x) += __int_as_float(__builtin_amdgcn_update_dpp(0, __float_as_int(x),        \
                                                    (ctrl), (rmask), 0xf, true))

// wave64 sum -> uniform scalar (valid via readlane 63)
__device__ __forceinline__ float wave_sum_u(float x) {
  DPPADD(x, 0x111, 0xf);  // row_shr:1
  DPPADD(x, 0x112, 0xf);  // row_shr:2
  DPPADD(x, 0x114, 0xf);  // row_shr:4
  DPPADD(x, 0x118, 0xf);  // row_shr:8
  DPPADD(x, 0x142, 0xa);  // row_bcast:15 -> rows 1,3
  DPPADD(x, 0x143, 0xc);  // row_bcast:31 -> rows 2,3
  return __int_as_float(__builtin_amdgcn_readlane(__float_as_int(x), 63));
}

// ---------------- preprocessing ----------------

__global__ __launch_bounds__(256) void k_hist(const int* __restrict__ ei,
                                              int* __restrict__ deg) {
  int e = blockIdx.x * 256 + threadIdx.x;
  if (e >= NE) return;
  atomicAdd(&deg[ei[NE + e]], 1);
}

// hierarchical scan: A (per-block) -> B (block sums) -> C (add offsets)
__global__ __launch_bounds__(1024) void k_scanA(const int* __restrict__ deg,
                                                int* __restrict__ rowp,
                                                int* __restrict__ bsum) {
  __shared__ int wsum[16];
  int t = threadIdx.x, lane = t & 63, w = t >> 6;
  int i = blockIdx.x * 1024 + t;
  int v = (i < NN) ? (deg[i] + 1) : 0;  // +1 self loop
  int s = v;
#pragma unroll
  for (int off = 1; off < 64; off <<= 1) {
    int y = __shfl_up(s, off, 64);
    if (lane >= off) s += y;
  }
  if (lane == 63) wsum[w] = s;
  __syncthreads();
  if (t < 16) {
    int xv = wsum[t];
#pragma unroll
    for (int off = 1; off < 16; off <<= 1) {
      int y = __shfl_up(xv, off, 64);
      if (t >= off) xv += y;
    }
    wsum[t] = xv;
  }
  __syncthreads();
  int wexcl = (w == 0) ? 0 : wsum[w - 1];
  int incl = wexcl + s;
  if (i < NN) rowp[i] = incl - v;  // block-local exclusive
  if (t == 1023) bsum[blockIdx.x] = incl;
}

__global__ __launch_bounds__(64) void k_scanB(int* __restrict__ bsum,
                                              int* __restrict__ rowp,
                                              float4* __restrict__ edat) {
  int t = threadIdx.x;  // one wave; 49 block sums
  int v = (t < 49) ? bsum[t] : 0;
  int s = v;
#pragma unroll
  for (int off = 1; off < 64; off <<= 1) {
    int y = __shfl_up(s, off, 64);
    if (t >= off) s += y;
  }
  bsum[t] = s - v;                 // exclusive
  if (t == 48) rowp[NN] = s;       // total (== NETOT)
  if (t < 4) {                     // pad entries for clamp-free prefetch
    float4 z;
    z.x = __int_as_float(0); z.y = 0.f; z.z = 0.f; z.w = 0.f;
    edat[NETOT + t] = z;
  }
}

__global__ __launch_bounds__(1024) void k_scanC(int* __restrict__ rowp,
                                                const int* __restrict__ bsum) {
  int i = blockIdx.x * 1024 + threadIdx.x;
  if (i < NN) rowp[i] += bsum[blockIdx.x];
}

// scatter edges into dst-CSR order as packed {src_bits, e0, e1, e2}
__global__ __launch_bounds__(256) void k_scatter(const int* __restrict__ ei,
    const float* __restrict__ eattr, const int* __restrict__ rowp,
    int* __restrict__ fill, float4* __restrict__ edat) {
  int e = blockIdx.x * 256 + threadIdx.x;
  if (e >= NE) return;
  int d = ei[NE + e];
  int p = rowp[d] + atomicAdd(&fill[d], 1);
  float4 v;
  v.x = __int_as_float(ei[e]);
  v.y = eattr[e * 3 + 0];
  v.z = eattr[e * 3 + 1];
  v.w = eattr[e * 3 + 2];
  edat[p] = v;
}

// self-loop entry: mean of incoming edge attrs. one WAVE per node.
__global__ __launch_bounds__(256) void k_selfmean(const int* __restrict__ rowp,
                                                  float4* __restrict__ edat) {
  int n = blockIdx.x * 4 + (threadIdx.x >> 6);
  int lane = threadIdx.x & 63;
  if (n >= NN) return;
  int beg = rowp[n], endm1 = rowp[n + 1] - 1;
  float s0 = 0.f, s1 = 0.f, s2 = 0.f;
  for (int i = beg + lane; i < endm1; i += 64) {
    float4 v = edat[i];
    s0 += v.y; s1 += v.z; s2 += v.w;
  }
#pragma unroll
  for (int off = 32; off > 0; off >>= 1) {
    s0 += __shfl_xor(s0, off, 64);
    s1 += __shfl_xor(s1, off, 64);
    s2 += __shfl_xor(s2, off, 64);
  }
  if (lane == 0) {
    int cnt = endm1 - beg;
    float inv = cnt > 0 ? 1.f / (float)cnt : 0.f;
    float4 o;
    o.x = __int_as_float(n);
    o.y = s0 * inv; o.z = s1 * inv; o.w = s2 * inv;
    edat[endm1] = o;
  }
}

// ---------------- layer 0 input transform: A = x@W0l (bf16), B = x@W0r (bf16) ----------------

__global__ __launch_bounds__(256) void k_xform0(const float* __restrict__ x,
    const float* __restrict__ W0l, const float* __restrict__ W0r,
    unsigned* __restrict__ A, unsigned* __restrict__ B) {
  int t = blockIdx.x * 256 + threadIdx.x;
  int n = t >> 5;
  int c = (t & 31) * 4;
  if (n >= NN) return;
  float x0 = x[n * 3 + 0], x1 = x[n * 3 + 1], x2 = x[n * 3 + 2];
  float4 a0 = *(const float4*)&W0l[c];
  float4 a1 = *(const float4*)&W0l[HID + c];
  float4 a2 = *(const float4*)&W0l[2 * HID + c];
  float oax = x0 * a0.x + x1 * a1.x + x2 * a2.x;
  float oay = x0 * a0.y + x1 * a1.y + x2 * a2.y;
  float oaz = x0 * a0.z + x1 * a1.z + x2 * a2.z;
  float oaw = x0 * a0.w + x1 * a1.w + x2 * a2.w;
  uint2 pa;
  pa.x = pack2(oax, oay);
  pa.y = pack2(oaz, oaw);
  *(uint2*)&A[n * 64 + (c >> 1)] = pa;   // row stride = 64 uints (128 bf16)
  float4 b0 = *(const float4*)&W0r[c];
  float4 b1 = *(const float4*)&W0r[HID + c];
  float4 b2 = *(const float4*)&W0r[2 * HID + c];
  float obx = x0 * b0.x + x1 * b1.x + x2 * b2.x;
  float oby = x0 * b0.y + x1 * b1.y + x2 * b2.y;
  float obz = x0 * b0.z + x1 * b1.z + x2 * b2.z;
  float obw = x0 * b0.w + x1 * b1.w + x2 * b2.w;
  uint2 pb;
  pb.x = pack2(obx, oby);
  pb.y = pack2(obz, obw);
  *(uint2*)&B[n * 64 + (c >> 1)] = pb;
}

// ---------------- GEMM: A(bf16) = BN(relu(H)) @ W, BN params from raw sums ----------------

__global__ __launch_bounds__(256) void k_gemm(const float* __restrict__ H,
    const float* __restrict__ W, const float* __restrict__ cs,
    const float* __restrict__ g, const float* __restrict__ b,
    unsigned* __restrict__ A) {
  extern __shared__ float lds[];
  float* hs = lds;              // 32 x 128
  float* Ws = lds + 32 * HID;   // 128 x 128
  int t = threadIdx.x;
  for (int i = t * 4; i < HID * HID; i += 1024)
    *(float4*)&Ws[i] = *(const float4*)&W[i];
  int rl = t >> 5;
  int c4 = (t & 31) * 4;
  float4 s1v = *(const float4*)&cs[c4];
  float4 s2v = *(const float4*)&cs[HID + c4];
  float4 gv  = *(const float4*)&g[c4];
  float4 bv  = *(const float4*)&b[c4];
  float4 sc, sh;
  {
    float mu, var;
    mu = s1v.x * (1.f / NN); var = fmaxf(s2v.x * (1.f / NN) - mu * mu, 0.f);
    sc.x = gv.x * rsqrtf(var + BNEPS); sh.x = bv.x - mu * sc.x;
    mu = s1v.y * (1.f / NN); var = fmaxf(s2v.y * (1.f / NN) - mu * mu, 0.f);
    sc.y = gv.y * rsqrtf(var + BNEPS); sh.y = bv.y - mu * sc.y;
    mu = s1v.z * (1.f / NN); var = fmaxf(s2v.z * (1.f / NN) - mu * mu, 0.f);
    sc.z = gv.z * rsqrtf(var + BNEPS); sh.z = bv.z - mu * sc.z;
    mu = s1v.w * (1.f / NN); var = fmaxf(s2v.w * (1.f / NN) - mu * mu, 0.f);
    sc.w = gv.w * rsqrtf(var + BNEPS); sh.w = bv.w - mu * sc.w;
  }
  for (int r0 = blockIdx.x * 32; r0 < NN; r0 += gridDim.x * 32) {
    __syncthreads();
#pragma unroll
    for (int j = 0; j < 4; ++j) {
      int row = rl + 8 * j;
      int r = r0 + row;
      float4 hv = make_float4(0.f, 0.f, 0.f, 0.f);
      if (r < NN) hv = *(const float4*)&H[(size_t)r * HID + c4];
      float4 o;
      o.x = fmaxf(hv.x, 0.f) * sc.x + sh.x;
      o.y = fmaxf(hv.y, 0.f) * sc.y + sh.y;
      o.z = fmaxf(hv.z, 0.f) * sc.z + sh.z;
      o.w = fmaxf(hv.w, 0.f) * sc.w + sh.w;
      *(float4*)&hs[row * HID + c4] = o;
    }
    __syncthreads();
    float4 a0 = make_float4(0.f, 0.f, 0.f, 0.f);
    float4 a1 = a0, a2 = a0, a3 = a0;
#pragma unroll 4
    for (int k = 0; k < HID; ++k) {
      float4 wv = *(float4*)&Ws[k * HID + c4];
      float h0 = hs[(rl + 0) * HID + k];
      float h1 = hs[(rl + 8) * HID + k];
      float h2 = hs[(rl + 16) * HID + k];
      float h3 = hs[(rl + 24) * HID + k];
      a0.x += h0 * wv.x; a0.y += h0 * wv.y; a0.z += h0 * wv.z; a0.w += h0 * wv.w;
      a1.x += h1 * wv.x; a1.y += h1 * wv.y; a1.z += h1 * wv.z; a1.w += h1 * wv.w;
      a2.x += h2 * wv.x; a2.y += h2 * wv.y; a2.z += h2 * wv.z; a2.w += h2 * wv.w;
      a3.x += h3 * wv.x; a3.y += h3 * wv.y; a3.z += h3 * wv.z; a3.w += h3 * wv.w;
    }
    int r = r0 + rl;
    int ci = c4 >> 1;  // uint offset within the 64-uint row
    if (r < NN) {
      uint2 p; p.x = pack2(a0.x, a0.y); p.y = pack2(a0.z, a0.w);
      *(uint2*)&A[r * 64 + ci] = p;
    }
    if (r + 8 < NN) {
      uint2 p; p.x = pack2(a1.x, a1.y); p.y = pack2(a1.z, a1.w);
      *(uint2*)&A[(r + 8) * 64 + ci] = p;
    }
    if (r + 16 < NN) {
      uint2 p; p.x = pack2(a2.x, a2.y); p.y = pack2(a2.z, a2.w);
      *(uint2*)&A[(r + 16) * 64 + ci] = p;
    }
    if (r + 24 < NN) {
      uint2 p; p.x = pack2(a3.x, a3.y); p.y = pack2(a3.z, a3.w);
      *(uint2*)&A[(r + 24) * 64 + ci] = p;
    }
  }
}

// ---- GATv2 edge phase v5: bf16 gathers, 4x-unrolled circular pipeline, DPP reduce ----

__global__ __launch_bounds__(256) void k_edge(const unsigned* __restrict__ XL,
    const unsigned* __restrict__ XR, const float4* __restrict__ edat,
    const int* __restrict__ rowp, const float* __restrict__ We,
    const float* __restrict__ att, const float* __restrict__ bias,
    float* __restrict__ H) {
  __shared__ float WeS[3 * HID];
  int t = threadIdx.x;
  for (int i = t; i < 3 * HID; i += 256) WeS[i] = We[i];
  __syncthreads();
  int lane = t & 63;
  int n = blockIdx.x * 4 + (t >> 6);
  int c = lane * 2;
  unsigned urx = XR[n * 64 + lane];
  float xrx = __uint_as_float(urx << 16);
  float xry = __uint_as_float(urx & 0xffff0000u);
  float2 av = *(const float2*)&att[c];
  av.x *= 1.44269504f;  // fold log2(e) into att
  av.y *= 1.44269504f;
  float w00 = WeS[c], w01 = WeS[c + 1];
  float w10 = WeS[HID + c], w11 = WeS[HID + c + 1];
  float w20 = WeS[2 * HID + c], w21 = WeS[2 * HID + c + 1];
  int beg = __builtin_amdgcn_readfirstlane(rowp[n]);
  int end = __builtin_amdgcn_readfirstlane(rowp[n + 1]);
  const unsigned* XLu = XL + lane;  // lane's packed channel pair

  // prologue: fill circular buffers (pads make all loads in-bounds)
  float4 e0 = edat[beg], e1 = edat[beg + 1], e2 = edat[beg + 2], e3 = edat[beg + 3];
  unsigned x0 = XLu[(size_t)__float_as_int(e0.x) << 6];
  unsigned x1 = XLu[(size_t)__float_as_int(e1.x) << 6];
  unsigned x2, x3;
  float m = -1e30f, s = 0.f, ax = 0.f, ay = 0.f;

#define EDGE_BODY(ED, XU)                                                         \
  {                                                                               \
    float xsx = __uint_as_float((XU) << 16);                                      \
    float xsy = __uint_as_float((XU) & 0xffff0000u);                              \
    float u0 = __builtin_fmaf(ED.w, w20, __builtin_fmaf(ED.z, w10,                \
               __builtin_fmaf(ED.y, w00, xsx + xrx)));                            \
    float u1 = __builtin_fmaf(ED.w, w21, __builtin_fmaf(ED.z, w11,                \
               __builtin_fmaf(ED.y, w01, xsy + xry)));                            \
    float v0 = fmaxf(u0, 0.2f * u0);                                              \
    float v1 = fmaxf(u1, 0.2f * u1);                                              \
    float part = wave_sum_u(__builtin_fmaf(v1, av.y, v0 * av.x));                 \
    if (part <= m) {                                                              \
      float p = __builtin_amdgcn_exp2f(part - m);                                 \
      s += p;                                                                     \
      ax = __builtin_fmaf(p, xsx, ax);                                            \
      ay = __builtin_fmaf(p, xsy, ay);                                            \
    } else {                                                                      \
      float scl = __builtin_amdgcn_exp2f(m - part);                               \
      s = __builtin_fmaf(s, scl, 1.f);                                            \
      ax = __builtin_fmaf(ax, scl, xsx);                                          \
      ay = __builtin_fmaf(ay, scl, xsy);                                          \
      m = part;                                                                   \
    }                                                                             \
  }

  int i = beg;
  for (; i + 4 <= end; i += 4) {
    x2 = XLu[(size_t)__float_as_int(e2.x) << 6];
    EDGE_BODY(e0, x0);
    e0 = edat[i + 4];
    x3 = XLu[(size_t)__float_as_int(e3.x) << 6];
    EDGE_BODY(e1, x1);
    e1 = edat[i + 5];
    x0 = XLu[(size_t)__float_as_int(e0.x) << 6];
    EDGE_BODY(e2, x2);
    e2 = edat[i + 6];
    x1 = XLu[(size_t)__float_as_int(e1.x) << 6];
    EDGE_BODY(e3, x3);
    e3 = edat[i + 7];
  }
  int r = end - i;
  if (r > 0) EDGE_BODY(e0, x0);
  if (r > 1) EDGE_BODY(e1, x1);
  if (r > 2) {
    x2 = XLu[(size_t)__float_as_int(e2.x) << 6];
    EDGE_BODY(e2, x2);
  }
#undef EDGE_BODY

  float inv = 1.f / s;
  float2 bv = *(const float2*)&bias[c];
  float2 o;
  o.x = __builtin_fmaf(ax, inv, bv.x);
  o.y = __builtin_fmaf(ay, inv, bv.y);
  *(float2*)&H[(size_t)n * HID + c] = o;
}

// ---------------- BN stats (raw sums) ----------------

__global__ __launch_bounds__(128) void k_bnstats(const float* __restrict__ H,
                                                 float* __restrict__ cs) {
  int c = threadIdx.x;
  int chunk = (NN + gridDim.x - 1) / gridDim.x;
  int n0 = blockIdx.x * chunk, n1 = min(n0 + chunk, NN);
  if (n0 >= n1) return;
  float s1 = 0.f, s2 = 0.f;
  for (int n = n0; n < n1; ++n) {
    float v = fmaxf(H[(size_t)n * HID + c], 0.f);
    s1 += v; s2 += v * v;
  }
  atomicAdd(&cs[c], s1);
  atomicAdd(&cs[HID + c], s2);
}

// ---------------- pooling (segment_max over sorted batch), BN fused ----------------

__global__ __launch_bounds__(128) void k_pool(const float* __restrict__ H,
    const int* __restrict__ batch, const float* __restrict__ cs,
    const float* __restrict__ g, const float* __restrict__ b,
    unsigned* __restrict__ pooled) {
  int c = threadIdx.x;
  const int chunk = (NN + gridDim.x - 1) / gridDim.x;
  int n0 = blockIdx.x * chunk;
  int n1 = min(n0 + chunk, NN);
  if (n0 >= n1) return;
  float mu = cs[c] * (1.f / NN);
  float var = fmaxf(cs[HID + c] * (1.f / NN) - mu * mu, 0.f);
  float sc = g[c] * rsqrtf(var + BNEPS);
  float sh = b[c] - mu * sc;
  int curg = batch[n0];
  float vmax = -3.402823e38f;
  for (int n = n0; n < n1; ++n) {
    int gg = batch[n];
    if (gg != curg) {
      atomicMax(&pooled[curg * HID + c], fenc(vmax));
      curg = gg;
      vmax = -3.402823e38f;
    }
    float v = fmaxf(H[(size_t)n * HID + c], 0.f) * sc + sh;
    vmax = fmaxf(vmax, v);
  }
  atomicMax(&pooled[curg * HID + c], fenc(vmax));
}

// ---------------- FC head: one block per graph ----------------

__global__ __launch_bounds__(128) void k_fc(const unsigned* __restrict__ pooled,
    const float* __restrict__ W1, const float* __restrict__ b1,
    const float* __restrict__ W2, const float* __restrict__ b2,
    float* __restrict__ out) {
  __shared__ float P[HID];
  __shared__ float Z[HID];
  int g = blockIdx.x, c = threadIdx.x;
  unsigned k = pooled[g * HID + c];
  P[c] = (k & 0x80000000u) ? __uint_as_float(k ^ 0x80000000u) : __uint_as_float(~k);
  __syncthreads();
  float acc = b1[c];
  for (int kk = 0; kk < HID; ++kk) acc += P[kk] * W1[kk * HID + c];
  Z[c] = fmaxf(acc, 0.f);
  __syncthreads();
  if (c < 40) {
    float a2 = b2[c];
    for (int kk = 0; kk < HID; ++kk) a2 += Z[kk] * W2[kk * 40 + c];
    out[g * 40 + c] = a2;
  }
}

// ---------------- launch ----------------

extern "C" void kernel_launch(void* const* d_in, const int* in_sizes, int n_in,
                              void* d_out, int out_size, void* d_ws, size_t ws_size,
                              hipStream_t stream) {
  (void)in_sizes; (void)n_in; (void)out_size; (void)ws_size;
  const float* x     = (const float*)d_in[0];
  const float* eattr = (const float*)d_in[1];
  const int*   ei    = (const int*)d_in[2];
  const int*   batch = (const int*)d_in[3];
  const float* W0l   = (const float*)d_in[4];
  const float* W0r   = (const float*)d_in[5];
  const float* We0   = (const float*)d_in[6];
  const float* a0    = (const float*)d_in[7];
  const float* b0    = (const float*)d_in[8];
  const float* bn0g  = (const float*)d_in[9];
  const float* bn0b  = (const float*)d_in[10];
  const float* Wl    = (const float*)d_in[11];
  const float* Wel   = (const float*)d_in[12];
  const float* al    = (const float*)d_in[13];
  const float* bl    = (const float*)d_in[14];
  const float* bng   = (const float*)d_in[15];
  const float* bnb   = (const float*)d_in[16];
  const float* fc1W  = (const float*)d_in[17];
  const float* fc1b  = (const float*)d_in[18];
  const float* fc2W  = (const float*)d_in[19];
  const float* fc2b  = (const float*)d_in[20];
  float* out = (float*)d_out;

  char* ws = (char*)d_ws;
  float*    Bm   = (float*)(ws + 0);               // 25,600,000  (H, f32)
  unsigned* Abf  = (unsigned*)(ws + 25600000);     // 12,800,000  (bf16 features)
  unsigned* X0bf = (unsigned*)(ws + 38400000);     // 12,800,000  (layer0 XR, bf16)
  float4*   edat = (float4*)(ws + 51200000);       // (850000+4)*16 = 13,600,064
  int*      rowp = (int*)(ws + 64800128);          // 50001*4
  char*     zb   = ws + 65000192;                  // zeroed region start
  int*      deg  = (int*)(zb + 0);                 // 200,000
  int*      fill = (int*)(zb + 200000);            // 200,000
  float*    cs   = (float*)(zb + 400000);          // 3*256*4 = 3,072
  unsigned* pooled = (unsigned*)(zb + 403072);     // 32*128*4 = 16,384
  int*      bsum = (int*)(zb + 419456);            // 64*4 = 256
  const size_t ZLEN = 419712;

  hipMemsetAsync(zb, 0, ZLEN, stream);

  // build CSR (dst-sorted) with self loops + mean edge_attr fill
  k_hist<<<(NE + 255) / 256, 256, 0, stream>>>(ei, deg);
  k_scanA<<<49, 1024, 0, stream>>>(deg, rowp, bsum);
  k_scanB<<<1, 64, 0, stream>>>(bsum, rowp, edat);
  k_scanC<<<49, 1024, 0, stream>>>(rowp, bsum);
  k_scatter<<<(NE + 255) / 256, 256, 0, stream>>>(ei, eattr, rowp, fill, edat);
  k_selfmean<<<(NN + 3) / 4, 256, 0, stream>>>(rowp, edat);

  const size_t GEMM_LDS = (size_t)(32 * HID + HID * HID) * 4;  // 81920 B

  // layer 0
  k_xform0<<<(NN * 32) / 256, 256, 0, stream>>>(x, W0l, W0r, Abf, X0bf);
  k_edge<<<NN / 4, 256, 0, stream>>>(Abf, X0bf, edat, rowp, We0, a0, b0, Bm);
  k_bnstats<<<2048, 128, 0, stream>>>(Bm, cs);

  // layer 1
  k_gemm<<<782, 256, GEMM_LDS, stream>>>(Bm, Wl, cs, bn0g, bn0b, Abf);
  k_edge<<<NN / 4, 256, 0, stream>>>(Abf, Abf, edat, rowp, Wel, al, bl, Bm);
  k_bnstats<<<2048, 128, 0, stream>>>(Bm, cs + 256);

  // layer 2
  k_gemm<<<782, 256, GEMM_LDS, stream>>>(Bm, Wl + 128 * 128, cs + 256, bng, bnb, Abf);
  k_edge<<<NN / 4, 256, 0, stream>>>(Abf, Abf, edat, rowp, Wel + 384, al + 128, bl + 128, Bm);
  k_bnstats<<<2048, 128, 0, stream>>>(Bm, cs + 512);

  // pool + FC head
  k_pool<<<2048, 128, 0, stream>>>(Bm, batch, cs + 512, bng + 128, bnb + 128, pooled);
  k_fc<<<NG, 128, 0, stream>>>(pooled, fc1W, fc1b, fc2W, fc2b, out);
}

// Round 8
// 538.258 us; speedup vs baseline: 1.7005x; 1.0398x over previous
//
#include <hip/hip_runtime.h>

#define NN 50000
#define NE 800000
#define NG 32
#define HID 128
#define BNEPS 1e-5f
#define NETOT (NE + NN)  // 850000, CSR total incl self loops

__device__ __forceinline__ unsigned fenc(float f) {
  unsigned u = __float_as_uint(f);
  return (u & 0x80000000u) ? ~u : (u | 0x80000000u);
}

// round-to-nearest-even f32 -> bf16 (as low 16 bits)
__device__ __forceinline__ unsigned bfr(float f) {
  unsigned u = __float_as_uint(f);
  return (u + 0x7fffu + ((u >> 16) & 1u)) >> 16;
}
__device__ __forceinline__ unsigned pack2(float a, float b) {
  return bfr(a) | (bfr(b) << 16);
}
__device__ __forceinline__ float bf_lo(unsigned u) { return __uint_as_float(u << 16); }
__device__ __forceinline__ float bf_hi(unsigned u) { return __uint_as_float(u & 0xffff0000u); }

// fused DPP add: x += dpp_move(x); masked-out rows add 0
#define DPPADD(x, ctrl, rmask)                                                   \
  (x) += __int_as_float(__builtin_amdgcn_update_dpp(0, __float_as_int(x),        \
                                                    (ctrl), (rmask), 0xf, true))

// wave64 sum -> uniform scalar (valid via readlane 63)
__device__ __forceinline__ float wave_sum_u(float x) {
  DPPADD(x, 0x111, 0xf);  // row_shr:1
  DPPADD(x, 0x112, 0xf);  // row_shr:2
  DPPADD(x, 0x114, 0xf);  // row_shr:4
  DPPADD(x, 0x118, 0xf);  // row_shr:8
  DPPADD(x, 0x142, 0xa);  // row_bcast:15 -> rows 1,3
  DPPADD(x, 0x143, 0xc);  // row_bcast:31 -> rows 2,3
  return __int_as_float(__builtin_amdgcn_readlane(__float_as_int(x), 63));
}

// ---------------- preprocessing ----------------

__global__ __launch_bounds__(256) void k_hist(const int* __restrict__ ei,
                                              int* __restrict__ deg) {
  int e = blockIdx.x * 256 + threadIdx.x;
  if (e >= NE) return;
  atomicAdd(&deg[ei[NE + e]], 1);
}

// hierarchical scan: A (per-block) -> B (block sums) -> C (add offsets)
__global__ __launch_bounds__(1024) void k_scanA(const int* __restrict__ deg,
                                                int* __restrict__ rowp,
                                                int* __restrict__ bsum) {
  __shared__ int wsum[16];
  int t = threadIdx.x, lane = t & 63, w = t >> 6;
  int i = blockIdx.x * 1024 + t;
  int v = (i < NN) ? (deg[i] + 1) : 0;  // +1 self loop
  int s = v;
#pragma unroll
  for (int off = 1; off < 64; off <<= 1) {
    int y = __shfl_up(s, off, 64);
    if (lane >= off) s += y;
  }
  if (lane == 63) wsum[w] = s;
  __syncthreads();
  if (t < 16) {
    int xv = wsum[t];
#pragma unroll
    for (int off = 1; off < 16; off <<= 1) {
      int y = __shfl_up(xv, off, 64);
      if (t >= off) xv += y;
    }
    wsum[t] = xv;
  }
  __syncthreads();
  int wexcl = (w == 0) ? 0 : wsum[w - 1];
  int incl = wexcl + s;
  if (i < NN) rowp[i] = incl - v;  // block-local exclusive
  if (t == 1023) bsum[blockIdx.x] = incl;
}

__global__ __launch_bounds__(64) void k_scanB(int* __restrict__ bsum,
                                              int* __restrict__ rowp,
                                              uint2* __restrict__ edat) {
  int t = threadIdx.x;  // one wave; 49 block sums
  int v = (t < 49) ? bsum[t] : 0;
  int s = v;
#pragma unroll
  for (int off = 1; off < 64; off <<= 1) {
    int y = __shfl_up(s, off, 64);
    if (t >= off) s += y;
  }
  bsum[t] = s - v;                 // exclusive
  if (t == 48) rowp[NN] = s;       // total (== NETOT)
  if (t < 4) {                     // pad entries for clamp-free prefetch
    uint2 z; z.x = 0u; z.y = 0u;
    edat[NETOT + t] = z;
  }
}

__global__ __launch_bounds__(1024) void k_scanC(int* __restrict__ rowp,
                                                const int* __restrict__ bsum) {
  int i = blockIdx.x * 1024 + threadIdx.x;
  if (i < NN) rowp[i] += bsum[blockIdx.x];
}

// scatter edges into dst-CSR order, packed 8B: {src|e0bf<<16, e1bf|e2bf<<16}
__global__ __launch_bounds__(256) void k_scatter(const int* __restrict__ ei,
    const float* __restrict__ eattr, const int* __restrict__ rowp,
    int* __restrict__ fill, uint2* __restrict__ edat) {
  int e = blockIdx.x * 256 + threadIdx.x;
  if (e >= NE) return;
  int d = ei[NE + e];
  int p = rowp[d] + atomicAdd(&fill[d], 1);
  uint2 v;
  v.x = (unsigned)ei[e] | (bfr(eattr[e * 3 + 0]) << 16);
  v.y = bfr(eattr[e * 3 + 1]) | (bfr(eattr[e * 3 + 2]) << 16);
  edat[p] = v;
}

// self-loop entry: mean of incoming edge attrs. one WAVE per node.
__global__ __launch_bounds__(256) void k_selfmean(const int* __restrict__ rowp,
                                                  uint2* __restrict__ edat) {
  int n = blockIdx.x * 4 + (threadIdx.x >> 6);
  int lane = threadIdx.x & 63;
  if (n >= NN) return;
  int beg = rowp[n], endm1 = rowp[n + 1] - 1;
  float s0 = 0.f, s1 = 0.f, s2 = 0.f;
  for (int i = beg + lane; i < endm1; i += 64) {
    uint2 v = edat[i];
    s0 += bf_hi(v.x); s1 += bf_lo(v.y); s2 += bf_hi(v.y);
  }
#pragma unroll
  for (int off = 32; off > 0; off >>= 1) {
    s0 += __shfl_xor(s0, off, 64);
    s1 += __shfl_xor(s1, off, 64);
    s2 += __shfl_xor(s2, off, 64);
  }
  if (lane == 0) {
    int cnt = endm1 - beg;
    float inv = cnt > 0 ? 1.f / (float)cnt : 0.f;
    uint2 o;
    o.x = (unsigned)n | (bfr(s0 * inv) << 16);
    o.y = bfr(s1 * inv) | (bfr(s2 * inv) << 16);
    edat[endm1] = o;
  }
}

// ---------------- layer 0 input transform: A = x@W0l (bf16), B = x@W0r (bf16) ----------------

__global__ __launch_bounds__(256) void k_xform0(const float* __restrict__ x,
    const float* __restrict__ W0l, const float* __restrict__ W0r,
    unsigned* __restrict__ A, unsigned* __restrict__ B) {
  int t = blockIdx.x * 256 + threadIdx.x;
  int n = t >> 5;
  int c = (t & 31) * 4;
  if (n >= NN) return;
  float x0 = x[n * 3 + 0], x1 = x[n * 3 + 1], x2 = x[n * 3 + 2];
  float4 a0 = *(const float4*)&W0l[c];
  float4 a1 = *(const float4*)&W0l[HID + c];
  float4 a2 = *(const float4*)&W0l[2 * HID + c];
  float oax = x0 * a0.x + x1 * a1.x + x2 * a2.x;
  float oay = x0 * a0.y + x1 * a1.y + x2 * a2.y;
  float oaz = x0 * a0.z + x1 * a1.z + x2 * a2.z;
  float oaw = x0 * a0.w + x1 * a1.w + x2 * a2.w;
  uint2 pa;
  pa.x = pack2(oax, oay);
  pa.y = pack2(oaz, oaw);
  *(uint2*)&A[n * 64 + (c >> 1)] = pa;   // row stride = 64 uints (128 bf16)
  float4 b0 = *(const float4*)&W0r[c];
  float4 b1 = *(const float4*)&W0r[HID + c];
  float4 b2 = *(const float4*)&W0r[2 * HID + c];
  float obx = x0 * b0.x + x1 * b1.x + x2 * b2.x;
  float oby = x0 * b0.y + x1 * b1.y + x2 * b2.y;
  float obz = x0 * b0.z + x1 * b1.z + x2 * b2.z;
  float obw = x0 * b0.w + x1 * b1.w + x2 * b2.w;
  uint2 pb;
  pb.x = pack2(obx, oby);
  pb.y = pack2(obz, obw);
  *(uint2*)&B[n * 64 + (c >> 1)] = pb;
}

// ---------------- GEMM: A(bf16) = BN(relu(Hbf)) @ W, BN params from raw sums ----------------

__global__ __launch_bounds__(256) void k_gemm(const unsigned* __restrict__ Hb,
    const float* __restrict__ W, const float* __restrict__ cs,
    const float* __restrict__ g, const float* __restrict__ b,
    unsigned* __restrict__ A) {
  extern __shared__ float lds[];
  float* hs = lds;              // 32 x 128
  float* Ws = lds + 32 * HID;   // 128 x 128
  int t = threadIdx.x;
  for (int i = t * 4; i < HID * HID; i += 1024)
    *(float4*)&Ws[i] = *(const float4*)&W[i];
  int rl = t >> 5;
  int c4 = (t & 31) * 4;
  float4 s1v = *(const float4*)&cs[c4];
  float4 s2v = *(const float4*)&cs[HID + c4];
  float4 gv  = *(const float4*)&g[c4];
  float4 bv  = *(const float4*)&b[c4];
  float4 sc, sh;
  {
    float mu, var;
    mu = s1v.x * (1.f / NN); var = fmaxf(s2v.x * (1.f / NN) - mu * mu, 0.f);
    sc.x = gv.x * rsqrtf(var + BNEPS); sh.x = bv.x - mu * sc.x;
    mu = s1v.y * (1.f / NN); var = fmaxf(s2v.y * (1.f / NN) - mu * mu, 0.f);
    sc.y = gv.y * rsqrtf(var + BNEPS); sh.y = bv.y - mu * sc.y;
    mu = s1v.z * (1.f / NN); var = fmaxf(s2v.z * (1.f / NN) - mu * mu, 0.f);
    sc.z = gv.z * rsqrtf(var + BNEPS); sh.z = bv.z - mu * sc.z;
    mu = s1v.w * (1.f / NN); var = fmaxf(s2v.w * (1.f / NN) - mu * mu, 0.f);
    sc.w = gv.w * rsqrtf(var + BNEPS); sh.w = bv.w - mu * sc.w;
  }
  for (int r0 = blockIdx.x * 32; r0 < NN; r0 += gridDim.x * 32) {
    __syncthreads();
#pragma unroll
    for (int j = 0; j < 4; ++j) {
      int row = rl + 8 * j;
      int r = r0 + row;
      uint2 hv = make_uint2(0u, 0u);
      if (r < NN) hv = *(const uint2*)&Hb[r * 64 + (c4 >> 1)];
      float4 o;
      o.x = fmaxf(bf_lo(hv.x), 0.f) * sc.x + sh.x;
      o.y = fmaxf(bf_hi(hv.x), 0.f) * sc.y + sh.y;
      o.z = fmaxf(bf_lo(hv.y), 0.f) * sc.z + sh.z;
      o.w = fmaxf(bf_hi(hv.y), 0.f) * sc.w + sh.w;
      *(float4*)&hs[row * HID + c4] = o;
    }
    __syncthreads();
    float4 a0 = make_float4(0.f, 0.f, 0.f, 0.f);
    float4 a1 = a0, a2 = a0, a3 = a0;
#pragma unroll 4
    for (int k = 0; k < HID; ++k) {
      float4 wv = *(float4*)&Ws[k * HID + c4];
      float h0 = hs[(rl + 0) * HID + k];
      float h1 = hs[(rl + 8) * HID + k];
      float h2 = hs[(rl + 16) * HID + k];
      float h3 = hs[(rl + 24) * HID + k];
      a0.x += h0 * wv.x; a0.y += h0 * wv.y; a0.z += h0 * wv.z; a0.w += h0 * wv.w;
      a1.x += h1 * wv.x; a1.y += h1 * wv.y; a1.z += h1 * wv.z; a1.w += h1 * wv.w;
      a2.x += h2 * wv.x; a2.y += h2 * wv.y; a2.z += h2 * wv.z; a2.w += h2 * wv.w;
      a3.x += h3 * wv.x; a3.y += h3 * wv.y; a3.z += h3 * wv.z; a3.w += h3 * wv.w;
    }
    int r = r0 + rl;
    int ci = c4 >> 1;  // uint offset within the 64-uint row
    if (r < NN) {
      uint2 p; p.x = pack2(a0.x, a0.y); p.y = pack2(a0.z, a0.w);
      *(uint2*)&A[r * 64 + ci] = p;
    }
    if (r + 8 < NN) {
      uint2 p; p.x = pack2(a1.x, a1.y); p.y = pack2(a1.z, a1.w);
      *(uint2*)&A[(r + 8) * 64 + ci] = p;
    }
    if (r + 16 < NN) {
      uint2 p; p.x = pack2(a2.x, a2.y); p.y = pack2(a2.z, a2.w);
      *(uint2*)&A[(r + 16) * 64 + ci] = p;
    }
    if (r + 24 < NN) {
      uint2 p; p.x = pack2(a3.x, a3.y); p.y = pack2(a3.z, a3.w);
      *(uint2*)&A[(r + 24) * 64 + ci] = p;
    }
  }
}

// ---- GATv2 edge phase v6: 8B edat, bf16 gathers, bf16 H out, 4x circular pipeline ----

__global__ __launch_bounds__(256) void k_edge(const unsigned* __restrict__ XL,
    const unsigned* __restrict__ XR, const uint2* __restrict__ edat,
    const int* __restrict__ rowp, const float* __restrict__ We,
    const float* __restrict__ att, const float* __restrict__ bias,
    unsigned* __restrict__ Hb) {
  __shared__ float WeS[3 * HID];
  int t = threadIdx.x;
  for (int i = t; i < 3 * HID; i += 256) WeS[i] = We[i];
  __syncthreads();
  int lane = t & 63;
  int n = blockIdx.x * 4 + (t >> 6);
  int c = lane * 2;
  unsigned urx = XR[n * 64 + lane];
  float xrx = bf_lo(urx);
  float xry = bf_hi(urx);
  float2 av = *(const float2*)&att[c];
  av.x *= 1.44269504f;  // fold log2(e) into att
  av.y *= 1.44269504f;
  float w00 = WeS[c], w01 = WeS[c + 1];
  float w10 = WeS[HID + c], w11 = WeS[HID + c + 1];
  float w20 = WeS[2 * HID + c], w21 = WeS[2 * HID + c + 1];
  int beg = __builtin_amdgcn_readfirstlane(rowp[n]);
  int end = __builtin_amdgcn_readfirstlane(rowp[n + 1]);
  const unsigned* XLu = XL + lane;  // lane's packed channel pair

  // prologue: fill circular buffers (pads make all loads in-bounds)
  uint2 e0 = edat[beg], e1 = edat[beg + 1], e2 = edat[beg + 2], e3 = edat[beg + 3];
  unsigned x0 = XLu[(e0.x & 0xffffu) << 6];
  unsigned x1 = XLu[(e1.x & 0xffffu) << 6];
  unsigned x2, x3;
  float m = -1e30f, s = 0.f, ax = 0.f, ay = 0.f;

#define EDGE_BODY(ED, XU)                                                         \
  {                                                                               \
    float xsx = bf_lo(XU);                                                        \
    float xsy = bf_hi(XU);                                                        \
    float ea0 = bf_hi(ED.x);                                                      \
    float ea1 = bf_lo(ED.y);                                                      \
    float ea2 = bf_hi(ED.y);                                                      \
    float u0 = __builtin_fmaf(ea2, w20, __builtin_fmaf(ea1, w10,                  \
               __builtin_fmaf(ea0, w00, xsx + xrx)));                             \
    float u1 = __builtin_fmaf(ea2, w21, __builtin_fmaf(ea1, w11,                  \
               __builtin_fmaf(ea0, w01, xsy + xry)));                             \
    float v0 = fmaxf(u0, 0.2f * u0);                                              \
    float v1 = fmaxf(u1, 0.2f * u1);                                              \
    float part = wave_sum_u(__builtin_fmaf(v1, av.y, v0 * av.x));                 \
    if (part <= m) {                                                              \
      float p = __builtin_amdgcn_exp2f(part - m);                                 \
      s += p;                                                                     \
      ax = __builtin_fmaf(p, xsx, ax);                                            \
      ay = __builtin_fmaf(p, xsy, ay);                                            \
    } else {                                                                      \
      float scl = __builtin_amdgcn_exp2f(m - part);                               \
      s = __builtin_fmaf(s, scl, 1.f);                                            \
      ax = __builtin_fmaf(ax, scl, xsx);                                          \
      ay = __builtin_fmaf(ay, scl, xsy);                                          \
      m = part;                                                                   \
    }                                                                             \
  }

  int i = beg;
  for (; i + 4 <= end; i += 4) {
    x2 = XLu[(e2.x & 0xffffu) << 6];
    EDGE_BODY(e0, x0);
    e0 = edat[i + 4];
    x3 = XLu[(e3.x & 0xffffu) << 6];
    EDGE_BODY(e1, x1);
    e1 = edat[i + 5];
    x0 = XLu[(e0.x & 0xffffu) << 6];
    EDGE_BODY(e2, x2);
    e2 = edat[i + 6];
    x1 = XLu[(e1.x & 0xffffu) << 6];
    EDGE_BODY(e3, x3);
    e3 = edat[i + 7];
  }
  int r = end - i;
  if (r > 0) EDGE_BODY(e0, x0);
  if (r > 1) EDGE_BODY(e1, x1);
  if (r > 2) {
    x2 = XLu[(e2.x & 0xffffu) << 6];
    EDGE_BODY(e2, x2);
  }
#undef EDGE_BODY

  float inv = 1.f / s;
  float2 bv = *(const float2*)&bias[c];
  float ox = __builtin_fmaf(ax, inv, bv.x);
  float oy = __builtin_fmaf(ay, inv, bv.y);
  Hb[n * 64 + lane] = pack2(ox, oy);
}

// ---------------- BN stats (raw sums) from bf16 H ----------------

__global__ __launch_bounds__(128) void k_bnstats(const unsigned* __restrict__ Hb,
                                                 float* __restrict__ cs) {
  int c = threadIdx.x;
  int ui = c >> 1;
  bool hi = c & 1;
  int chunk = (NN + gridDim.x - 1) / gridDim.x;
  int n0 = blockIdx.x * chunk, n1 = min(n0 + chunk, NN);
  if (n0 >= n1) return;
  float s1 = 0.f, s2 = 0.f;
  for (int n = n0; n < n1; ++n) {
    unsigned u = Hb[n * 64 + ui];
    float v = hi ? bf_hi(u) : bf_lo(u);
    v = fmaxf(v, 0.f);
    s1 += v; s2 += v * v;
  }
  atomicAdd(&cs[c], s1);
  atomicAdd(&cs[HID + c], s2);
}

// ---------------- pooling (segment_max over sorted batch), BN fused ----------------

__global__ __launch_bounds__(128) void k_pool(const unsigned* __restrict__ Hb,
    const int* __restrict__ batch, const float* __restrict__ cs,
    const float* __restrict__ g, const float* __restrict__ b,
    unsigned* __restrict__ pooled) {
  int c = threadIdx.x;
  int ui = c >> 1;
  bool hi = c & 1;
  const int chunk = (NN + gridDim.x - 1) / gridDim.x;
  int n0 = blockIdx.x * chunk;
  int n1 = min(n0 + chunk, NN);
  if (n0 >= n1) return;
  float mu = cs[c] * (1.f / NN);
  float var = fmaxf(cs[HID + c] * (1.f / NN) - mu * mu, 0.f);
  float sc = g[c] * rsqrtf(var + BNEPS);
  float sh = b[c] - mu * sc;
  int curg = batch[n0];
  float vmax = -3.402823e38f;
  for (int n = n0; n < n1; ++n) {
    int gg = batch[n];
    if (gg != curg) {
      atomicMax(&pooled[curg * HID + c], fenc(vmax));
      curg = gg;
      vmax = -3.402823e38f;
    }
    unsigned u = Hb[n * 64 + ui];
    float v = hi ? bf_hi(u) : bf_lo(u);
    v = fmaxf(v, 0.f) * sc + sh;
    vmax = fmaxf(vmax, v);
  }
  atomicMax(&pooled[curg * HID + c], fenc(vmax));
}

// ---------------- FC head: one block per graph ----------------

__global__ __launch_bounds__(128) void k_fc(const unsigned* __restrict__ pooled,
    const float* __restrict__ W1, const float* __restrict__ b1,
    const float* __restrict__ W2, const float* __restrict__ b2,
    float* __restrict__ out) {
  __shared__ float P[HID];
  __shared__ float Z[HID];
  int g = blockIdx.x, c = threadIdx.x;
  unsigned k = pooled[g * HID + c];
  P[c] = (k & 0x80000000u) ? __uint_as_float(k ^ 0x80000000u) : __uint_as_float(~k);
  __syncthreads();
  float acc = b1[c];
  for (int kk = 0; kk < HID; ++kk) acc += P[kk] * W1[kk * HID + c];
  Z[c] = fmaxf(acc, 0.f);
  __syncthreads();
  if (c < 40) {
    float a2 = b2[c];
    for (int kk = 0; kk < HID; ++kk) a2 += Z[kk] * W2[kk * 40 + c];
    out[g * 40 + c] = a2;
  }
}

// ---------------- launch ----------------

extern "C" void kernel_launch(void* const* d_in, const int* in_sizes, int n_in,
                              void* d_out, int out_size, void* d_ws, size_t ws_size,
                              hipStream_t stream) {
  (void)in_sizes; (void)n_in; (void)out_size; (void)ws_size;
  const float* x     = (const float*)d_in[0];
  const float* eattr = (const float*)d_in[1];
  const int*   ei    = (const int*)d_in[2];
  const int*   batch = (const int*)d_in[3];
  const float* W0l   = (const float*)d_in[4];
  const float* W0r   = (const float*)d_in[5];
  const float* We0   = (const float*)d_in[6];
  const float* a0    = (const float*)d_in[7];
  const float* b0    = (const float*)d_in[8];
  const float* bn0g  = (const float*)d_in[9];
  const float* bn0b  = (const float*)d_in[10];
  const float* Wl    = (const float*)d_in[11];
  const float* Wel   = (const float*)d_in[12];
  const float* al    = (const float*)d_in[13];
  const float* bl    = (const float*)d_in[14];
  const float* bng   = (const float*)d_in[15];
  const float* bnb   = (const float*)d_in[16];
  const float* fc1W  = (const float*)d_in[17];
  const float* fc1b  = (const float*)d_in[18];
  const float* fc2W  = (const float*)d_in[19];
  const float* fc2b  = (const float*)d_in[20];
  float* out = (float*)d_out;

  char* ws = (char*)d_ws;
  unsigned* Hbf  = (unsigned*)(ws + 0);            // 12,800,000  (bf16 H)
  unsigned* Abf  = (unsigned*)(ws + 12800000);     // 12,800,000  (bf16 features)
  unsigned* X0bf = (unsigned*)(ws + 25600000);     // 12,800,000  (layer0 XR, bf16)
  uint2*    edat = (uint2*)(ws + 38400000);        // (850000+4)*8 = 6,800,032
  int*      rowp = (int*)(ws + 45200064);          // 50001*4
  char*     zb   = ws + 45400128;                  // zeroed region start
  int*      deg  = (int*)(zb + 0);                 // 200,000
  int*      fill = (int*)(zb + 200000);            // 200,000
  float*    cs   = (float*)(zb + 400000);          // 3*256*4 = 3,072
  unsigned* pooled = (unsigned*)(zb + 403072);     // 32*128*4 = 16,384
  int*      bsum = (int*)(zb + 419456);            // 64*4 = 256
  const size_t ZLEN = 419712;

  hipMemsetAsync(zb, 0, ZLEN, stream);

  // build CSR (dst-sorted) with self loops + mean edge_attr fill
  k_hist<<<(NE + 255) / 256, 256, 0, stream>>>(ei, deg);
  k_scanA<<<49, 1024, 0, stream>>>(deg, rowp, bsum);
  k_scanB<<<1, 64, 0, stream>>>(bsum, rowp, edat);
  k_scanC<<<49, 1024, 0, stream>>>(rowp, bsum);
  k_scatter<<<(NE + 255) / 256, 256, 0, stream>>>(ei, eattr, rowp, fill, edat);
  k_selfmean<<<(NN + 3) / 4, 256, 0, stream>>>(rowp, edat);

  const size_t GEMM_LDS = (size_t)(32 * HID + HID * HID) * 4;  // 81920 B

  // layer 0
  k_xform0<<<(NN * 32) / 256, 256, 0, stream>>>(x, W0l, W0r, Abf, X0bf);
  k_edge<<<NN / 4, 256, 0, stream>>>(Abf, X0bf, edat, rowp, We0, a0, b0, Hbf);
  k_bnstats<<<2048, 128, 0, stream>>>(Hbf, cs);

  // layer 1
  k_gemm<<<782, 256, GEMM_LDS, stream>>>(Hbf, Wl, cs, bn0g, bn0b, Abf);
  k_edge<<<NN / 4, 256, 0, stream>>>(Abf, Abf, edat, rowp, Wel, al, bl, Hbf);
  k_bnstats<<<2048, 128, 0, stream>>>(Hbf, cs + 256);

  // layer 2
  k_gemm<<<782, 256, GEMM_LDS, stream>>>(Hbf, Wl + 128 * 128, cs + 256, bng, bnb, Abf);
  k_edge<<<NN / 4, 256, 0, stream>>>(Abf, Abf, edat, rowp, Wel + 384, al + 128, bl + 128, Hbf);
  k_bnstats<<<2048, 128, 0, stream>>>(Hbf, cs + 512);

  // pool + FC head
  k_pool<<<2048, 128, 0, stream>>>(Hbf, batch, cs + 512, bng + 128, bnb + 128, pooled);
  k_fc<<<NG, 128, 0, stream>>>(pooled, fc1W, fc1b, fc2W, fc2b, out);
}

// Round 9
// 514.112 us; speedup vs baseline: 1.7803x; 1.0470x over previous
//
#include <hip/hip_runtime.h>

#define NN 50000
#define NE 800000
#define NG 32
#define HID 128
#define BNEPS 1e-5f
#define NETOT (NE + NN)  // 850000, CSR total incl self loops

__device__ __forceinline__ unsigned fenc(float f) {
  unsigned u = __float_as_uint(f);
  return (u & 0x80000000u) ? ~u : (u | 0x80000000u);
}

// round-to-nearest-even f32 -> bf16 (as low 16 bits)
__device__ __forceinline__ unsigned bfr(float f) {
  unsigned u = __float_as_uint(f);
  return (u + 0x7fffu + ((u >> 16) & 1u)) >> 16;
}
__device__ __forceinline__ unsigned pack2(float a, float b) {
  return bfr(a) | (bfr(b) << 16);
}
__device__ __forceinline__ float bf_lo(unsigned u) { return __uint_as_float(u << 16); }
__device__ __forceinline__ float bf_hi(unsigned u) { return __uint_as_float(u & 0xffff0000u); }

// fused DPP add: x += dpp_move(x); masked-out rows add 0
#define DPPADD(x, ctrl, rmask)                                                   \
  (x) += __int_as_float(__builtin_amdgcn_update_dpp(0, __float_as_int(x),        \
                                                    (ctrl), (rmask), 0xf, true))

// ---------------- preprocessing ----------------

// degree histogram; also records each edge's position within its dst bucket
__global__ __launch_bounds__(256) void k_hist(const int* __restrict__ ei,
                                              int* __restrict__ deg,
                                              int* __restrict__ pos) {
  int e = blockIdx.x * 256 + threadIdx.x;
  if (e >= NE) return;
  pos[e] = atomicAdd(&deg[ei[NE + e]], 1);
}

// hierarchical scan: A (per-block) -> B (block sums) -> C (add offsets)
__global__ __launch_bounds__(1024) void k_scanA(const int* __restrict__ deg,
                                                int* __restrict__ rowp,
                                                int* __restrict__ bsum) {
  __shared__ int wsum[16];
  int t = threadIdx.x, lane = t & 63, w = t >> 6;
  int i = blockIdx.x * 1024 + t;
  int v = (i < NN) ? (deg[i] + 1) : 0;  // +1 self loop
  int s = v;
#pragma unroll
  for (int off = 1; off < 64; off <<= 1) {
    int y = __shfl_up(s, off, 64);
    if (lane >= off) s += y;
  }
  if (lane == 63) wsum[w] = s;
  __syncthreads();
  if (t < 16) {
    int xv = wsum[t];
#pragma unroll
    for (int off = 1; off < 16; off <<= 1) {
      int y = __shfl_up(xv, off, 64);
      if (t >= off) xv += y;
    }
    wsum[t] = xv;
  }
  __syncthreads();
  int wexcl = (w == 0) ? 0 : wsum[w - 1];
  int incl = wexcl + s;
  if (i < NN) rowp[i] = incl - v;  // block-local exclusive
  if (t == 1023) bsum[blockIdx.x] = incl;
}

__global__ __launch_bounds__(64) void k_scanB(int* __restrict__ bsum,
                                              int* __restrict__ rowp,
                                              uint2* __restrict__ edat) {
  int t = threadIdx.x;  // one wave; 49 block sums
  int v = (t < 49) ? bsum[t] : 0;
  int s = v;
#pragma unroll
  for (int off = 1; off < 64; off <<= 1) {
    int y = __shfl_up(s, off, 64);
    if (t >= off) s += y;
  }
  bsum[t] = s - v;                 // exclusive
  if (t == 48) rowp[NN] = s;       // total (== NETOT)
  if (t < 4) {                     // pad entries (unused after clamping, harmless)
    uint2 z; z.x = 0u; z.y = 0u;
    edat[NETOT + t] = z;
  }
}

__global__ __launch_bounds__(1024) void k_scanC(int* __restrict__ rowp,
                                                const int* __restrict__ bsum) {
  int i = blockIdx.x * 1024 + threadIdx.x;
  if (i < NN) rowp[i] += bsum[blockIdx.x];
}

// scatter edges into dst-CSR order (atomic-free; position from k_hist)
__global__ __launch_bounds__(256) void k_scatter(const int* __restrict__ ei,
    const float* __restrict__ eattr, const int* __restrict__ rowp,
    const int* __restrict__ pos, uint2* __restrict__ edat) {
  int e = blockIdx.x * 256 + threadIdx.x;
  if (e >= NE) return;
  int d = ei[NE + e];
  int p = rowp[d] + pos[e];
  uint2 v;
  v.x = (unsigned)ei[e] | (bfr(eattr[e * 3 + 0]) << 16);
  v.y = bfr(eattr[e * 3 + 1]) | (bfr(eattr[e * 3 + 2]) << 16);
  edat[p] = v;
}

// self-loop entry: mean of incoming edge attrs. one WAVE per node.
__global__ __launch_bounds__(256) void k_selfmean(const int* __restrict__ rowp,
                                                  uint2* __restrict__ edat) {
  int n = blockIdx.x * 4 + (threadIdx.x >> 6);
  int lane = threadIdx.x & 63;
  if (n >= NN) return;
  int beg = rowp[n], endm1 = rowp[n + 1] - 1;
  float s0 = 0.f, s1 = 0.f, s2 = 0.f;
  for (int i = beg + lane; i < endm1; i += 64) {
    uint2 v = edat[i];
    s0 += bf_hi(v.x); s1 += bf_lo(v.y); s2 += bf_hi(v.y);
  }
#pragma unroll
  for (int off = 32; off > 0; off >>= 1) {
    s0 += __shfl_xor(s0, off, 64);
    s1 += __shfl_xor(s1, off, 64);
    s2 += __shfl_xor(s2, off, 64);
  }
  if (lane == 0) {
    int cnt = endm1 - beg;
    float inv = cnt > 0 ? 1.f / (float)cnt : 0.f;
    uint2 o;
    o.x = (unsigned)n | (bfr(s0 * inv) << 16);
    o.y = bfr(s1 * inv) | (bfr(s2 * inv) << 16);
    edat[endm1] = o;
  }
}

// ---------------- layer 0 input transform: A = x@W0l (bf16), B = x@W0r (bf16) ----------------

__global__ __launch_bounds__(256) void k_xform0(const float* __restrict__ x,
    const float* __restrict__ W0l, const float* __restrict__ W0r,
    unsigned* __restrict__ A, unsigned* __restrict__ B) {
  int t = blockIdx.x * 256 + threadIdx.x;
  int n = t >> 5;
  int c = (t & 31) * 4;
  if (n >= NN) return;
  float x0 = x[n * 3 + 0], x1 = x[n * 3 + 1], x2 = x[n * 3 + 2];
  float4 a0 = *(const float4*)&W0l[c];
  float4 a1 = *(const float4*)&W0l[HID + c];
  float4 a2 = *(const float4*)&W0l[2 * HID + c];
  float oax = x0 * a0.x + x1 * a1.x + x2 * a2.x;
  float oay = x0 * a0.y + x1 * a1.y + x2 * a2.y;
  float oaz = x0 * a0.z + x1 * a1.z + x2 * a2.z;
  float oaw = x0 * a0.w + x1 * a1.w + x2 * a2.w;
  uint2 pa;
  pa.x = pack2(oax, oay);
  pa.y = pack2(oaz, oaw);
  *(uint2*)&A[n * 64 + (c >> 1)] = pa;   // row stride = 64 uints (128 bf16)
  float4 b0 = *(const float4*)&W0r[c];
  float4 b1 = *(const float4*)&W0r[HID + c];
  float4 b2 = *(const float4*)&W0r[2 * HID + c];
  float obx = x0 * b0.x + x1 * b1.x + x2 * b2.x;
  float oby = x0 * b0.y + x1 * b1.y + x2 * b2.y;
  float obz = x0 * b0.z + x1 * b1.z + x2 * b2.z;
  float obw = x0 * b0.w + x1 * b1.w + x2 * b2.w;
  uint2 pb;
  pb.x = pack2(obx, oby);
  pb.y = pack2(obz, obw);
  *(uint2*)&B[n * 64 + (c >> 1)] = pb;
}

// ---------------- GEMM: A(bf16) = BN(relu(Hbf)) @ W, BN params from raw sums ----------------

__global__ __launch_bounds__(256) void k_gemm(const unsigned* __restrict__ Hb,
    const float* __restrict__ W, const float* __restrict__ cs,
    const float* __restrict__ g, const float* __restrict__ b,
    unsigned* __restrict__ A) {
  extern __shared__ float lds[];
  float* hs = lds;              // 32 x 128
  float* Ws = lds + 32 * HID;   // 128 x 128
  int t = threadIdx.x;
  for (int i = t * 4; i < HID * HID; i += 1024)
    *(float4*)&Ws[i] = *(const float4*)&W[i];
  int rl = t >> 5;
  int c4 = (t & 31) * 4;
  float4 s1v = *(const float4*)&cs[c4];
  float4 s2v = *(const float4*)&cs[HID + c4];
  float4 gv  = *(const float4*)&g[c4];
  float4 bv  = *(const float4*)&b[c4];
  float4 sc, sh;
  {
    float mu, var;
    mu = s1v.x * (1.f / NN); var = fmaxf(s2v.x * (1.f / NN) - mu * mu, 0.f);
    sc.x = gv.x * rsqrtf(var + BNEPS); sh.x = bv.x - mu * sc.x;
    mu = s1v.y * (1.f / NN); var = fmaxf(s2v.y * (1.f / NN) - mu * mu, 0.f);
    sc.y = gv.y * rsqrtf(var + BNEPS); sh.y = bv.y - mu * sc.y;
    mu = s1v.z * (1.f / NN); var = fmaxf(s2v.z * (1.f / NN) - mu * mu, 0.f);
    sc.z = gv.z * rsqrtf(var + BNEPS); sh.z = bv.z - mu * sc.z;
    mu = s1v.w * (1.f / NN); var = fmaxf(s2v.w * (1.f / NN) - mu * mu, 0.f);
    sc.w = gv.w * rsqrtf(var + BNEPS); sh.w = bv.w - mu * sc.w;
  }
  for (int r0 = blockIdx.x * 32; r0 < NN; r0 += gridDim.x * 32) {
    __syncthreads();
#pragma unroll
    for (int j = 0; j < 4; ++j) {
      int row = rl + 8 * j;
      int r = r0 + row;
      uint2 hv = make_uint2(0u, 0u);
      if (r < NN) hv = *(const uint2*)&Hb[r * 64 + (c4 >> 1)];
      float4 o;
      o.x = fmaxf(bf_lo(hv.x), 0.f) * sc.x + sh.x;
      o.y = fmaxf(bf_hi(hv.x), 0.f) * sc.y + sh.y;
      o.z = fmaxf(bf_lo(hv.y), 0.f) * sc.z + sh.z;
      o.w = fmaxf(bf_hi(hv.y), 0.f) * sc.w + sh.w;
      *(float4*)&hs[row * HID + c4] = o;
    }
    __syncthreads();
    float4 a0 = make_float4(0.f, 0.f, 0.f, 0.f);
    float4 a1 = a0, a2 = a0, a3 = a0;
#pragma unroll 4
    for (int k4 = 0; k4 < HID; k4 += 4) {
      float4 w0 = *(float4*)&Ws[(k4 + 0) * HID + c4];
      float4 w1 = *(float4*)&Ws[(k4 + 1) * HID + c4];
      float4 w2 = *(float4*)&Ws[(k4 + 2) * HID + c4];
      float4 w3 = *(float4*)&Ws[(k4 + 3) * HID + c4];
      float4 h;
      h = *(float4*)&hs[(rl + 0) * HID + k4];
      a0.x += h.x*w0.x + h.y*w1.x + h.z*w2.x + h.w*w3.x;
      a0.y += h.x*w0.y + h.y*w1.y + h.z*w2.y + h.w*w3.y;
      a0.z += h.x*w0.z + h.y*w1.z + h.z*w2.z + h.w*w3.z;
      a0.w += h.x*w0.w + h.y*w1.w + h.z*w2.w + h.w*w3.w;
      h = *(float4*)&hs[(rl + 8) * HID + k4];
      a1.x += h.x*w0.x + h.y*w1.x + h.z*w2.x + h.w*w3.x;
      a1.y += h.x*w0.y + h.y*w1.y + h.z*w2.y + h.w*w3.y;
      a1.z += h.x*w0.z + h.y*w1.z + h.z*w2.z + h.w*w3.z;
      a1.w += h.x*w0.w + h.y*w1.w + h.z*w2.w + h.w*w3.w;
      h = *(float4*)&hs[(rl + 16) * HID + k4];
      a2.x += h.x*w0.x + h.y*w1.x + h.z*w2.x + h.w*w3.x;
      a2.y += h.x*w0.y + h.y*w1.y + h.z*w2.y + h.w*w3.y;
      a2.z += h.x*w0.z + h.y*w1.z + h.z*w2.z + h.w*w3.z;
      a2.w += h.x*w0.w + h.y*w1.w + h.z*w2.w + h.w*w3.w;
      h = *(float4*)&hs[(rl + 24) * HID + k4];
      a3.x += h.x*w0.x + h.y*w1.x + h.z*w2.x + h.w*w3.x;
      a3.y += h.x*w0.y + h.y*w1.y + h.z*w2.y + h.w*w3.y;
      a3.z += h.x*w0.z + h.y*w1.z + h.z*w2.z + h.w*w3.z;
      a3.w += h.x*w0.w + h.y*w1.w + h.z*w2.w + h.w*w3.w;
    }
    int r = r0 + rl;
    int ci = c4 >> 1;  // uint offset within the 64-uint row
    if (r < NN) {
      uint2 p; p.x = pack2(a0.x, a0.y); p.y = pack2(a0.z, a0.w);
      *(uint2*)&A[r * 64 + ci] = p;
    }
    if (r + 8 < NN) {
      uint2 p; p.x = pack2(a1.x, a1.y); p.y = pack2(a1.z, a1.w);
      *(uint2*)&A[(r + 8) * 64 + ci] = p;
    }
    if (r + 16 < NN) {
      uint2 p; p.x = pack2(a2.x, a2.y); p.y = pack2(a2.z, a2.w);
      *(uint2*)&A[(r + 16) * 64 + ci] = p;
    }
    if (r + 24 < NN) {
      uint2 p; p.x = pack2(a3.x, a3.y); p.y = pack2(a3.z, a3.w);
      *(uint2*)&A[(r + 24) * 64 + ci] = p;
    }
  }
}

// ---- GATv2 edge phase v7: 2 dst nodes per wave (32 lanes / 4 ch each),
//      no-max softmax (exp2 direct), clamped loads + act-masking, DPP half-reduce ----

__global__ __launch_bounds__(256) void k_edge(const unsigned* __restrict__ XL,
    const unsigned* __restrict__ XR, const uint2* __restrict__ edat,
    const int* __restrict__ rowp, const float* __restrict__ We,
    const float* __restrict__ att, const float* __restrict__ bias,
    unsigned* __restrict__ Hb) {
  __shared__ float WeS[3 * HID];
  int t = threadIdx.x;
  for (int i = t; i < 3 * HID; i += 256) WeS[i] = We[i];
  __syncthreads();
  int lane = t & 63;
  int l5 = lane & 31;
  int half = lane >> 5;
  int n = blockIdx.x * 8 + (t >> 6) * 2 + half;   // 8 nodes per block
  int c0 = l5 * 4;                                 // this lane's 4 channels
  uint2 urx = *(const uint2*)&XR[n * 64 + l5 * 2];
  float xr0 = bf_lo(urx.x), xr1 = bf_hi(urx.x);
  float xr2 = bf_lo(urx.y), xr3 = bf_hi(urx.y);
  float4 av = *(const float4*)&att[c0];
  av.x *= 1.44269504f; av.y *= 1.44269504f;
  av.z *= 1.44269504f; av.w *= 1.44269504f;
  float w00 = WeS[c0],           w01 = WeS[c0 + 1],           w02 = WeS[c0 + 2],           w03 = WeS[c0 + 3];
  float w10 = WeS[HID + c0],     w11 = WeS[HID + c0 + 1],     w12 = WeS[HID + c0 + 2],     w13 = WeS[HID + c0 + 3];
  float w20 = WeS[2 * HID + c0], w21 = WeS[2 * HID + c0 + 1], w22 = WeS[2 * HID + c0 + 2], w23 = WeS[2 * HID + c0 + 3];
  int beg = rowp[n], end = rowp[n + 1];
  int last = end - 1;
  int tc = end - beg;
#pragma unroll
  for (int off = 32; off > 0; off >>= 1) tc = max(tc, __shfl_xor(tc, off, 64));
  int trips = (__builtin_amdgcn_readfirstlane(tc) + 1) & ~1;
  const unsigned* XLg = XL + l5 * 2;

  int vi = beg;
  uint2 ed0 = edat[beg];
  uint2 ed1 = edat[min(beg + 1, last)];
  uint2 x0 = *(const uint2*)&XLg[(ed0.x & 0xffffu) * 64];
  float s = 0.f, a0 = 0.f, a1 = 0.f, a2 = 0.f, a3 = 0.f;

#define EDGE_BODY(ED, XU)                                                         \
  {                                                                               \
    float xs0 = bf_lo(XU.x), xs1 = bf_hi(XU.x);                                   \
    float xs2 = bf_lo(XU.y), xs3 = bf_hi(XU.y);                                   \
    float ea0 = bf_hi(ED.x), ea1 = bf_lo(ED.y), ea2 = bf_hi(ED.y);                \
    float u0 = __builtin_fmaf(ea2, w20, __builtin_fmaf(ea1, w10,                  \
               __builtin_fmaf(ea0, w00, xs0 + xr0)));                             \
    float u1 = __builtin_fmaf(ea2, w21, __builtin_fmaf(ea1, w11,                  \
               __builtin_fmaf(ea0, w01, xs1 + xr1)));                             \
    float u2 = __builtin_fmaf(ea2, w22, __builtin_fmaf(ea1, w12,                  \
               __builtin_fmaf(ea0, w02, xs2 + xr2)));                             \
    float u3 = __builtin_fmaf(ea2, w23, __builtin_fmaf(ea1, w13,                  \
               __builtin_fmaf(ea0, w03, xs3 + xr3)));                             \
    float v0 = fmaxf(u0, 0.2f * u0), v1 = fmaxf(u1, 0.2f * u1);                   \
    float v2 = fmaxf(u2, 0.2f * u2), v3 = fmaxf(u3, 0.2f * u3);                   \
    float part = __builtin_fmaf(v3, av.w, __builtin_fmaf(v2, av.z,                \
                 __builtin_fmaf(v1, av.y, v0 * av.x)));                           \
    DPPADD(part, 0x111, 0xf);  /* row_shr:1 */                                    \
    DPPADD(part, 0x112, 0xf);  /* row_shr:2 */                                    \
    DPPADD(part, 0x114, 0xf);  /* row_shr:4 */                                    \
    DPPADD(part, 0x118, 0xf);  /* row_shr:8 */                                    \
    DPPADD(part, 0x142, 0xa);  /* row_bcast:15 -> lane31/63 hold half-sums */     \
    part = __int_as_float(__builtin_amdgcn_ds_swizzle(                            \
        __float_as_int(part), 0x3E0)); /* bcast lane31 within each 32-group */    \
    float p = __builtin_amdgcn_exp2f(part);                                       \
    p = (vi < end) ? p : 0.f;                                                     \
    s += p;                                                                       \
    a0 = __builtin_fmaf(p, xs0, a0); a1 = __builtin_fmaf(p, xs1, a1);             \
    a2 = __builtin_fmaf(p, xs2, a2); a3 = __builtin_fmaf(p, xs3, a3);             \
    ++vi;                                                                         \
  }

  for (int k = 0; k < trips; k += 2) {
    uint2 ed2 = edat[min(vi + 2, last)];
    uint2 x1 = *(const uint2*)&XLg[(ed1.x & 0xffffu) * 64];
    EDGE_BODY(ed0, x0);
    uint2 ed3 = edat[min(vi + 2, last)];  // original vi+3 (vi advanced)
    uint2 x0n = *(const uint2*)&XLg[(ed2.x & 0xffffu) * 64];
    EDGE_BODY(ed1, x1);
    ed0 = ed2; ed1 = ed3; x0 = x0n;
  }
#undef EDGE_BODY

  float inv = 1.f / s;
  float4 bv = *(const float4*)&bias[c0];
  uint2 o;
  o.x = pack2(__builtin_fmaf(a0, inv, bv.x), __builtin_fmaf(a1, inv, bv.y));
  o.y = pack2(__builtin_fmaf(a2, inv, bv.z), __builtin_fmaf(a3, inv, bv.w));
  *(uint2*)&Hb[n * 64 + l5 * 2] = o;
}

// ---------------- BN stats (raw sums) from bf16 H ----------------

__global__ __launch_bounds__(128) void k_bnstats(const unsigned* __restrict__ Hb,
                                                 float* __restrict__ cs) {
  int c = threadIdx.x;
  int ui = c >> 1;
  bool hi = c & 1;
  int chunk = (NN + gridDim.x - 1) / gridDim.x;
  int n0 = blockIdx.x * chunk, n1 = min(n0 + chunk, NN);
  if (n0 >= n1) return;
  float s1 = 0.f, s2 = 0.f;
  for (int n = n0; n < n1; ++n) {
    unsigned u = Hb[n * 64 + ui];
    float v = hi ? bf_hi(u) : bf_lo(u);
    v = fmaxf(v, 0.f);
    s1 += v; s2 += v * v;
  }
  atomicAdd(&cs[c], s1);
  atomicAdd(&cs[HID + c], s2);
}

// ---------------- pooling (segment_max over sorted batch), BN fused ----------------

__global__ __launch_bounds__(128) void k_pool(const unsigned* __restrict__ Hb,
    const int* __restrict__ batch, const float* __restrict__ cs,
    const float* __restrict__ g, const float* __restrict__ b,
    unsigned* __restrict__ pooled) {
  int c = threadIdx.x;
  int ui = c >> 1;
  bool hi = c & 1;
  const int chunk = (NN + gridDim.x - 1) / gridDim.x;
  int n0 = blockIdx.x * chunk;
  int n1 = min(n0 + chunk, NN);
  if (n0 >= n1) return;
  float mu = cs[c] * (1.f / NN);
  float var = fmaxf(cs[HID + c] * (1.f / NN) - mu * mu, 0.f);
  float sc = g[c] * rsqrtf(var + BNEPS);
  float sh = b[c] - mu * sc;
  int curg = batch[n0];
  float vmax = -3.402823e38f;
  for (int n = n0; n < n1; ++n) {
    int gg = batch[n];
    if (gg != curg) {
      atomicMax(&pooled[curg * HID + c], fenc(vmax));
      curg = gg;
      vmax = -3.402823e38f;
    }
    unsigned u = Hb[n * 64 + ui];
    float v = hi ? bf_hi(u) : bf_lo(u);
    v = fmaxf(v, 0.f) * sc + sh;
    vmax = fmaxf(vmax, v);
  }
  atomicMax(&pooled[curg * HID + c], fenc(vmax));
}

// ---------------- FC head: one block per graph ----------------

__global__ __launch_bounds__(128) void k_fc(const unsigned* __restrict__ pooled,
    const float* __restrict__ W1, const float* __restrict__ b1,
    const float* __restrict__ W2, const float* __restrict__ b2,
    float* __restrict__ out) {
  __shared__ float P[HID];
  __shared__ float Z[HID];
  int g = blockIdx.x, c = threadIdx.x;
  unsigned k = pooled[g * HID + c];
  P[c] = (k & 0x80000000u) ? __uint_as_float(k ^ 0x80000000u) : __uint_as_float(~k);
  __syncthreads();
  float acc = b1[c];
  for (int kk = 0; kk < HID; ++kk) acc += P[kk] * W1[kk * HID + c];
  Z[c] = fmaxf(acc, 0.f);
  __syncthreads();
  if (c < 40) {
    float a2 = b2[c];
    for (int kk = 0; kk < HID; ++kk) a2 += Z[kk] * W2[kk * 40 + c];
    out[g * 40 + c] = a2;
  }
}

// ---------------- launch ----------------

extern "C" void kernel_launch(void* const* d_in, const int* in_sizes, int n_in,
                              void* d_out, int out_size, void* d_ws, size_t ws_size,
                              hipStream_t stream) {
  (void)in_sizes; (void)n_in; (void)out_size; (void)ws_size;
  const float* x     = (const float*)d_in[0];
  const float* eattr = (const float*)d_in[1];
  const int*   ei    = (const int*)d_in[2];
  const int*   batch = (const int*)d_in[3];
  const float* W0l   = (const float*)d_in[4];
  const float* W0r   = (const float*)d_in[5];
  const float* We0   = (const float*)d_in[6];
  const float* a0    = (const float*)d_in[7];
  const float* b0    = (const float*)d_in[8];
  const float* bn0g  = (const float*)d_in[9];
  const float* bn0b  = (const float*)d_in[10];
  const float* Wl    = (const float*)d_in[11];
  const float* Wel   = (const float*)d_in[12];
  const float* al    = (const float*)d_in[13];
  const float* bl    = (const float*)d_in[14];
  const float* bng   = (const float*)d_in[15];
  const float* bnb   = (const float*)d_in[16];
  const float* fc1W  = (const float*)d_in[17];
  const float* fc1b  = (const float*)d_in[18];
  const float* fc2W  = (const float*)d_in[19];
  const float* fc2b  = (const float*)d_in[20];
  float* out = (float*)d_out;

  char* ws = (char*)d_ws;
  unsigned* Hbf  = (unsigned*)(ws + 0);            // 12,800,000  (bf16 H)
  unsigned* Abf  = (unsigned*)(ws + 12800000);     // 12,800,000  (bf16 features)
  unsigned* X0bf = (unsigned*)(ws + 25600000);     // 12,800,000  (layer0 XR, bf16)
  uint2*    edat = (uint2*)(ws + 38400000);        // (850000+4)*8 = 6,800,032
  int*      rowp = (int*)(ws + 45200064);          // 50001*4
  int*      pos  = (int*)(ws + 45400128);          // 800000*4 = 3,200,000
  char*     zb   = ws + 48600128;                  // zeroed region start
  int*      deg  = (int*)(zb + 0);                 // 200,000
  float*    cs   = (float*)(zb + 200000);          // 3*256*4 = 3,072
  unsigned* pooled = (unsigned*)(zb + 203072);     // 32*128*4 = 16,384
  int*      bsum = (int*)(zb + 219456);            // 64*4 = 256
  const size_t ZLEN = 219712;

  hipMemsetAsync(zb, 0, ZLEN, stream);

  // build CSR (dst-sorted) with self loops + mean edge_attr fill
  k_hist<<<(NE + 255) / 256, 256, 0, stream>>>(ei, deg, pos);
  k_scanA<<<49, 1024, 0, stream>>>(deg, rowp, bsum);
  k_scanB<<<1, 64, 0, stream>>>(bsum, rowp, edat);
  k_scanC<<<49, 1024, 0, stream>>>(rowp, bsum);
  k_scatter<<<(NE + 255) / 256, 256, 0, stream>>>(ei, eattr, rowp, pos, edat);
  k_selfmean<<<(NN + 3) / 4, 256, 0, stream>>>(rowp, edat);

  const size_t GEMM_LDS = (size_t)(32 * HID + HID * HID) * 4;  // 81920 B

  // layer 0
  k_xform0<<<(NN * 32) / 256, 256, 0, stream>>>(x, W0l, W0r, Abf, X0bf);
  k_edge<<<NN / 8, 256, 0, stream>>>(Abf, X0bf, edat, rowp, We0, a0, b0, Hbf);
  k_bnstats<<<2048, 128, 0, stream>>>(Hbf, cs);

  // layer 1
  k_gemm<<<782, 256, GEMM_LDS, stream>>>(Hbf, Wl, cs, bn0g, bn0b, Abf);
  k_edge<<<NN / 8, 256, 0, stream>>>(Abf, Abf, edat, rowp, Wel, al, bl, Hbf);
  k_bnstats<<<2048, 128, 0, stream>>>(Hbf, cs + 256);

  // layer 2
  k_gemm<<<782, 256, GEMM_LDS, stream>>>(Hbf, Wl + 128 * 128, cs + 256, bng, bnb, Abf);
  k_edge<<<NN / 8, 256, 0, stream>>>(Abf, Abf, edat, rowp, Wel + 384, al + 128, bl + 128, Hbf);
  k_bnstats<<<2048, 128, 0, stream>>>(Hbf, cs + 512);

  // pool + FC head
  k_pool<<<2048, 128, 0, stream>>>(Hbf, batch, cs + 512, bng + 128, bnb + 128, pooled);
  k_fc<<<NG, 128, 0, stream>>>(pooled, fc1W, fc1b, fc2W, fc2b, out);
}

// Round 10
// 398.013 us; speedup vs baseline: 2.2996x; 1.2917x over previous
//
#include <hip/hip_runtime.h>

#define NN 50000
#define NE 800000
#define NG 32
#define HID 128
#define BNEPS 1e-5f
#define NETOT (NE + NN)  // 850000, CSR total incl self loops

typedef float f32x2 __attribute__((ext_vector_type(2)));

__device__ __forceinline__ unsigned fenc(float f) {
  unsigned u = __float_as_uint(f);
  return (u & 0x80000000u) ? ~u : (u | 0x80000000u);
}

// round-to-nearest-even f32 -> bf16 (as low 16 bits)
__device__ __forceinline__ unsigned bfr(float f) {
  unsigned u = __float_as_uint(f);
  return (u + 0x7fffu + ((u >> 16) & 1u)) >> 16;
}
__device__ __forceinline__ unsigned pack2(float a, float b) {
  return bfr(a) | (bfr(b) << 16);
}
__device__ __forceinline__ float bf_lo(unsigned u) { return __uint_as_float(u << 16); }
__device__ __forceinline__ float bf_hi(unsigned u) { return __uint_as_float(u & 0xffff0000u); }

// fused DPP add: x += dpp_move(x); masked-out rows add 0
#define DPPADD(x, ctrl, rmask)                                                   \
  (x) += __int_as_float(__builtin_amdgcn_update_dpp(0, __float_as_int(x),        \
                                                    (ctrl), (rmask), 0xf, true))

// ---------------- preprocessing ----------------

// degree histogram; also records each edge's position within its dst bucket
__global__ __launch_bounds__(256) void k_hist(const int* __restrict__ ei,
                                              int* __restrict__ deg,
                                              int* __restrict__ pos) {
  int e = blockIdx.x * 256 + threadIdx.x;
  if (e >= NE) return;
  pos[e] = atomicAdd(&deg[ei[NE + e]], 1);
}

// hierarchical scan: A (per-block) -> B (block sums) -> C (add offsets)
__global__ __launch_bounds__(1024) void k_scanA(const int* __restrict__ deg,
                                                int* __restrict__ rowp,
                                                int* __restrict__ bsum) {
  __shared__ int wsum[16];
  int t = threadIdx.x, lane = t & 63, w = t >> 6;
  int i = blockIdx.x * 1024 + t;
  int v = (i < NN) ? (deg[i] + 1) : 0;  // +1 self loop
  int s = v;
#pragma unroll
  for (int off = 1; off < 64; off <<= 1) {
    int y = __shfl_up(s, off, 64);
    if (lane >= off) s += y;
  }
  if (lane == 63) wsum[w] = s;
  __syncthreads();
  if (t < 16) {
    int xv = wsum[t];
#pragma unroll
    for (int off = 1; off < 16; off <<= 1) {
      int y = __shfl_up(xv, off, 64);
      if (t >= off) xv += y;
    }
    wsum[t] = xv;
  }
  __syncthreads();
  int wexcl = (w == 0) ? 0 : wsum[w - 1];
  int incl = wexcl + s;
  if (i < NN) rowp[i] = incl - v;  // block-local exclusive
  if (t == 1023) bsum[blockIdx.x] = incl;
}

__global__ __launch_bounds__(64) void k_scanB(int* __restrict__ bsum,
                                              int* __restrict__ rowp,
                                              uint2* __restrict__ edat) {
  int t = threadIdx.x;  // one wave; 49 block sums
  int v = (t < 49) ? bsum[t] : 0;
  int s = v;
#pragma unroll
  for (int off = 1; off < 64; off <<= 1) {
    int y = __shfl_up(s, off, 64);
    if (t >= off) s += y;
  }
  bsum[t] = s - v;                 // exclusive
  if (t == 48) rowp[NN] = s;       // total (== NETOT)
  for (int j = t; j < 256; j += 64) {  // zero pad entries (clamp-free prefetch)
    uint2 z; z.x = 0u; z.y = 0u;
    edat[NETOT + j] = z;
  }
}

__global__ __launch_bounds__(1024) void k_scanC(int* __restrict__ rowp,
                                                const int* __restrict__ bsum) {
  int i = blockIdx.x * 1024 + threadIdx.x;
  if (i < NN) rowp[i] += bsum[blockIdx.x];
}

// scatter edges into dst-CSR order (atomic-free; position from k_hist)
__global__ __launch_bounds__(256) void k_scatter(const int* __restrict__ ei,
    const float* __restrict__ eattr, const int* __restrict__ rowp,
    const int* __restrict__ pos, uint2* __restrict__ edat) {
  int e = blockIdx.x * 256 + threadIdx.x;
  if (e >= NE) return;
  int d = ei[NE + e];
  int p = rowp[d] + pos[e];
  uint2 v;
  v.x = (unsigned)ei[e] | (bfr(eattr[e * 3 + 0]) << 16);
  v.y = bfr(eattr[e * 3 + 1]) | (bfr(eattr[e * 3 + 2]) << 16);
  edat[p] = v;
}

// self-loop entry: mean of incoming edge attrs. one THREAD per node (contiguous seg).
__global__ __launch_bounds__(256) void k_selfmean(const int* __restrict__ rowp,
                                                  uint2* __restrict__ edat) {
  int n = blockIdx.x * 256 + threadIdx.x;
  if (n >= NN) return;
  int beg = rowp[n], endm1 = rowp[n + 1] - 1;
  float s0 = 0.f, s1 = 0.f, s2 = 0.f;
  for (int i = beg; i < endm1; ++i) {
    uint2 v = edat[i];
    s0 += bf_hi(v.x); s1 += bf_lo(v.y); s2 += bf_hi(v.y);
  }
  int cnt = endm1 - beg;
  float inv = cnt > 0 ? 1.f / (float)cnt : 0.f;
  uint2 o;
  o.x = (unsigned)n | (bfr(s0 * inv) << 16);
  o.y = bfr(s1 * inv) | (bfr(s2 * inv) << 16);
  edat[endm1] = o;
}

// ---------------- layer 0 input transform: A = x@W0l (bf16), B = x@W0r (bf16) ----------------

__global__ __launch_bounds__(256) void k_xform0(const float* __restrict__ x,
    const float* __restrict__ W0l, const float* __restrict__ W0r,
    unsigned* __restrict__ A, unsigned* __restrict__ B) {
  int t = blockIdx.x * 256 + threadIdx.x;
  int n = t >> 5;
  int c = (t & 31) * 4;
  if (n >= NN) return;
  float x0 = x[n * 3 + 0], x1 = x[n * 3 + 1], x2 = x[n * 3 + 2];
  float4 a0 = *(const float4*)&W0l[c];
  float4 a1 = *(const float4*)&W0l[HID + c];
  float4 a2 = *(const float4*)&W0l[2 * HID + c];
  float oax = x0 * a0.x + x1 * a1.x + x2 * a2.x;
  float oay = x0 * a0.y + x1 * a1.y + x2 * a2.y;
  float oaz = x0 * a0.z + x1 * a1.z + x2 * a2.z;
  float oaw = x0 * a0.w + x1 * a1.w + x2 * a2.w;
  uint2 pa;
  pa.x = pack2(oax, oay);
  pa.y = pack2(oaz, oaw);
  *(uint2*)&A[n * 64 + (c >> 1)] = pa;   // row stride = 64 uints (128 bf16)
  float4 b0 = *(const float4*)&W0r[c];
  float4 b1 = *(const float4*)&W0r[HID + c];
  float4 b2 = *(const float4*)&W0r[2 * HID + c];
  float obx = x0 * b0.x + x1 * b1.x + x2 * b2.x;
  float oby = x0 * b0.y + x1 * b1.y + x2 * b2.y;
  float obz = x0 * b0.z + x1 * b1.z + x2 * b2.z;
  float obw = x0 * b0.w + x1 * b1.w + x2 * b2.w;
  uint2 pb;
  pb.x = pack2(obx, oby);
  pb.y = pack2(obz, obw);
  *(uint2*)&B[n * 64 + (c >> 1)] = pb;
}

// ---------------- GEMM: A(bf16) = BN(relu(Hbf)) @ W, BN params from raw sums ----------------

__global__ __launch_bounds__(256) void k_gemm(const unsigned* __restrict__ Hb,
    const float* __restrict__ W, const float* __restrict__ cs,
    const float* __restrict__ g, const float* __restrict__ b,
    unsigned* __restrict__ A) {
  extern __shared__ float lds[];
  float* hs = lds;              // 32 x 128
  float* Ws = lds + 32 * HID;   // 128 x 128
  int t = threadIdx.x;
  for (int i = t * 4; i < HID * HID; i += 1024)
    *(float4*)&Ws[i] = *(const float4*)&W[i];
  int rl = t >> 5;
  int c4 = (t & 31) * 4;
  float4 s1v = *(const float4*)&cs[c4];
  float4 s2v = *(const float4*)&cs[HID + c4];
  float4 gv  = *(const float4*)&g[c4];
  float4 bv  = *(const float4*)&b[c4];
  float4 sc, sh;
  {
    float mu, var;
    mu = s1v.x * (1.f / NN); var = fmaxf(s2v.x * (1.f / NN) - mu * mu, 0.f);
    sc.x = gv.x * rsqrtf(var + BNEPS); sh.x = bv.x - mu * sc.x;
    mu = s1v.y * (1.f / NN); var = fmaxf(s2v.y * (1.f / NN) - mu * mu, 0.f);
    sc.y = gv.y * rsqrtf(var + BNEPS); sh.y = bv.y - mu * sc.y;
    mu = s1v.z * (1.f / NN); var = fmaxf(s2v.z * (1.f / NN) - mu * mu, 0.f);
    sc.z = gv.z * rsqrtf(var + BNEPS); sh.z = bv.z - mu * sc.z;
    mu = s1v.w * (1.f / NN); var = fmaxf(s2v.w * (1.f / NN) - mu * mu, 0.f);
    sc.w = gv.w * rsqrtf(var + BNEPS); sh.w = bv.w - mu * sc.w;
  }
  for (int r0 = blockIdx.x * 32; r0 < NN; r0 += gridDim.x * 32) {
    __syncthreads();
#pragma unroll
    for (int j = 0; j < 4; ++j) {
      int row = rl + 8 * j;
      int r = r0 + row;
      uint2 hv = make_uint2(0u, 0u);
      if (r < NN) hv = *(const uint2*)&Hb[r * 64 + (c4 >> 1)];
      float4 o;
      o.x = fmaxf(bf_lo(hv.x), 0.f) * sc.x + sh.x;
      o.y = fmaxf(bf_hi(hv.x), 0.f) * sc.y + sh.y;
      o.z = fmaxf(bf_lo(hv.y), 0.f) * sc.z + sh.z;
      o.w = fmaxf(bf_hi(hv.y), 0.f) * sc.w + sh.w;
      *(float4*)&hs[row * HID + c4] = o;
    }
    __syncthreads();
    float4 a0 = make_float4(0.f, 0.f, 0.f, 0.f);
    float4 a1 = a0, a2 = a0, a3 = a0;
#pragma unroll 4
    for (int k4 = 0; k4 < HID; k4 += 4) {
      float4 w0 = *(float4*)&Ws[(k4 + 0) * HID + c4];
      float4 w1 = *(float4*)&Ws[(k4 + 1) * HID + c4];
      float4 w2 = *(float4*)&Ws[(k4 + 2) * HID + c4];
      float4 w3 = *(float4*)&Ws[(k4 + 3) * HID + c4];
      float4 h;
      h = *(float4*)&hs[(rl + 0) * HID + k4];
      a0.x += h.x*w0.x + h.y*w1.x + h.z*w2.x + h.w*w3.x;
      a0.y += h.x*w0.y + h.y*w1.y + h.z*w2.y + h.w*w3.y;
      a0.z += h.x*w0.z + h.y*w1.z + h.z*w2.z + h.w*w3.z;
      a0.w += h.x*w0.w + h.y*w1.w + h.z*w2.w + h.w*w3.w;
      h = *(float4*)&hs[(rl + 8) * HID + k4];
      a1.x += h.x*w0.x + h.y*w1.x + h.z*w2.x + h.w*w3.x;
      a1.y += h.x*w0.y + h.y*w1.y + h.z*w2.y + h.w*w3.y;
      a1.z += h.x*w0.z + h.y*w1.z + h.z*w2.z + h.w*w3.z;
      a1.w += h.x*w0.w + h.y*w1.w + h.z*w2.w + h.w*w3.w;
      h = *(float4*)&hs[(rl + 16) * HID + k4];
      a2.x += h.x*w0.x + h.y*w1.x + h.z*w2.x + h.w*w3.x;
      a2.y += h.x*w0.y + h.y*w1.y + h.z*w2.y + h.w*w3.y;
      a2.z += h.x*w0.z + h.y*w1.z + h.z*w2.z + h.w*w3.z;
      a2.w += h.x*w0.w + h.y*w1.w + h.z*w2.w + h.w*w3.w;
      h = *(float4*)&hs[(rl + 24) * HID + k4];
      a3.x += h.x*w0.x + h.y*w1.x + h.z*w2.x + h.w*w3.x;
      a3.y += h.x*w0.y + h.y*w1.y + h.z*w2.y + h.w*w3.y;
      a3.z += h.x*w0.z + h.y*w1.z + h.z*w2.z + h.w*w3.z;
      a3.w += h.x*w0.w + h.y*w1.w + h.z*w2.w + h.w*w3.w;
    }
    int r = r0 + rl;
    int ci = c4 >> 1;  // uint offset within the 64-uint row
    if (r < NN) {
      uint2 p; p.x = pack2(a0.x, a0.y); p.y = pack2(a0.z, a0.w);
      *(uint2*)&A[r * 64 + ci] = p;
    }
    if (r + 8 < NN) {
      uint2 p; p.x = pack2(a1.x, a1.y); p.y = pack2(a1.z, a1.w);
      *(uint2*)&A[(r + 8) * 64 + ci] = p;
    }
    if (r + 16 < NN) {
      uint2 p; p.x = pack2(a2.x, a2.y); p.y = pack2(a2.z, a2.w);
      *(uint2*)&A[(r + 16) * 64 + ci] = p;
    }
    if (r + 24 < NN) {
      uint2 p; p.x = pack2(a3.x, a3.y); p.y = pack2(a3.z, a3.w);
      *(uint2*)&A[(r + 24) * 64 + ci] = p;
    }
  }
}

// ---- GATv2 edge phase v8: 2 dst/wave, packed-f32 channel math (f32x2),
//      static 4-unroll (no rotation movs), padded edat (no clamps) ----

__global__ __launch_bounds__(256) void k_edge(const unsigned* __restrict__ XL,
    const unsigned* __restrict__ XR, const uint2* __restrict__ edat,
    const int* __restrict__ rowp, const float* __restrict__ We,
    const float* __restrict__ att, const float* __restrict__ bias,
    unsigned* __restrict__ Hb) {
  __shared__ float WeS[3 * HID];
  int t = threadIdx.x;
  for (int i = t; i < 3 * HID; i += 256) WeS[i] = We[i];
  __syncthreads();
  int lane = t & 63;
  int l5 = lane & 31;
  int half = lane >> 5;
  int n = blockIdx.x * 8 + (t >> 6) * 2 + half;   // 8 nodes per block
  int c0 = l5 * 4;                                 // this lane's 4 channels
  uint2 urx = *(const uint2*)&XR[n * 64 + l5 * 2];
  f32x2 xr01 = {bf_lo(urx.x), bf_hi(urx.x)};
  f32x2 xr23 = {bf_lo(urx.y), bf_hi(urx.y)};
  f32x2 at01 = *(const f32x2*)&att[c0];
  f32x2 at23 = *(const f32x2*)&att[c0 + 2];
  at01 *= 1.44269504f;  // fold log2(e)
  at23 *= 1.44269504f;
  f32x2 w0a = {WeS[c0], WeS[c0 + 1]},               w0b = {WeS[c0 + 2], WeS[c0 + 3]};
  f32x2 w1a = {WeS[HID + c0], WeS[HID + c0 + 1]},   w1b = {WeS[HID + c0 + 2], WeS[HID + c0 + 3]};
  f32x2 w2a = {WeS[2*HID + c0], WeS[2*HID + c0+1]}, w2b = {WeS[2*HID + c0+2], WeS[2*HID + c0+3]};
  int beg = rowp[n], end = rowp[n + 1];
  int rem = end - beg;
  int tc = max(rem, __shfl_xor(rem, 32, 64));
  int trips = (__builtin_amdgcn_readfirstlane(tc) + 3) & ~3;
  const unsigned* XLg = XL + l5 * 2;

  // prologue (pads make all loads in-bounds; pad src=0 valid, masked out)
  uint2 e0 = edat[beg], e1 = edat[beg + 1], e2 = edat[beg + 2], e3 = edat[beg + 3];
  uint2 x0 = *(const uint2*)&XLg[(e0.x & 0xffffu) * 64];
  uint2 x1 = *(const uint2*)&XLg[(e1.x & 0xffffu) * 64];
  uint2 x2, x3;
  f32x2 a01 = {0.f, 0.f}, a23 = {0.f, 0.f};
  float s = 0.f;

#define BODY(ED, XU, J)                                                           \
  {                                                                               \
    f32x2 xs01 = {bf_lo(XU.x), bf_hi(XU.x)};                                      \
    f32x2 xs23 = {bf_lo(XU.y), bf_hi(XU.y)};                                      \
    float ea0 = bf_hi(ED.x), ea1 = bf_lo(ED.y), ea2 = bf_hi(ED.y);                \
    f32x2 u01 = xs01 + xr01;                                                      \
    f32x2 u23 = xs23 + xr23;                                                      \
    u01 = ea0 * w0a + u01;  u23 = ea0 * w0b + u23;                                \
    u01 = ea1 * w1a + u01;  u23 = ea1 * w1b + u23;                                \
    u01 = ea2 * w2a + u01;  u23 = ea2 * w2b + u23;                                \
    f32x2 v01 = __builtin_elementwise_max(u01, 0.2f * u01);                       \
    f32x2 v23 = __builtin_elementwise_max(u23, 0.2f * u23);                       \
    f32x2 pl = v01 * at01 + v23 * at23;                                           \
    float part = pl.x + pl.y;                                                     \
    DPPADD(part, 0x111, 0xf);                                                     \
    DPPADD(part, 0x112, 0xf);                                                     \
    DPPADD(part, 0x114, 0xf);                                                     \
    DPPADD(part, 0x118, 0xf);                                                     \
    DPPADD(part, 0x142, 0xa);                                                     \
    part = __int_as_float(__builtin_amdgcn_ds_swizzle(                            \
        __float_as_int(part), 0x3E0));  /* bcast lane31 within 32-group */        \
    float p = __builtin_amdgcn_exp2f(part);                                       \
    p = (i + (J) < rem) ? p : 0.f;                                                \
    s += p;                                                                       \
    a01 = p * xs01 + a01;                                                         \
    a23 = p * xs23 + a23;                                                         \
  }

  for (int i = 0; i < trips; i += 4) {
    x2 = *(const uint2*)&XLg[(e2.x & 0xffffu) * 64];
    BODY(e0, x0, 0);
    e0 = edat[beg + i + 4];
    x3 = *(const uint2*)&XLg[(e3.x & 0xffffu) * 64];
    BODY(e1, x1, 1);
    e1 = edat[beg + i + 5];
    x0 = *(const uint2*)&XLg[(e0.x & 0xffffu) * 64];
    BODY(e2, x2, 2);
    e2 = edat[beg + i + 6];
    x1 = *(const uint2*)&XLg[(e1.x & 0xffffu) * 64];
    BODY(e3, x3, 3);
    e3 = edat[beg + i + 7];
  }
#undef BODY

  float inv = 1.f / s;
  f32x2 b01 = *(const f32x2*)&bias[c0];
  f32x2 b23 = *(const f32x2*)&bias[c0 + 2];
  f32x2 o01 = a01 * inv + b01;
  f32x2 o23 = a23 * inv + b23;
  uint2 o;
  o.x = pack2(o01.x, o01.y);
  o.y = pack2(o23.x, o23.y);
  *(uint2*)&Hb[n * 64 + l5 * 2] = o;
}

// ---------------- BN stats: 8 row-streams/block, uint2 loads, LDS tree ----------------

__global__ __launch_bounds__(256) void k_bnstats(const unsigned* __restrict__ Hb,
                                                 float* __restrict__ cs) {
  __shared__ float red[8][256];
  int t = threadIdx.x;
  int ui = (t & 31) * 2;   // uint2 index -> channels c0..c0+3
  int c0 = ui * 2;
  int grp = t >> 5;        // 0..7 row streams
  int chunk = (NN + gridDim.x - 1) / gridDim.x;
  int n0 = blockIdx.x * chunk, n1 = min(n0 + chunk, NN);
  float s10 = 0.f, s11 = 0.f, s12 = 0.f, s13 = 0.f;
  float s20 = 0.f, s21 = 0.f, s22 = 0.f, s23 = 0.f;
  for (int n = n0 + grp; n < n1; n += 8) {
    uint2 h = *(const uint2*)&Hb[n * 64 + ui];
    float v0 = fmaxf(bf_lo(h.x), 0.f), v1 = fmaxf(bf_hi(h.x), 0.f);
    float v2 = fmaxf(bf_lo(h.y), 0.f), v3 = fmaxf(bf_hi(h.y), 0.f);
    s10 += v0; s11 += v1; s12 += v2; s13 += v3;
    s20 += v0 * v0; s21 += v1 * v1; s22 += v2 * v2; s23 += v3 * v3;
  }
  red[grp][c0 + 0] = s10; red[grp][c0 + 1] = s11;
  red[grp][c0 + 2] = s12; red[grp][c0 + 3] = s13;
  red[grp][128 + c0 + 0] = s20; red[grp][128 + c0 + 1] = s21;
  red[grp][128 + c0 + 2] = s22; red[grp][128 + c0 + 3] = s23;
  __syncthreads();
  float sum = 0.f;
#pragma unroll
  for (int g2 = 0; g2 < 8; ++g2) sum += red[g2][t];
  atomicAdd(&cs[t], sum);
}

// ---------------- pooling: 8 row-streams/block, uint2 loads, BN fused ----------------

__global__ __launch_bounds__(256) void k_pool(const unsigned* __restrict__ Hb,
    const int* __restrict__ batch, const float* __restrict__ cs,
    const float* __restrict__ g, const float* __restrict__ b,
    unsigned* __restrict__ pooled) {
  int t = threadIdx.x;
  int ui = (t & 31) * 2;
  int c0 = ui * 2;
  int grp = t >> 5;
  float scv0, scv1, scv2, scv3, shv0, shv1, shv2, shv3;
  {
    float mu, var;
    mu = cs[c0 + 0] * (1.f / NN); var = fmaxf(cs[HID + c0 + 0] * (1.f / NN) - mu * mu, 0.f);
    scv0 = g[c0 + 0] * rsqrtf(var + BNEPS); shv0 = b[c0 + 0] - mu * scv0;
    mu = cs[c0 + 1] * (1.f / NN); var = fmaxf(cs[HID + c0 + 1] * (1.f / NN) - mu * mu, 0.f);
    scv1 = g[c0 + 1] * rsqrtf(var + BNEPS); shv1 = b[c0 + 1] - mu * scv1;
    mu = cs[c0 + 2] * (1.f / NN); var = fmaxf(cs[HID + c0 + 2] * (1.f / NN) - mu * mu, 0.f);
    scv2 = g[c0 + 2] * rsqrtf(var + BNEPS); shv2 = b[c0 + 2] - mu * scv2;
    mu = cs[c0 + 3] * (1.f / NN); var = fmaxf(cs[HID + c0 + 3] * (1.f / NN) - mu * mu, 0.f);
    scv3 = g[c0 + 3] * rsqrtf(var + BNEPS); shv3 = b[c0 + 3] - mu * scv3;
  }
  int chunk = (NN + gridDim.x - 1) / gridDim.x;
  int n0 = blockIdx.x * chunk, n1 = min(n0 + chunk, NN);
  int curg = -1;
  float m0 = -3.402823e38f, m1 = m0, m2 = m0, m3 = m0;
  for (int n = n0 + grp; n < n1; n += 8) {
    int gg = batch[n];
    if (gg != curg) {
      if (curg >= 0) {
        atomicMax(&pooled[curg * HID + c0 + 0], fenc(m0));
        atomicMax(&pooled[curg * HID + c0 + 1], fenc(m1));
        atomicMax(&pooled[curg * HID + c0 + 2], fenc(m2));
        atomicMax(&pooled[curg * HID + c0 + 3], fenc(m3));
      }
      curg = gg;
      m0 = m1 = m2 = m3 = -3.402823e38f;
    }
    uint2 h = *(const uint2*)&Hb[n * 64 + ui];
    m0 = fmaxf(m0, fmaxf(bf_lo(h.x), 0.f) * scv0 + shv0);
    m1 = fmaxf(m1, fmaxf(bf_hi(h.x), 0.f) * scv1 + shv1);
    m2 = fmaxf(m2, fmaxf(bf_lo(h.y), 0.f) * scv2 + shv2);
    m3 = fmaxf(m3, fmaxf(bf_hi(h.y), 0.f) * scv3 + shv3);
  }
  if (curg >= 0) {
    atomicMax(&pooled[curg * HID + c0 + 0], fenc(m0));
    atomicMax(&pooled[curg * HID + c0 + 1], fenc(m1));
    atomicMax(&pooled[curg * HID + c0 + 2], fenc(m2));
    atomicMax(&pooled[curg * HID + c0 + 3], fenc(m3));
  }
}

// ---------------- FC head: one block per graph ----------------

__global__ __launch_bounds__(128) void k_fc(const unsigned* __restrict__ pooled,
    const float* __restrict__ W1, const float* __restrict__ b1,
    const float* __restrict__ W2, const float* __restrict__ b2,
    float* __restrict__ out) {
  __shared__ float P[HID];
  __shared__ float Z[HID];
  int g = blockIdx.x, c = threadIdx.x;
  unsigned k = pooled[g * HID + c];
  P[c] = (k & 0x80000000u) ? __uint_as_float(k ^ 0x80000000u) : __uint_as_float(~k);
  __syncthreads();
  float acc = b1[c];
  for (int kk = 0; kk < HID; ++kk) acc += P[kk] * W1[kk * HID + c];
  Z[c] = fmaxf(acc, 0.f);
  __syncthreads();
  if (c < 40) {
    float a2 = b2[c];
    for (int kk = 0; kk < HID; ++kk) a2 += Z[kk] * W2[kk * 40 + c];
    out[g * 40 + c] = a2;
  }
}

// ---------------- launch ----------------

extern "C" void kernel_launch(void* const* d_in, const int* in_sizes, int n_in,
                              void* d_out, int out_size, void* d_ws, size_t ws_size,
                              hipStream_t stream) {
  (void)in_sizes; (void)n_in; (void)out_size; (void)ws_size;
  const float* x     = (const float*)d_in[0];
  const float* eattr = (const float*)d_in[1];
  const int*   ei    = (const int*)d_in[2];
  const int*   batch = (const int*)d_in[3];
  const float* W0l   = (const float*)d_in[4];
  const float* W0r   = (const float*)d_in[5];
  const float* We0   = (const float*)d_in[6];
  const float* a0    = (const float*)d_in[7];
  const float* b0    = (const float*)d_in[8];
  const float* bn0g  = (const float*)d_in[9];
  const float* bn0b  = (const float*)d_in[10];
  const float* Wl    = (const float*)d_in[11];
  const float* Wel   = (const float*)d_in[12];
  const float* al    = (const float*)d_in[13];
  const float* bl    = (const float*)d_in[14];
  const float* bng   = (const float*)d_in[15];
  const float* bnb   = (const float*)d_in[16];
  const float* fc1W  = (const float*)d_in[17];
  const float* fc1b  = (const float*)d_in[18];
  const float* fc2W  = (const float*)d_in[19];
  const float* fc2b  = (const float*)d_in[20];
  float* out = (float*)d_out;

  char* ws = (char*)d_ws;
  unsigned* Hbf  = (unsigned*)(ws + 0);            // 12,800,000  (bf16 H)
  unsigned* Abf  = (unsigned*)(ws + 12800000);     // 12,800,000  (bf16 features)
  unsigned* X0bf = (unsigned*)(ws + 25600000);     // 12,800,000  (layer0 XR, bf16)
  uint2*    edat = (uint2*)(ws + 38400000);        // (850000+256)*8 = 6,802,048
  int*      rowp = (int*)(ws + 45202048);          // 50001*4 = 200,004
  int*      pos  = (int*)(ws + 45402112);          // 800000*4 = 3,200,000
  char*     zb   = ws + 48602112;                  // zeroed region start
  int*      deg  = (int*)(zb + 0);                 // 200,000
  float*    cs   = (float*)(zb + 200000);          // 3*256*4 = 3,072
  unsigned* pooled = (unsigned*)(zb + 203072);     // 32*128*4 = 16,384
  int*      bsum = (int*)(zb + 219456);            // 64*4 = 256
  const size_t ZLEN = 219712;

  hipMemsetAsync(zb, 0, ZLEN, stream);

  // build CSR (dst-sorted) with self loops + mean edge_attr fill
  k_hist<<<(NE + 255) / 256, 256, 0, stream>>>(ei, deg, pos);
  k_scanA<<<49, 1024, 0, stream>>>(deg, rowp, bsum);
  k_scanB<<<1, 64, 0, stream>>>(bsum, rowp, edat);
  k_scanC<<<49, 1024, 0, stream>>>(rowp, bsum);
  k_scatter<<<(NE + 255) / 256, 256, 0, stream>>>(ei, eattr, rowp, pos, edat);
  k_selfmean<<<(NN + 255) / 256, 256, 0, stream>>>(rowp, edat);

  const size_t GEMM_LDS = (size_t)(32 * HID + HID * HID) * 4;  // 81920 B

  // layer 0
  k_xform0<<<(NN * 32) / 256, 256, 0, stream>>>(x, W0l, W0r, Abf, X0bf);
  k_edge<<<NN / 8, 256, 0, stream>>>(Abf, X0bf, edat, rowp, We0, a0, b0, Hbf);
  k_bnstats<<<512, 256, 0, stream>>>(Hbf, cs);

  // layer 1
  k_gemm<<<782, 256, GEMM_LDS, stream>>>(Hbf, Wl, cs, bn0g, bn0b, Abf);
  k_edge<<<NN / 8, 256, 0, stream>>>(Abf, Abf, edat, rowp, Wel, al, bl, Hbf);
  k_bnstats<<<512, 256, 0, stream>>>(Hbf, cs + 256);

  // layer 2
  k_gemm<<<782, 256, GEMM_LDS, stream>>>(Hbf, Wl + 128 * 128, cs + 256, bng, bnb, Abf);
  k_edge<<<NN / 8, 256, 0, stream>>>(Abf, Abf, edat, rowp, Wel + 384, al + 128, bl + 128, Hbf);
  k_bnstats<<<512, 256, 0, stream>>>(Hbf, cs + 512);

  // pool + FC head
  k_pool<<<512, 256, 0, stream>>>(Hbf, batch, cs + 512, bng + 128, bnb + 128, pooled);
  k_fc<<<NG, 128, 0, stream>>>(pooled, fc1W, fc1b, fc2W, fc2b, out);
}

// Round 11
// 352.152 us; speedup vs baseline: 2.5991x; 1.1302x over previous
//
#include <hip/hip_runtime.h>

#define NN 50000
#define NE 800000
#define NG 32
#define HID 128
#define BNEPS 1e-5f
#define NETOT (NE + NN)  // 850000, CSR total incl self loops

typedef float f32x2 __attribute__((ext_vector_type(2)));
typedef float f32x4 __attribute__((ext_vector_type(4)));
typedef short bf16x8 __attribute__((ext_vector_type(8)));

__device__ __forceinline__ unsigned fenc(float f) {
  unsigned u = __float_as_uint(f);
  return (u & 0x80000000u) ? ~u : (u | 0x80000000u);
}

// round-to-nearest-even f32 -> bf16 (as low 16 bits)
__device__ __forceinline__ unsigned bfr(float f) {
  unsigned u = __float_as_uint(f);
  return (u + 0x7fffu + ((u >> 16) & 1u)) >> 16;
}
__device__ __forceinline__ unsigned pack2(float a, float b) {
  return bfr(a) | (bfr(b) << 16);
}
__device__ __forceinline__ float bf_lo(unsigned u) { return __uint_as_float(u << 16); }
__device__ __forceinline__ float bf_hi(unsigned u) { return __uint_as_float(u & 0xffff0000u); }

// fused DPP add: x += dpp_move(x); masked-out rows add 0
#define DPPADD(x, ctrl, rmask)                                                   \
  (x) += __int_as_float(__builtin_amdgcn_update_dpp(0, __float_as_int(x),        \
                                                    (ctrl), (rmask), 0xf, true))

// ---------------- preprocessing ----------------

__global__ __launch_bounds__(256) void k_hist(const int* __restrict__ ei,
                                              int* __restrict__ deg,
                                              int* __restrict__ pos) {
  int e = blockIdx.x * 256 + threadIdx.x;
  if (e >= NE) return;
  pos[e] = atomicAdd(&deg[ei[NE + e]], 1);
}

__global__ __launch_bounds__(1024) void k_scanA(const int* __restrict__ deg,
                                                int* __restrict__ rowp,
                                                int* __restrict__ bsum) {
  __shared__ int wsum[16];
  int t = threadIdx.x, lane = t & 63, w = t >> 6;
  int i = blockIdx.x * 1024 + t;
  int v = (i < NN) ? (deg[i] + 1) : 0;  // +1 self loop
  int s = v;
#pragma unroll
  for (int off = 1; off < 64; off <<= 1) {
    int y = __shfl_up(s, off, 64);
    if (lane >= off) s += y;
  }
  if (lane == 63) wsum[w] = s;
  __syncthreads();
  if (t < 16) {
    int xv = wsum[t];
#pragma unroll
    for (int off = 1; off < 16; off <<= 1) {
      int y = __shfl_up(xv, off, 64);
      if (t >= off) xv += y;
    }
    wsum[t] = xv;
  }
  __syncthreads();
  int wexcl = (w == 0) ? 0 : wsum[w - 1];
  int incl = wexcl + s;
  if (i < NN) rowp[i] = incl - v;  // block-local exclusive
  if (t == 1023) bsum[blockIdx.x] = incl;
}

__global__ __launch_bounds__(64) void k_scanB(int* __restrict__ bsum,
                                              int* __restrict__ rowp,
                                              uint2* __restrict__ edat) {
  int t = threadIdx.x;  // one wave; 49 block sums
  int v = (t < 49) ? bsum[t] : 0;
  int s = v;
#pragma unroll
  for (int off = 1; off < 64; off <<= 1) {
    int y = __shfl_up(s, off, 64);
    if (t >= off) s += y;
  }
  bsum[t] = s - v;                 // exclusive
  if (t == 48) rowp[NN] = s;       // total (== NETOT)
  for (int j = t; j < 256; j += 64) {  // zero pad entries (clamp-free prefetch)
    uint2 z; z.x = 0u; z.y = 0u;
    edat[NETOT + j] = z;
  }
}

__global__ __launch_bounds__(1024) void k_scanC(int* __restrict__ rowp,
                                                const int* __restrict__ bsum) {
  int i = blockIdx.x * 1024 + threadIdx.x;
  if (i < NN) rowp[i] += bsum[blockIdx.x];
}

// scatter edges into dst-CSR order (atomic-free; position from k_hist)
__global__ __launch_bounds__(256) void k_scatter(const int* __restrict__ ei,
    const float* __restrict__ eattr, const int* __restrict__ rowp,
    const int* __restrict__ pos, uint2* __restrict__ edat) {
  int e = blockIdx.x * 256 + threadIdx.x;
  if (e >= NE) return;
  int d = ei[NE + e];
  int p = rowp[d] + pos[e];
  uint2 v;
  v.x = (unsigned)ei[e] | (bfr(eattr[e * 3 + 0]) << 16);
  v.y = bfr(eattr[e * 3 + 1]) | (bfr(eattr[e * 3 + 2]) << 16);
  edat[p] = v;
}

// self-loop entry: mean of incoming edge attrs. one THREAD per node (contiguous seg).
__global__ __launch_bounds__(256) void k_selfmean(const int* __restrict__ rowp,
                                                  uint2* __restrict__ edat) {
  int n = blockIdx.x * 256 + threadIdx.x;
  if (n >= NN) return;
  int beg = rowp[n], endm1 = rowp[n + 1] - 1;
  float s0 = 0.f, s1 = 0.f, s2 = 0.f;
  for (int i = beg; i < endm1; ++i) {
    uint2 v = edat[i];
    s0 += bf_hi(v.x); s1 += bf_lo(v.y); s2 += bf_hi(v.y);
  }
  int cnt = endm1 - beg;
  float inv = cnt > 0 ? 1.f / (float)cnt : 0.f;
  uint2 o;
  o.x = (unsigned)n | (bfr(s0 * inv) << 16);
  o.y = bfr(s1 * inv) | (bfr(s2 * inv) << 16);
  edat[endm1] = o;
}

// ---------------- layer 0 input transform: A = x@W0l (bf16), B = x@W0r (bf16) ----------------

__global__ __launch_bounds__(256) void k_xform0(const float* __restrict__ x,
    const float* __restrict__ W0l, const float* __restrict__ W0r,
    unsigned* __restrict__ A, unsigned* __restrict__ B) {
  int t = blockIdx.x * 256 + threadIdx.x;
  int n = t >> 5;
  int c = (t & 31) * 4;
  if (n >= NN) return;
  float x0 = x[n * 3 + 0], x1 = x[n * 3 + 1], x2 = x[n * 3 + 2];
  float4 a0 = *(const float4*)&W0l[c];
  float4 a1 = *(const float4*)&W0l[HID + c];
  float4 a2 = *(const float4*)&W0l[2 * HID + c];
  float oax = x0 * a0.x + x1 * a1.x + x2 * a2.x;
  float oay = x0 * a0.y + x1 * a1.y + x2 * a2.y;
  float oaz = x0 * a0.z + x1 * a1.z + x2 * a2.z;
  float oaw = x0 * a0.w + x1 * a1.w + x2 * a2.w;
  uint2 pa;
  pa.x = pack2(oax, oay);
  pa.y = pack2(oaz, oaw);
  *(uint2*)&A[n * 64 + (c >> 1)] = pa;   // row stride = 64 uints (128 bf16)
  float4 b0 = *(const float4*)&W0r[c];
  float4 b1 = *(const float4*)&W0r[HID + c];
  float4 b2 = *(const float4*)&W0r[2 * HID + c];
  float obx = x0 * b0.x + x1 * b1.x + x2 * b2.x;
  float oby = x0 * b0.y + x1 * b1.y + x2 * b2.y;
  float obz = x0 * b0.z + x1 * b1.z + x2 * b2.z;
  float obw = x0 * b0.w + x1 * b1.w + x2 * b2.w;
  uint2 pb;
  pb.x = pack2(obx, oby);
  pb.y = pack2(obz, obw);
  *(uint2*)&B[n * 64 + (c >> 1)] = pb;
}

// ---------------- weight prep: Wt[n][k] = bf16(sc[k]*W[k][n]); bias2[n] = sh@W ----------------

__global__ __launch_bounds__(256) void k_wprep(const float* __restrict__ W,
    const float* __restrict__ cs, const float* __restrict__ g,
    const float* __restrict__ b, unsigned* __restrict__ Wt,
    float* __restrict__ bias2) {
  __shared__ float scS[HID], shS[HID];
  int t = threadIdx.x;
  if (t < HID) {
    float mu = cs[t] * (1.f / NN);
    float var = fmaxf(cs[HID + t] * (1.f / NN) - mu * mu, 0.f);
    float sc = g[t] * rsqrtf(var + BNEPS);
    scS[t] = sc;
    shS[t] = b[t] - mu * sc;
  }
  __syncthreads();
  for (int i = t; i < HID * 64; i += 256) {
    int n = i >> 6, kp = (i & 63) * 2;
    Wt[i] = pack2(scS[kp] * W[kp * HID + n], scS[kp + 1] * W[(kp + 1) * HID + n]);
  }
  if (t < HID) {
    float acc = 0.f;
    for (int k = 0; k < HID; ++k) acc += shS[k] * W[k * HID + t];
    bias2[t] = acc;
  }
}

// ---------------- GEMM v2 (MFMA): A(bf16) = relu(Hb) @ Wt^T + bias2 ----------------
// Wt is [n][k] bf16-packed. Per block: 4 waves x 16 rows. 16x16x32 bf16 MFMA.

__global__ __launch_bounds__(256) void k_gemm(const unsigned* __restrict__ Hb,
    const unsigned* __restrict__ Wt, const float* __restrict__ bias2,
    unsigned* __restrict__ A) {
  __shared__ unsigned WsL[HID * 68];  // [128][68] pad -> 2-way-free banks, 34.8KB
  int t = threadIdx.x;
  for (int i = t; i < HID * 64; i += 256)
    WsL[(i >> 6) * 68 + (i & 63)] = Wt[i];
  __syncthreads();
  int l = t & 63;
  int w = t >> 6;
  int r0 = blockIdx.x * 64 + w * 16;
  int l15 = l & 15;
  int arow = min(r0 + l15, NN - 1);
  int kg = (l >> 4) * 4;  // uint offset of this lane's k-group (8 bf16)
  float bl[8];
#pragma unroll
  for (int nt = 0; nt < 8; ++nt) bl[nt] = bias2[nt * 16 + l15];
  f32x4 acc[8] = {};
#pragma unroll
  for (int ks = 0; ks < 4; ++ks) {
    uint4 au = *(const uint4*)&Hb[arow * 64 + ks * 16 + kg];
    au.x &= ~(((au.x >> 15) & 0x10001u) * 0xFFFFu);  // packed relu
    au.y &= ~(((au.y >> 15) & 0x10001u) * 0xFFFFu);
    au.z &= ~(((au.z >> 15) & 0x10001u) * 0xFFFFu);
    au.w &= ~(((au.w >> 15) & 0x10001u) * 0xFFFFu);
    bf16x8 af = *(bf16x8*)&au;
#pragma unroll
    for (int nt = 0; nt < 8; ++nt) {
      uint4 bu = *(const uint4*)&WsL[(nt * 16 + l15) * 68 + ks * 16 + kg];
      bf16x8 bf = *(bf16x8*)&bu;
      acc[nt] = __builtin_amdgcn_mfma_f32_16x16x32_bf16(af, bf, acc[nt], 0, 0, 0);
    }
  }
  // D: row=(l>>4)*4+reg, col=nt*16+(l&15). Pack col pairs via shfl, even lanes store.
#pragma unroll
  for (int nt = 0; nt < 8; ++nt) {
#pragma unroll
    for (int reg = 0; reg < 4; ++reg) {
      float v = acc[nt][reg] + bl[nt];
      float nb = __shfl_down(v, 1, 64);
      int rm = r0 + (l >> 4) * 4 + reg;
      if (((l & 1) == 0) && rm < NN)
        A[rm * 64 + nt * 8 + (l15 >> 1)] = pack2(v, nb);
    }
  }
}

// ---- GATv2 edge phase v8: 2 dst/wave, packed-f32 channel math (f32x2),
//      static 4-unroll (no rotation movs), padded edat (no clamps) ----

__global__ __launch_bounds__(256) void k_edge(const unsigned* __restrict__ XL,
    const unsigned* __restrict__ XR, const uint2* __restrict__ edat,
    const int* __restrict__ rowp, const float* __restrict__ We,
    const float* __restrict__ att, const float* __restrict__ bias,
    unsigned* __restrict__ Hb) {
  __shared__ float WeS[3 * HID];
  int t = threadIdx.x;
  for (int i = t; i < 3 * HID; i += 256) WeS[i] = We[i];
  __syncthreads();
  int lane = t & 63;
  int l5 = lane & 31;
  int half = lane >> 5;
  int n = blockIdx.x * 8 + (t >> 6) * 2 + half;   // 8 nodes per block
  int c0 = l5 * 4;                                 // this lane's 4 channels
  uint2 urx = *(const uint2*)&XR[n * 64 + l5 * 2];
  f32x2 xr01 = {bf_lo(urx.x), bf_hi(urx.x)};
  f32x2 xr23 = {bf_lo(urx.y), bf_hi(urx.y)};
  f32x2 at01 = *(const f32x2*)&att[c0];
  f32x2 at23 = *(const f32x2*)&att[c0 + 2];
  at01 *= 1.44269504f;  // fold log2(e)
  at23 *= 1.44269504f;
  f32x2 w0a = {WeS[c0], WeS[c0 + 1]},               w0b = {WeS[c0 + 2], WeS[c0 + 3]};
  f32x2 w1a = {WeS[HID + c0], WeS[HID + c0 + 1]},   w1b = {WeS[HID + c0 + 2], WeS[HID + c0 + 3]};
  f32x2 w2a = {WeS[2*HID + c0], WeS[2*HID + c0+1]}, w2b = {WeS[2*HID + c0+2], WeS[2*HID + c0+3]};
  int beg = rowp[n], end = rowp[n + 1];
  int rem = end - beg;
  int tc = max(rem, __shfl_xor(rem, 32, 64));
  int trips = (__builtin_amdgcn_readfirstlane(tc) + 3) & ~3;
  const unsigned* XLg = XL + l5 * 2;

  // prologue (pads make all loads in-bounds; pad src=0 valid, masked out)
  uint2 e0 = edat[beg], e1 = edat[beg + 1], e2 = edat[beg + 2], e3 = edat[beg + 3];
  uint2 x0 = *(const uint2*)&XLg[(e0.x & 0xffffu) * 64];
  uint2 x1 = *(const uint2*)&XLg[(e1.x & 0xffffu) * 64];
  uint2 x2, x3;
  f32x2 a01 = {0.f, 0.f}, a23 = {0.f, 0.f};
  float s = 0.f;

#define BODY(ED, XU, J)                                                           \
  {                                                                               \
    f32x2 xs01 = {bf_lo(XU.x), bf_hi(XU.x)};                                      \
    f32x2 xs23 = {bf_lo(XU.y), bf_hi(XU.y)};                                      \
    float ea0 = bf_hi(ED.x), ea1 = bf_lo(ED.y), ea2 = bf_hi(ED.y);                \
    f32x2 u01 = xs01 + xr01;                                                      \
    f32x2 u23 = xs23 + xr23;                                                      \
    u01 = ea0 * w0a + u01;  u23 = ea0 * w0b + u23;                                \
    u01 = ea1 * w1a + u01;  u23 = ea1 * w1b + u23;                                \
    u01 = ea2 * w2a + u01;  u23 = ea2 * w2b + u23;                                \
    f32x2 v01 = __builtin_elementwise_max(u01, 0.2f * u01);                       \
    f32x2 v23 = __builtin_elementwise_max(u23, 0.2f * u23);                       \
    f32x2 pl = v01 * at01 + v23 * at23;                                           \
    float part = pl.x + pl.y;                                                     \
    DPPADD(part, 0x111, 0xf);                                                     \
    DPPADD(part, 0x112, 0xf);                                                     \
    DPPADD(part, 0x114, 0xf);                                                     \
    DPPADD(part, 0x118, 0xf);                                                     \
    DPPADD(part, 0x142, 0xa);                                                     \
    part = __int_as_float(__builtin_amdgcn_ds_swizzle(                            \
        __float_as_int(part), 0x3E0));  /* bcast lane31 within 32-group */        \
    float p = __builtin_amdgcn_exp2f(part);                                       \
    p = (i + (J) < rem) ? p : 0.f;                                                \
    s += p;                                                                       \
    a01 = p * xs01 + a01;                                                         \
    a23 = p * xs23 + a23;                                                         \
  }

  for (int i = 0; i < trips; i += 4) {
    x2 = *(const uint2*)&XLg[(e2.x & 0xffffu) * 64];
    BODY(e0, x0, 0);
    e0 = edat[beg + i + 4];
    x3 = *(const uint2*)&XLg[(e3.x & 0xffffu) * 64];
    BODY(e1, x1, 1);
    e1 = edat[beg + i + 5];
    x0 = *(const uint2*)&XLg[(e0.x & 0xffffu) * 64];
    BODY(e2, x2, 2);
    e2 = edat[beg + i + 6];
    x1 = *(const uint2*)&XLg[(e1.x & 0xffffu) * 64];
    BODY(e3, x3, 3);
    e3 = edat[beg + i + 7];
  }
#undef BODY

  float inv = 1.f / s;
  f32x2 b01 = *(const f32x2*)&bias[c0];
  f32x2 b23 = *(const f32x2*)&bias[c0 + 2];
  f32x2 o01 = a01 * inv + b01;
  f32x2 o23 = a23 * inv + b23;
  uint2 o;
  o.x = pack2(o01.x, o01.y);
  o.y = pack2(o23.x, o23.y);
  *(uint2*)&Hb[n * 64 + l5 * 2] = o;
}

// ---------------- BN stats: 8 row-streams/block, uint2 loads, LDS tree ----------------

__global__ __launch_bounds__(256) void k_bnstats(const unsigned* __restrict__ Hb,
                                                 float* __restrict__ cs) {
  __shared__ float red[8][256];
  int t = threadIdx.x;
  int ui = (t & 31) * 2;   // uint2 index -> channels c0..c0+3
  int c0 = ui * 2;
  int grp = t >> 5;        // 0..7 row streams
  int chunk = (NN + gridDim.x - 1) / gridDim.x;
  int n0 = blockIdx.x * chunk, n1 = min(n0 + chunk, NN);
  float s10 = 0.f, s11 = 0.f, s12 = 0.f, s13 = 0.f;
  float s20 = 0.f, s21 = 0.f, s22 = 0.f, s23 = 0.f;
  for (int n = n0 + grp; n < n1; n += 8) {
    uint2 h = *(const uint2*)&Hb[n * 64 + ui];
    float v0 = fmaxf(bf_lo(h.x), 0.f), v1 = fmaxf(bf_hi(h.x), 0.f);
    float v2 = fmaxf(bf_lo(h.y), 0.f), v3 = fmaxf(bf_hi(h.y), 0.f);
    s10 += v0; s11 += v1; s12 += v2; s13 += v3;
    s20 += v0 * v0; s21 += v1 * v1; s22 += v2 * v2; s23 += v3 * v3;
  }
  red[grp][c0 + 0] = s10; red[grp][c0 + 1] = s11;
  red[grp][c0 + 2] = s12; red[grp][c0 + 3] = s13;
  red[grp][128 + c0 + 0] = s20; red[grp][128 + c0 + 1] = s21;
  red[grp][128 + c0 + 2] = s22; red[grp][128 + c0 + 3] = s23;
  __syncthreads();
  float sum = 0.f;
#pragma unroll
  for (int g2 = 0; g2 < 8; ++g2) sum += red[g2][t];
  atomicAdd(&cs[t], sum);
}

// ---------------- pooling: 8 row-streams/block, uint2 loads, BN fused ----------------

__global__ __launch_bounds__(256) void k_pool(const unsigned* __restrict__ Hb,
    const int* __restrict__ batch, const float* __restrict__ cs,
    const float* __restrict__ g, const float* __restrict__ b,
    unsigned* __restrict__ pooled) {
  int t = threadIdx.x;
  int ui = (t & 31) * 2;
  int c0 = ui * 2;
  int grp = t >> 5;
  float scv0, scv1, scv2, scv3, shv0, shv1, shv2, shv3;
  {
    float mu, var;
    mu = cs[c0 + 0] * (1.f / NN); var = fmaxf(cs[HID + c0 + 0] * (1.f / NN) - mu * mu, 0.f);
    scv0 = g[c0 + 0] * rsqrtf(var + BNEPS); shv0 = b[c0 + 0] - mu * scv0;
    mu = cs[c0 + 1] * (1.f / NN); var = fmaxf(cs[HID + c0 + 1] * (1.f / NN) - mu * mu, 0.f);
    scv1 = g[c0 + 1] * rsqrtf(var + BNEPS); shv1 = b[c0 + 1] - mu * scv1;
    mu = cs[c0 + 2] * (1.f / NN); var = fmaxf(cs[HID + c0 + 2] * (1.f / NN) - mu * mu, 0.f);
    scv2 = g[c0 + 2] * rsqrtf(var + BNEPS); shv2 = b[c0 + 2] - mu * scv2;
    mu = cs[c0 + 3] * (1.f / NN); var = fmaxf(cs[HID + c0 + 3] * (1.f / NN) - mu * mu, 0.f);
    scv3 = g[c0 + 3] * rsqrtf(var + BNEPS); shv3 = b[c0 + 3] - mu * scv3;
  }
  int chunk = (NN + gridDim.x - 1) / gridDim.x;
  int n0 = blockIdx.x * chunk, n1 = min(n0 + chunk, NN);
  int curg = -1;
  float m0 = -3.402823e38f, m1 = m0, m2 = m0, m3 = m0;
  for (int n = n0 + grp; n < n1; n += 8) {
    int gg = batch[n];
    if (gg != curg) {
      if (curg >= 0) {
        atomicMax(&pooled[curg * HID + c0 + 0], fenc(m0));
        atomicMax(&pooled[curg * HID + c0 + 1], fenc(m1));
        atomicMax(&pooled[curg * HID + c0 + 2], fenc(m2));
        atomicMax(&pooled[curg * HID + c0 + 3], fenc(m3));
      }
      curg = gg;
      m0 = m1 = m2 = m3 = -3.402823e38f;
    }
    uint2 h = *(const uint2*)&Hb[n * 64 + ui];
    m0 = fmaxf(m0, fmaxf(bf_lo(h.x), 0.f) * scv0 + shv0);
    m1 = fmaxf(m1, fmaxf(bf_hi(h.x), 0.f) * scv1 + shv1);
    m2 = fmaxf(m2, fmaxf(bf_lo(h.y), 0.f) * scv2 + shv2);
    m3 = fmaxf(m3, fmaxf(bf_hi(h.y), 0.f) * scv3 + shv3);
  }
  if (curg >= 0) {
    atomicMax(&pooled[curg * HID + c0 + 0], fenc(m0));
    atomicMax(&pooled[curg * HID + c0 + 1], fenc(m1));
    atomicMax(&pooled[curg * HID + c0 + 2], fenc(m2));
    atomicMax(&pooled[curg * HID + c0 + 3], fenc(m3));
  }
}

// ---------------- FC head: one block per graph ----------------

__global__ __launch_bounds__(128) void k_fc(const unsigned* __restrict__ pooled,
    const float* __restrict__ W1, const float* __restrict__ b1,
    const float* __restrict__ W2, const float* __restrict__ b2,
    float* __restrict__ out) {
  __shared__ float P[HID];
  __shared__ float Z[HID];
  int g = blockIdx.x, c = threadIdx.x;
  unsigned k = pooled[g * HID + c];
  P[c] = (k & 0x80000000u) ? __uint_as_float(k ^ 0x80000000u) : __uint_as_float(~k);
  __syncthreads();
  float acc = b1[c];
  for (int kk = 0; kk < HID; ++kk) acc += P[kk] * W1[kk * HID + c];
  Z[c] = fmaxf(acc, 0.f);
  __syncthreads();
  if (c < 40) {
    float a2 = b2[c];
    for (int kk = 0; kk < HID; ++kk) a2 += Z[kk] * W2[kk * 40 + c];
    out[g * 40 + c] = a2;
  }
}

// ---------------- launch ----------------

extern "C" void kernel_launch(void* const* d_in, const int* in_sizes, int n_in,
                              void* d_out, int out_size, void* d_ws, size_t ws_size,
                              hipStream_t stream) {
  (void)in_sizes; (void)n_in; (void)out_size; (void)ws_size;
  const float* x     = (const float*)d_in[0];
  const float* eattr = (const float*)d_in[1];
  const int*   ei    = (const int*)d_in[2];
  const int*   batch = (const int*)d_in[3];
  const float* W0l   = (const float*)d_in[4];
  const float* W0r   = (const float*)d_in[5];
  const float* We0   = (const float*)d_in[6];
  const float* a0    = (const float*)d_in[7];
  const float* b0    = (const float*)d_in[8];
  const float* bn0g  = (const float*)d_in[9];
  const float* bn0b  = (const float*)d_in[10];
  const float* Wl    = (const float*)d_in[11];
  const float* Wel   = (const float*)d_in[12];
  const float* al    = (const float*)d_in[13];
  const float* bl    = (const float*)d_in[14];
  const float* bng   = (const float*)d_in[15];
  const float* bnb   = (const float*)d_in[16];
  const float* fc1W  = (const float*)d_in[17];
  const float* fc1b  = (const float*)d_in[18];
  const float* fc2W  = (const float*)d_in[19];
  const float* fc2b  = (const float*)d_in[20];
  float* out = (float*)d_out;

  char* ws = (char*)d_ws;
  unsigned* Hbf  = (unsigned*)(ws + 0);            // 12,800,000  (bf16 H)
  unsigned* Abf  = (unsigned*)(ws + 12800000);     // 12,800,000  (bf16 features)
  unsigned* X0bf = (unsigned*)(ws + 25600000);     // 12,800,000  (layer0 XR, bf16)
  uint2*    edat = (uint2*)(ws + 38400000);        // (850000+256)*8 = 6,802,048
  int*      rowp = (int*)(ws + 45202048);          // 50001*4 = 200,004
  int*      pos  = (int*)(ws + 45402112);          // 800000*4 = 3,200,000
  char*     zb   = ws + 48602112;                  // zeroed region start
  int*      deg  = (int*)(zb + 0);                 // 200,000
  float*    cs   = (float*)(zb + 200000);          // 3*256*4 = 3,072
  unsigned* pooled = (unsigned*)(zb + 203072);     // 32*128*4 = 16,384
  int*      bsum = (int*)(zb + 219456);            // 64*4 = 256
  const size_t ZLEN = 219712;
  unsigned* wtb   = (unsigned*)(ws + 48821824);    // 128*64*4 = 32,768
  float*    bias2 = (float*)(ws + 48854592);       // 128*4 = 512

  hipMemsetAsync(zb, 0, ZLEN, stream);

  // build CSR (dst-sorted) with self loops + mean edge_attr fill
  k_hist<<<(NE + 255) / 256, 256, 0, stream>>>(ei, deg, pos);
  k_scanA<<<49, 1024, 0, stream>>>(deg, rowp, bsum);
  k_scanB<<<1, 64, 0, stream>>>(bsum, rowp, edat);
  k_scanC<<<49, 1024, 0, stream>>>(rowp, bsum);
  k_scatter<<<(NE + 255) / 256, 256, 0, stream>>>(ei, eattr, rowp, pos, edat);
  k_selfmean<<<(NN + 255) / 256, 256, 0, stream>>>(rowp, edat);

  // layer 0
  k_xform0<<<(NN * 32) / 256, 256, 0, stream>>>(x, W0l, W0r, Abf, X0bf);
  k_edge<<<NN / 8, 256, 0, stream>>>(Abf, X0bf, edat, rowp, We0, a0, b0, Hbf);
  k_bnstats<<<512, 256, 0, stream>>>(Hbf, cs);

  // layer 1
  k_wprep<<<1, 256, 0, stream>>>(Wl, cs, bn0g, bn0b, wtb, bias2);
  k_gemm<<<(NN + 63) / 64, 256, 0, stream>>>(Hbf, wtb, bias2, Abf);
  k_edge<<<NN / 8, 256, 0, stream>>>(Abf, Abf, edat, rowp, Wel, al, bl, Hbf);
  k_bnstats<<<512, 256, 0, stream>>>(Hbf, cs + 256);

  // layer 2
  k_wprep<<<1, 256, 0, stream>>>(Wl + 128 * 128, cs + 256, bng, bnb, wtb, bias2);
  k_gemm<<<(NN + 63) / 64, 256, 0, stream>>>(Hbf, wtb, bias2, Abf);
  k_edge<<<NN / 8, 256, 0, stream>>>(Abf, Abf, edat, rowp, Wel + 384, al + 128, bl + 128, Hbf);
  k_bnstats<<<512, 256, 0, stream>>>(Hbf, cs + 512);

  // pool + FC head
  k_pool<<<512, 256, 0, stream>>>(Hbf, batch, cs + 512, bng + 128, bnb + 128, pooled);
  k_fc<<<NG, 128, 0, stream>>>(pooled, fc1W, fc1b, fc2W, fc2b, out);
}